// Round 1
// baseline (2819.460 us; speedup 1.0000x reference)
//
#include <hip/hip_runtime.h>
#include <hip/hip_bf16.h>

#define NTOK 65536      // 4 * 16384 tokens
#define NPB  16384      // tokens per window-batch

__device__ __forceinline__ float gelu_f(float x){
    return 0.5f * x * (1.0f + erff(x * 0.70710678118654752440f));
}
__device__ __forceinline__ float bf2f(unsigned short u){
    union { unsigned int i; float f; } w; w.i = ((unsigned int)u) << 16; return w.f;
}

// ---------- std LayerNorm over 256 (biased var, /sqrt(var+eps)) ----------
__global__ __launch_bounds__(256) void stdln_kernel(const float* __restrict__ X,
                                                    const float* __restrict__ w,
                                                    const float* __restrict__ b,
                                                    float* __restrict__ out){
    int r = blockIdx.x, c = threadIdx.x;
    size_t base = (size_t)r * 256;
    float v = X[base + c];
    float s = v;
    #pragma unroll
    for (int m = 1; m < 64; m <<= 1) s += __shfl_xor(s, m, 64);
    __shared__ float sm[8];
    int wid = c >> 6;
    if ((c & 63) == 0) sm[wid] = s;
    __syncthreads();
    float mean = (sm[0] + sm[1] + sm[2] + sm[3]) * (1.0f / 256.0f);
    float dv = v - mean;
    float ss = dv * dv;
    #pragma unroll
    for (int m = 1; m < 64; m <<= 1) ss += __shfl_xor(ss, m, 64);
    if ((c & 63) == 0) sm[4 + wid] = ss;
    __syncthreads();
    float var = (sm[4] + sm[5] + sm[6] + sm[7]) * (1.0f / 256.0f);
    out[base + c] = w[c] * dv * rsqrtf(var + 1e-5f) + b[c];
}

// ---------- custom LN (ddof=1, /(std+eps)) over 32-wide head groups, K and V in place ----------
__global__ __launch_bounds__(256) void kvln_kernel(float* __restrict__ Kb, float* __restrict__ Vb,
                                                   const float* __restrict__ kw, const float* __restrict__ kbb,
                                                   const float* __restrict__ vw, const float* __restrict__ vbb){
    int r = blockIdx.x, c = threadIdx.x;
    size_t idx = (size_t)r * 256 + c;
    {
        float v = Kb[idx];
        float s = v;
        #pragma unroll
        for (int m = 1; m < 32; m <<= 1) s += __shfl_xor(s, m, 64);
        float mean = s * (1.0f / 32.0f);
        float dv = v - mean;
        float ss = dv * dv;
        #pragma unroll
        for (int m = 1; m < 32; m <<= 1) ss += __shfl_xor(ss, m, 64);
        float sd = sqrtf(ss * (1.0f / 31.0f));
        Kb[idx] = kw[c] * dv / (sd + 1e-5f) + kbb[c];
    }
    {
        float v = Vb[idx];
        float s = v;
        #pragma unroll
        for (int m = 1; m < 32; m <<= 1) s += __shfl_xor(s, m, 64);
        float mean = s * (1.0f / 32.0f);
        float dv = v - mean;
        float ss = dv * dv;
        #pragma unroll
        for (int m = 1; m < 32; m <<= 1) ss += __shfl_xor(ss, m, 64);
        float sd = sqrtf(ss * (1.0f / 31.0f));
        Vb[idx] = vw[c] * dv / (sd + 1e-5f) + vbb[c];
    }
}

// ---------- ce_flat = cor @ cor_w.T (K=2) fused with 16-wide-group custom LN ----------
__global__ __launch_bounds__(128) void ce_kernel(const float* __restrict__ cor,
                                                 const float* __restrict__ cor_w,
                                                 const float* __restrict__ cw, const float* __restrict__ cb,
                                                 float* __restrict__ CEF, float* __restrict__ CE){
    int r = blockIdx.x, m = threadIdx.x;  // 128 threads
    float c0 = cor[(size_t)r * 2 + 0];
    float c1 = cor[(size_t)r * 2 + 1];
    float v = c0 * cor_w[m * 2 + 0] + c1 * cor_w[m * 2 + 1];
    size_t idx = (size_t)r * 128 + m;
    CEF[idx] = v;
    float s = v;
    #pragma unroll
    for (int mm = 1; mm < 16; mm <<= 1) s += __shfl_xor(s, mm, 64);
    float mean = s * (1.0f / 16.0f);
    float dv = v - mean;
    float ss = dv * dv;
    #pragma unroll
    for (int mm = 1; mm < 16; mm <<= 1) ss += __shfl_xor(ss, mm, 64);
    float sd = sqrtf(ss * (1.0f / 15.0f));
    CE[idx] = cw[m] * dv / (sd + 1e-5f) + cb[m];
}

// ---------- ktv[b][h][d][e] = sum_n K[b,n,h*32+d] * V[b,n,h*32+e] / N ----------
__global__ __launch_bounds__(1024) void ktv_kernel(const float* __restrict__ Kb,
                                                   const float* __restrict__ Vb,
                                                   float* __restrict__ KTV){
    int bh = blockIdx.x;          // 0..31
    int b = bh >> 3, h = bh & 7;
    int chunk = blockIdx.y;       // 0..7, each 2048 tokens
    int t = threadIdx.x;          // 1024
    int d = t >> 5, e = t & 31;
    int n0 = chunk * 2048;
    const float* kp = Kb + ((size_t)(b << 14) + n0) * 256 + h * 32 + d;
    const float* vp = Vb + ((size_t)(b << 14) + n0) * 256 + h * 32 + e;
    float acc = 0.0f;
    for (int n = 0; n < 2048; n++){ acc = fmaf(kp[0], vp[0], acc); kp += 256; vp += 256; }
    atomicAdd(&KTV[((bh * 32 + d) * 32 + e)], acc * (1.0f / 16384.0f));
}

// ---------- ktc[b][h][d][e] = sum_n K[b,n,h*32+d] * CE[b,n,h*16+e] / N ----------
__global__ __launch_bounds__(512) void ktc_kernel(const float* __restrict__ Kb,
                                                  const float* __restrict__ CE,
                                                  float* __restrict__ KTC){
    int bh = blockIdx.x;
    int b = bh >> 3, h = bh & 7;
    int chunk = blockIdx.y;
    int t = threadIdx.x;          // 512
    int d = t >> 4, e = t & 15;
    int n0 = chunk * 2048;
    const float* kp = Kb + ((size_t)(b << 14) + n0) * 256 + h * 32 + d;
    const float* cp = CE + ((size_t)(b << 14) + n0) * 128 + h * 16 + e;
    float acc = 0.0f;
    for (int n = 0; n < 2048; n++){ acc = fmaf(kp[0], cp[0], acc); kp += 256; cp += 128; }
    atomicAdd(&KTC[((bh * 32 + d) * 16 + e)], acc * (1.0f / 16384.0f));
}

// ---------- t = q @ ktv + xn ----------
__global__ __launch_bounds__(256) void app_kernel(const float* __restrict__ Q,
                                                  const float* __restrict__ XN,
                                                  const float* __restrict__ KTV,
                                                  float* __restrict__ T1){
    int r = blockIdx.x, c = threadIdx.x;
    int b = r >> 14;
    __shared__ float qrow[256];
    size_t base = (size_t)r * 256;
    qrow[c] = Q[base + c];
    __syncthreads();
    int h = c >> 5, e = c & 31;
    const float* kt = KTV + ((size_t)((b * 8 + h) * 32)) * 32 + e;
    float acc = 0.0f;
    #pragma unroll
    for (int d = 0; d < 32; d++) acc = fmaf(qrow[h * 32 + d], kt[d * 32], acc);
    T1[base + c] = acc + XN[base + c];
}

// ---------- dm = q @ ktc - ce_flat ----------
__global__ __launch_bounds__(128) void crev_kernel(const float* __restrict__ Q,
                                                   const float* __restrict__ KTC,
                                                   const float* __restrict__ CEF,
                                                   float* __restrict__ TM){
    int r = blockIdx.x, c = threadIdx.x;   // c = m in 0..127
    int b = r >> 14;
    __shared__ float qrow[256];
    size_t qb = (size_t)r * 256;
    qrow[c] = Q[qb + c];
    qrow[c + 128] = Q[qb + c + 128];
    __syncthreads();
    int h = c >> 4, e = c & 15;
    const float* kt = KTC + ((size_t)((b * 8 + h) * 32)) * 16 + e;
    float acc = 0.0f;
    #pragma unroll
    for (int d = 0; d < 32; d++) acc = fmaf(qrow[h * 32 + d], kt[d * 16], acc);
    size_t idx = (size_t)r * 128 + c;
    TM[idx] = acc - CEF[idx];
}

// ---------- depthwise 3x3 conv (SAME) + bias + gelu, channel-last bf16 ----------
__global__ __launch_bounds__(256) void dwconv_kernel(const __hip_bfloat16* __restrict__ H1b,
                                                     const float* __restrict__ dww,
                                                     const float* __restrict__ dwb,
                                                     __hip_bfloat16* __restrict__ H2b){
    int p = blockIdx.x;
    int bb = p >> 14;
    int yy = (p >> 7) & 127;
    int xx = p & 127;
    const unsigned short* H1u = (const unsigned short*)H1b;
    for (int ch = threadIdx.x; ch < 768; ch += 256){
        float acc = dwb[ch];
        #pragma unroll
        for (int dy = -1; dy <= 1; dy++){
            int y2 = yy + dy; if (y2 < 0 || y2 > 127) continue;
            #pragma unroll
            for (int dx = -1; dx <= 1; dx++){
                int x2 = xx + dx; if (x2 < 0 || x2 > 127) continue;
                size_t idx = ((size_t)((bb << 14) + (y2 << 7) + x2)) * 768 + ch;
                acc = fmaf(bf2f(H1u[idx]), dww[ch * 9 + (dy + 1) * 3 + (dx + 1)], acc);
            }
        }
        H2b[(size_t)p * 768 + ch] = __float2bfloat16(gelu_f(acc));
    }
}

// ---------- tiled fp32 GEMM: out[r][c] = dot(A[r], W[c]) (+ epilogue) ----------
// A: (NTOK, K) row-major (fp32 or bf16); W: (O, K) row-major fp32
#define M_PLAIN     0
#define M_KV        1
#define M_BIAS_GELU 2
#define M_BIAS_ADD2 3
#define M_BIAS      4
#define M_BIAS_BF16 5
#define M_BIAS_ADDX 6

template<int MODE, bool SWAP, bool A_BF16, int K, int O>
__global__ __launch_bounds__(256) void gemm_kernel(const void* __restrict__ Ap,
                                                   const float* __restrict__ W,
                                                   const float* __restrict__ bias,
                                                   const float* __restrict__ add,
                                                   void* __restrict__ out0,
                                                   void* __restrict__ out1){
    __shared__ float As[64][33];
    __shared__ float Bs[64][33];
    int t = threadIdx.x;
    int tm = t >> 4, tn = t & 15;
    int row0 = blockIdx.x * 64;
    int col0 = blockIdx.y * 64;
    float acc[4][4] = {};

    for (int kb = 0; kb < K; kb += 32){
        #pragma unroll
        for (int i = 0; i < 2; i++){
            int idx = t + i * 256;
            int r = idx >> 3;
            int c4 = (idx & 7) * 4;
            int grow = row0 + r;
            if (SWAP){ int b = grow >> 14; int n = grow & 16383; grow = (((b + 2) & 3) << 14) | n; }
            if (A_BF16){
                const unsigned short* Au = (const unsigned short*)Ap;
                ushort4 u = *reinterpret_cast<const ushort4*>(&Au[(size_t)grow * K + kb + c4]);
                As[r][c4 + 0] = bf2f(u.x); As[r][c4 + 1] = bf2f(u.y);
                As[r][c4 + 2] = bf2f(u.z); As[r][c4 + 3] = bf2f(u.w);
            } else {
                const float* Af = (const float*)Ap;
                float4 v = *reinterpret_cast<const float4*>(&Af[(size_t)grow * K + kb + c4]);
                As[r][c4 + 0] = v.x; As[r][c4 + 1] = v.y; As[r][c4 + 2] = v.z; As[r][c4 + 3] = v.w;
            }
            float4 w4 = *reinterpret_cast<const float4*>(&W[(size_t)(col0 + r) * K + kb + c4]);
            Bs[r][c4 + 0] = w4.x; Bs[r][c4 + 1] = w4.y; Bs[r][c4 + 2] = w4.z; Bs[r][c4 + 3] = w4.w;
        }
        __syncthreads();
        #pragma unroll
        for (int kk = 0; kk < 32; kk++){
            float a[4], bv[4];
            #pragma unroll
            for (int i = 0; i < 4; i++) a[i] = As[tm * 4 + i][kk];
            #pragma unroll
            for (int j = 0; j < 4; j++) bv[j] = Bs[tn * 4 + j][kk];
            #pragma unroll
            for (int i = 0; i < 4; i++)
                #pragma unroll
                for (int j = 0; j < 4; j++) acc[i][j] = fmaf(a[i], bv[j], acc[i][j]);
        }
        __syncthreads();
    }

    #pragma unroll
    for (int i = 0; i < 4; i++){
        int r = row0 + tm * 4 + i;
        #pragma unroll
        for (int j = 0; j < 4; j++){
            int c = col0 + tn * 4 + j;
            float v = acc[i][j];
            if constexpr (MODE == M_PLAIN){
                ((float*)out0)[(size_t)r * O + c] = v;
            } else if constexpr (MODE == M_KV){
                if (c < 256) ((float*)out0)[(size_t)r * 256 + c] = v;
                else         ((float*)out1)[(size_t)r * 256 + (c - 256)] = v;
            } else if constexpr (MODE == M_BIAS_GELU){
                ((float*)out0)[(size_t)r * O + c] = gelu_f(v + bias[c]);
            } else if constexpr (MODE == M_BIAS_ADD2){
                ((float*)out0)[(size_t)r * O + c] = v + bias[c] + 2.0f * add[(size_t)r * O + c];
            } else if constexpr (MODE == M_BIAS){
                ((float*)out0)[(size_t)r * O + c] = v + bias[c];
            } else if constexpr (MODE == M_BIAS_BF16){
                ((__hip_bfloat16*)out0)[(size_t)r * O + c] = __float2bfloat16(v + bias[c]);
            } else if constexpr (MODE == M_BIAS_ADDX){
                ((float*)out0)[(size_t)r * O + c] = v + bias[c] + add[(size_t)r * O + c];
            }
        }
    }
}

extern "C" void kernel_launch(void* const* d_in, const int* in_sizes, int n_in,
                              void* d_out, int out_size, void* d_ws, size_t ws_size,
                              hipStream_t stream){
    const float* x     = (const float*)d_in[0];
    const float* cor   = (const float*)d_in[1];
    const float* q_w   = (const float*)d_in[2];
    const float* kv_w  = (const float*)d_in[3];
    const float* cor_w = (const float*)d_in[4];
    const float* kln_w = (const float*)d_in[5];
    const float* kln_b = (const float*)d_in[6];
    const float* vln_w = (const float*)d_in[7];
    const float* vln_b = (const float*)d_in[8];
    const float* corln_w = (const float*)d_in[9];
    const float* corln_b = (const float*)d_in[10];
    const float* op1_w = (const float*)d_in[11];
    const float* op1_b = (const float*)d_in[12];
    const float* op2_w = (const float*)d_in[13];
    const float* op2_b = (const float*)d_in[14];
    const float* om1_w = (const float*)d_in[15];
    const float* om1_b = (const float*)d_in[16];
    const float* om2_w = (const float*)d_in[17];
    const float* om2_b = (const float*)d_in[18];
    const float* n1_w  = (const float*)d_in[19];
    const float* n1_b  = (const float*)d_in[20];
    const float* n2_w  = (const float*)d_in[21];
    const float* n2_b  = (const float*)d_in[22];
    const float* fc1_w = (const float*)d_in[23];
    const float* fc1_b = (const float*)d_in[24];
    const float* dw_w  = (const float*)d_in[25];
    const float* dw_b  = (const float*)d_in[26];
    const float* fc2_w = (const float*)d_in[27];
    const float* fc2_b = (const float*)d_in[28];

    // workspace layout (floats)
    float* XN  = (float*)d_ws;                       // 65536*256
    float* Q   = XN  + (size_t)NTOK * 256;
    float* Kb  = Q   + (size_t)NTOK * 256;
    float* Vb  = Kb  + (size_t)NTOK * 256;
    float* CEF = Vb  + (size_t)NTOK * 256;           // 65536*128
    float* CE  = CEF + (size_t)NTOK * 128;
    float* TM  = CE  + (size_t)NTOK * 128;
    float* KTV = TM  + (size_t)NTOK * 128;           // 4*8*32*32
    float* KTC = KTV + 32768;                        // 4*8*32*16
    float* T1  = Kb;                                 // reuse after ktv/ktc consume K
    float* T2  = Vb;
    float* MH  = CE;                                 // motion hidden (CE dead after ktc)
    float* Y   = CEF;                                // spans CEF+CE (both dead by then)
    __hip_bfloat16* H1 = (__hip_bfloat16*)XN;        // spans XN + half of Q (dead)
    __hip_bfloat16* H2 = (__hip_bfloat16*)Kb;        // spans Kb + half of Vb (dead)
    float* xout = (float*)d_out;
    float* mout = xout + (size_t)NTOK * 256;

    // 1. xn = std_ln(x, norm1)
    stdln_kernel<<<NTOK, 256, 0, stream>>>(x, n1_w, n1_b, XN);
    // 2. q = xn @ q_w.T
    gemm_kernel<M_PLAIN, false, false, 256, 256><<<dim3(1024, 4), 256, 0, stream>>>(XN, q_w, nullptr, nullptr, Q, nullptr);
    // 3. kv = xr @ kv_w.T  (frame-half swapped rows), split into K,V
    gemm_kernel<M_KV, true, false, 256, 512><<<dim3(1024, 8), 256, 0, stream>>>(XN, kv_w, nullptr, nullptr, Kb, Vb);
    // 4. custom LN on K,V (per-head groups of 32)
    kvln_kernel<<<NTOK, 256, 0, stream>>>(Kb, Vb, kln_w, kln_b, vln_w, vln_b);
    // 5. ce_flat + custom LN on ce (groups of 16)
    ce_kernel<<<NTOK, 128, 0, stream>>>(cor, cor_w, corln_w, corln_b, CEF, CE);
    // 6. zero small accumulators
    hipMemsetAsync(KTV, 0, (32768 + 16384) * sizeof(float), stream);
    // 7-8. ktv, ktc reductions
    ktv_kernel<<<dim3(32, 8), 1024, 0, stream>>>(Kb, Vb, KTV);
    ktc_kernel<<<dim3(32, 8),  512, 0, stream>>>(Kb, CE, KTC);
    // 9. t = q@ktv + xn
    app_kernel<<<NTOK, 256, 0, stream>>>(Q, XN, KTV, T1);
    // 10. dm = q@ktc - ce_flat
    crev_kernel<<<NTOK, 128, 0, stream>>>(Q, KTC, CEF, TM);
    // 11. hidden = gelu(t @ op1.T + b)
    gemm_kernel<M_BIAS_GELU, false, false, 256, 256><<<dim3(1024, 4), 256, 0, stream>>>(T1, op1_w, op1_b, nullptr, T2, nullptr);
    // 12. x_back = (hidden @ op2.T + b) + 2*xn   (in place into XN)
    gemm_kernel<M_BIAS_ADD2, false, false, 256, 256><<<dim3(1024, 4), 256, 0, stream>>>(T2, op2_w, op2_b, XN, XN, nullptr);
    // 13. mh = gelu(dm @ om1.T + b)
    gemm_kernel<M_BIAS_GELU, false, false, 128, 128><<<dim3(1024, 2), 256, 0, stream>>>(TM, om1_w, om1_b, nullptr, MH, nullptr);
    // 14. motion = mh @ om2.T + b  -> output 1
    gemm_kernel<M_BIAS, false, false, 128, 128><<<dim3(1024, 2), 256, 0, stream>>>(MH, om2_w, om2_b, nullptr, mout, nullptr);
    // 15. y = std_ln(x_back, norm2)
    stdln_kernel<<<NTOK, 256, 0, stream>>>(XN, n2_w, n2_b, Y);
    // 16. h1 = y @ fc1.T + b  (bf16 store)
    gemm_kernel<M_BIAS_BF16, false, false, 256, 768><<<dim3(1024, 12), 256, 0, stream>>>(Y, fc1_w, fc1_b, nullptr, H1, nullptr);
    // 17. depthwise conv + bias + gelu
    dwconv_kernel<<<NTOK, 256, 0, stream>>>(H1, dw_w, dw_b, H2);
    // 18. x_out = h2 @ fc2.T + b + x  -> output 0
    gemm_kernel<M_BIAS_ADDX, false, true, 768, 256><<<dim3(1024, 4), 256, 0, stream>>>(H2, fc2_w, fc2_b, x, xout, nullptr);
}

// Round 2
// 845.504 us; speedup vs baseline: 3.3347x; 3.3347x over previous
//
#include <hip/hip_runtime.h>
#include <hip/hip_bf16.h>

#define NTOK 65536      // 4 * 16384 tokens

typedef __attribute__((ext_vector_type(4))) float f32x4;
typedef __attribute__((ext_vector_type(8))) short bf16x8;

__device__ __forceinline__ float gelu_f(float x){
    return 0.5f * x * (1.0f + erff(x * 0.70710678118654752440f));
}
__device__ __forceinline__ float bf2f(unsigned short u){
    union { unsigned int i; float f; } w; w.i = ((unsigned int)u) << 16; return w.f;
}
__device__ __forceinline__ unsigned short f2bf(float f){
    __hip_bfloat16 h = __float2bfloat16(f);
    return *reinterpret_cast<unsigned short*>(&h);
}

// ---------- weight fp32 -> bf16 conversion into contiguous Wb ----------
__global__ __launch_bounds__(256) void wconv_kernel(const float* __restrict__ q_w, const float* __restrict__ kv_w,
                                                    const float* __restrict__ op1_w, const float* __restrict__ op2_w,
                                                    const float* __restrict__ om1_w, const float* __restrict__ om2_w,
                                                    const float* __restrict__ fc1_w, const float* __restrict__ fc2_w,
                                                    unsigned short* __restrict__ Wb){
    size_t e = ((size_t)blockIdx.x * 256 + threadIdx.x) * 4;
    if (e >= 753664) return;
    const float* src; size_t off;
    if      (e <  65536){ src = q_w;   off = 0; }
    else if (e < 196608){ src = kv_w;  off = 65536; }
    else if (e < 262144){ src = op1_w; off = 196608; }
    else if (e < 327680){ src = op2_w; off = 262144; }
    else if (e < 344064){ src = om1_w; off = 327680; }
    else if (e < 360448){ src = om2_w; off = 344064; }
    else if (e < 557056){ src = fc1_w; off = 360448; }
    else                { src = fc2_w; off = 557056; }
    float4 v = *reinterpret_cast<const float4*>(src + (e - off));
    ushort4 o; o.x = f2bf(v.x); o.y = f2bf(v.y); o.z = f2bf(v.z); o.w = f2bf(v.w);
    *reinterpret_cast<ushort4*>(Wb + e) = o;
}

// ---------- std LayerNorm over 256 -> bf16 out ----------
template<bool BF16IN>
__global__ __launch_bounds__(256) void stdln_kernel(const void* __restrict__ Xp,
                                                    const float* __restrict__ w,
                                                    const float* __restrict__ b,
                                                    unsigned short* __restrict__ out){
    int r = blockIdx.x, c = threadIdx.x;
    size_t base = (size_t)r * 256;
    float v;
    if constexpr (BF16IN) v = bf2f(((const unsigned short*)Xp)[base + c]);
    else                  v = ((const float*)Xp)[base + c];
    float s = v;
    #pragma unroll
    for (int m = 1; m < 64; m <<= 1) s += __shfl_xor(s, m, 64);
    __shared__ float sm[8];
    int wid = c >> 6;
    if ((c & 63) == 0) sm[wid] = s;
    __syncthreads();
    float mean = (sm[0] + sm[1] + sm[2] + sm[3]) * (1.0f / 256.0f);
    float dv = v - mean;
    float ss = dv * dv;
    #pragma unroll
    for (int m = 1; m < 64; m <<= 1) ss += __shfl_xor(ss, m, 64);
    if ((c & 63) == 0) sm[4 + wid] = ss;
    __syncthreads();
    float var = (sm[4] + sm[5] + sm[6] + sm[7]) * (1.0f / 256.0f);
    out[base + c] = f2bf(w[c] * dv * rsqrtf(var + 1e-5f) + b[c]);
}

// ---------- custom LN (ddof=1, /(std+eps)) over 32-wide head groups, K and V in place (bf16) ----------
__global__ __launch_bounds__(256) void kvln_kernel(unsigned short* __restrict__ Kb, unsigned short* __restrict__ Vb,
                                                   const float* __restrict__ kw, const float* __restrict__ kbb,
                                                   const float* __restrict__ vw, const float* __restrict__ vbb){
    int r = blockIdx.x, c = threadIdx.x;
    size_t idx = (size_t)r * 256 + c;
    {
        float v = bf2f(Kb[idx]);
        float s = v;
        #pragma unroll
        for (int m = 1; m < 32; m <<= 1) s += __shfl_xor(s, m, 64);
        float mean = s * (1.0f / 32.0f);
        float dv = v - mean;
        float ss = dv * dv;
        #pragma unroll
        for (int m = 1; m < 32; m <<= 1) ss += __shfl_xor(ss, m, 64);
        float sd = sqrtf(ss * (1.0f / 31.0f));
        Kb[idx] = f2bf(kw[c] * dv / (sd + 1e-5f) + kbb[c]);
    }
    {
        float v = bf2f(Vb[idx]);
        float s = v;
        #pragma unroll
        for (int m = 1; m < 32; m <<= 1) s += __shfl_xor(s, m, 64);
        float mean = s * (1.0f / 32.0f);
        float dv = v - mean;
        float ss = dv * dv;
        #pragma unroll
        for (int m = 1; m < 32; m <<= 1) ss += __shfl_xor(ss, m, 64);
        float sd = sqrtf(ss * (1.0f / 31.0f));
        Vb[idx] = f2bf(vw[c] * dv / (sd + 1e-5f) + vbb[c]);
    }
}

// ---------- ce_flat = cor @ cor_w.T (K=2) fused with 16-wide-group custom LN ----------
__global__ __launch_bounds__(128) void ce_kernel(const float* __restrict__ cor,
                                                 const float* __restrict__ cor_w,
                                                 const float* __restrict__ cw, const float* __restrict__ cb,
                                                 unsigned short* __restrict__ CEF, unsigned short* __restrict__ CE){
    int r = blockIdx.x, m = threadIdx.x;  // 128 threads
    float c0 = cor[(size_t)r * 2 + 0];
    float c1 = cor[(size_t)r * 2 + 1];
    float v = c0 * cor_w[m * 2 + 0] + c1 * cor_w[m * 2 + 1];
    size_t idx = (size_t)r * 128 + m;
    CEF[idx] = f2bf(v);
    float s = v;
    #pragma unroll
    for (int mm = 1; mm < 16; mm <<= 1) s += __shfl_xor(s, mm, 64);
    float mean = s * (1.0f / 16.0f);
    float dv = v - mean;
    float ss = dv * dv;
    #pragma unroll
    for (int mm = 1; mm < 16; mm <<= 1) ss += __shfl_xor(ss, mm, 64);
    float sd = sqrtf(ss * (1.0f / 15.0f));
    CE[idx] = f2bf(cw[m] * dv / (sd + 1e-5f) + cb[m]);
}

// ---------- ktv[bh][d][e] = sum_n K[b,n,h*32+d] * V[b,n,h*32+e] / N  (LDS-tiled) ----------
__global__ __launch_bounds__(256) void ktv_kernel(const unsigned short* __restrict__ Kb,
                                                  const unsigned short* __restrict__ Vb,
                                                  float* __restrict__ KTV){
    int bh = blockIdx.x, b = bh >> 3, h = bh & 7;
    __shared__ float Ks[64][33];
    __shared__ float Vs[64][33];
    int t = threadIdx.x;
    int lr = t >> 2, lq = t & 3;
    int d0 = (t >> 4) * 2, e0 = (t & 15) * 2;
    float a00 = 0, a01 = 0, a10 = 0, a11 = 0;
    size_t base = ((size_t)b << 14) + (size_t)blockIdx.y * 1024;
    for (int n0 = 0; n0 < 1024; n0 += 64){
        const ushort4* kp = reinterpret_cast<const ushort4*>(Kb + (base + n0 + lr) * 256 + h * 32 + lq * 8);
        ushort4 ka = kp[0], kc = kp[1];
        const ushort4* vp = reinterpret_cast<const ushort4*>(Vb + (base + n0 + lr) * 256 + h * 32 + lq * 8);
        ushort4 va = vp[0], vc = vp[1];
        __syncthreads();
        Ks[lr][lq*8+0] = bf2f(ka.x); Ks[lr][lq*8+1] = bf2f(ka.y); Ks[lr][lq*8+2] = bf2f(ka.z); Ks[lr][lq*8+3] = bf2f(ka.w);
        Ks[lr][lq*8+4] = bf2f(kc.x); Ks[lr][lq*8+5] = bf2f(kc.y); Ks[lr][lq*8+6] = bf2f(kc.z); Ks[lr][lq*8+7] = bf2f(kc.w);
        Vs[lr][lq*8+0] = bf2f(va.x); Vs[lr][lq*8+1] = bf2f(va.y); Vs[lr][lq*8+2] = bf2f(va.z); Vs[lr][lq*8+3] = bf2f(va.w);
        Vs[lr][lq*8+4] = bf2f(vc.x); Vs[lr][lq*8+5] = bf2f(vc.y); Vs[lr][lq*8+6] = bf2f(vc.z); Vs[lr][lq*8+7] = bf2f(vc.w);
        __syncthreads();
        #pragma unroll 4
        for (int n = 0; n < 64; n++){
            float k0 = Ks[n][d0], k1 = Ks[n][d0+1];
            float v0 = Vs[n][e0], v1 = Vs[n][e0+1];
            a00 = fmaf(k0, v0, a00); a01 = fmaf(k0, v1, a01);
            a10 = fmaf(k1, v0, a10); a11 = fmaf(k1, v1, a11);
        }
    }
    const float sc = 1.0f / 16384.0f;
    float* o = KTV + (size_t)bh * 1024;
    atomicAdd(&o[(d0+0)*32 + e0+0], a00 * sc);
    atomicAdd(&o[(d0+0)*32 + e0+1], a01 * sc);
    atomicAdd(&o[(d0+1)*32 + e0+0], a10 * sc);
    atomicAdd(&o[(d0+1)*32 + e0+1], a11 * sc);
}

// ---------- ktc[bh][d][e] = sum_n K[b,n,h*32+d] * CE[b,n,h*16+e] / N ----------
__global__ __launch_bounds__(256) void ktc_kernel(const unsigned short* __restrict__ Kb,
                                                  const unsigned short* __restrict__ CE,
                                                  float* __restrict__ KTC){
    int bh = blockIdx.x, b = bh >> 3, h = bh & 7;
    __shared__ float Ks[64][33];
    __shared__ float Cs[64][17];
    int t = threadIdx.x;
    int lr = t >> 2, lq = t & 3;
    int d0 = (t >> 4) * 2, e = t & 15;
    float a0 = 0, a1 = 0;
    size_t base = ((size_t)b << 14) + (size_t)blockIdx.y * 1024;
    for (int n0 = 0; n0 < 1024; n0 += 64){
        const ushort4* kp = reinterpret_cast<const ushort4*>(Kb + (base + n0 + lr) * 256 + h * 32 + lq * 8);
        ushort4 ka = kp[0], kc = kp[1];
        ushort4 ca = *reinterpret_cast<const ushort4*>(CE + (base + n0 + lr) * 128 + h * 16 + lq * 4);
        __syncthreads();
        Ks[lr][lq*8+0] = bf2f(ka.x); Ks[lr][lq*8+1] = bf2f(ka.y); Ks[lr][lq*8+2] = bf2f(ka.z); Ks[lr][lq*8+3] = bf2f(ka.w);
        Ks[lr][lq*8+4] = bf2f(kc.x); Ks[lr][lq*8+5] = bf2f(kc.y); Ks[lr][lq*8+6] = bf2f(kc.z); Ks[lr][lq*8+7] = bf2f(kc.w);
        Cs[lr][lq*4+0] = bf2f(ca.x); Cs[lr][lq*4+1] = bf2f(ca.y); Cs[lr][lq*4+2] = bf2f(ca.z); Cs[lr][lq*4+3] = bf2f(ca.w);
        __syncthreads();
        #pragma unroll 4
        for (int n = 0; n < 64; n++){
            float c0 = Cs[n][e];
            a0 = fmaf(Ks[n][d0],   c0, a0);
            a1 = fmaf(Ks[n][d0+1], c0, a1);
        }
    }
    const float sc = 1.0f / 16384.0f;
    float* o = KTC + (size_t)bh * 512;
    atomicAdd(&o[(d0+0)*16 + e], a0 * sc);
    atomicAdd(&o[(d0+1)*16 + e], a1 * sc);
}

// ---------- t = q @ ktv + xn  (bf16) ----------
__global__ __launch_bounds__(256) void app_kernel(const unsigned short* __restrict__ Q,
                                                  const unsigned short* __restrict__ XN,
                                                  const float* __restrict__ KTV,
                                                  unsigned short* __restrict__ T1){
    int r = blockIdx.x, c = threadIdx.x;
    int b = r >> 14;
    __shared__ float qrow[256];
    size_t base = (size_t)r * 256;
    qrow[c] = bf2f(Q[base + c]);
    __syncthreads();
    int h = c >> 5, e = c & 31;
    const float* kt = KTV + (size_t)(b * 8 + h) * 1024 + e;
    float acc = 0.0f;
    #pragma unroll
    for (int d = 0; d < 32; d++) acc = fmaf(qrow[h * 32 + d], kt[d * 32], acc);
    T1[base + c] = f2bf(acc + bf2f(XN[base + c]));
}

// ---------- dm = q @ ktc - ce_flat  (bf16) ----------
__global__ __launch_bounds__(128) void crev_kernel(const unsigned short* __restrict__ Q,
                                                   const float* __restrict__ KTC,
                                                   const unsigned short* __restrict__ CEF,
                                                   unsigned short* __restrict__ TM){
    int r = blockIdx.x, c = threadIdx.x;   // c = m in 0..127
    int b = r >> 14;
    __shared__ float qrow[256];
    size_t qb = (size_t)r * 256;
    qrow[c] = bf2f(Q[qb + c]);
    qrow[c + 128] = bf2f(Q[qb + c + 128]);
    __syncthreads();
    int h = c >> 4, e = c & 15;
    const float* kt = KTC + (size_t)(b * 8 + h) * 512 + e;
    float acc = 0.0f;
    #pragma unroll
    for (int d = 0; d < 32; d++) acc = fmaf(qrow[h * 32 + d], kt[d * 16], acc);
    size_t idx = (size_t)r * 128 + c;
    TM[idx] = f2bf(acc - bf2f(CEF[idx]));
}

// ---------- depthwise 3x3 conv (SAME) + bias + gelu, channel-last bf16, ushort4-vectorized ----------
__global__ __launch_bounds__(192) void dwconv_kernel(const unsigned short* __restrict__ H1,
                                                     const float* __restrict__ dww,
                                                     const float* __restrict__ dwb,
                                                     unsigned short* __restrict__ H2){
    int p = blockIdx.x;
    int bb = p >> 14;
    int yy = (p >> 7) & 127;
    int xx = p & 127;
    int ch = threadIdx.x * 4;     // 192 threads * 4 = 768 channels
    float w[9][4];
    #pragma unroll
    for (int k = 0; k < 9; k++)
        #pragma unroll
        for (int j = 0; j < 4; j++) w[k][j] = dww[(ch + j) * 9 + k];
    float acc[4] = { dwb[ch], dwb[ch+1], dwb[ch+2], dwb[ch+3] };
    #pragma unroll
    for (int dy = -1; dy <= 1; dy++){
        int y2 = yy + dy; if ((unsigned)y2 > 127u) continue;
        #pragma unroll
        for (int dx = -1; dx <= 1; dx++){
            int x2 = xx + dx; if ((unsigned)x2 > 127u) continue;
            int k = (dy + 1) * 3 + (dx + 1);
            ushort4 u = *reinterpret_cast<const ushort4*>(H1 + ((size_t)((bb << 14) + (y2 << 7) + x2)) * 768 + ch);
            acc[0] = fmaf(bf2f(u.x), w[k][0], acc[0]);
            acc[1] = fmaf(bf2f(u.y), w[k][1], acc[1]);
            acc[2] = fmaf(bf2f(u.z), w[k][2], acc[2]);
            acc[3] = fmaf(bf2f(u.w), w[k][3], acc[3]);
        }
    }
    ushort4 o;
    o.x = f2bf(gelu_f(acc[0])); o.y = f2bf(gelu_f(acc[1]));
    o.z = f2bf(gelu_f(acc[2])); o.w = f2bf(gelu_f(acc[3]));
    *reinterpret_cast<ushort4*>(H2 + (size_t)p * 768 + ch) = o;
}

// ---------- bf16 MFMA GEMM: C[r][c] = dot(A[r,:K], W[c,:K]) + epilogue ----------
// m97 structure: 128x128 tile, BK=32, 4 waves, global_load_lds(16B), 16x mfma 16x16x32 per K-step.
// LDS slot-swizzle (s ^= (row>>1)&3) applied on the GLOBAL source (linear LDS dest) and on the read.
#define M_PLAIN     0
#define M_KV        1
#define M_BIAS_GELU 2
#define M_BIAS_ADD2 3
#define M_BIAS      4
#define M_BIAS_BF16 5
#define M_BIAS_ADDX 6

template<int MODE, bool SWAP, int K, int O>
__global__ __launch_bounds__(256) void mgemm(const unsigned short* __restrict__ A,
                                             const unsigned short* __restrict__ W,
                                             const float* __restrict__ bias,
                                             const void* __restrict__ add,
                                             void* __restrict__ out0,
                                             void* __restrict__ out1){
    __shared__ __align__(16) unsigned short As[128 * 32];
    __shared__ __align__(16) unsigned short Bs[128 * 32];
    const int t = threadIdx.x;
    const int lane = t & 63, wid = t >> 6;
    const int wm = wid >> 1, wn = wid & 1;
    const int row0 = blockIdx.x * 128;
    const int col0 = blockIdx.y * 128;
    f32x4 acc[4][4];
    #pragma unroll
    for (int i = 0; i < 4; i++)
        #pragma unroll
        for (int j = 0; j < 4; j++){ f32x4 z = {0.f, 0.f, 0.f, 0.f}; acc[i][j] = z; }

    const int lr = lane >> 2;   // staging row within 16-row wave stripe
    const int ls = lane & 3;    // physical 16B slot
    const int kq = lane >> 4;   // logical k-block for MFMA frags
    const int rr = lane & 15;

    for (int kb = 0; kb < K; kb += 32){
        #pragma unroll
        for (int i = 0; i < 2; i++){
            int r = i * 64 + wid * 16 + lr;
            int ko = ls ^ ((r >> 1) & 3);           // pre-swizzled global slot
            int ga = row0 + r;
            if (SWAP) ga ^= 32768;                  // (b+2)&3 == b^2 for 2-bit b
            const unsigned short* srcA = A + (size_t)ga * K + kb + ko * 8;
            __builtin_amdgcn_global_load_lds(
                (const __attribute__((address_space(1))) unsigned int*)srcA,
                (__attribute__((address_space(3))) unsigned int*)(As + (i * 64 + wid * 16) * 32),
                16, 0, 0);
            const unsigned short* srcB = W + (size_t)(col0 + r) * K + kb + ko * 8;
            __builtin_amdgcn_global_load_lds(
                (const __attribute__((address_space(1))) unsigned int*)srcB,
                (__attribute__((address_space(3))) unsigned int*)(Bs + (i * 64 + wid * 16) * 32),
                16, 0, 0);
        }
        __syncthreads();
        bf16x8 af[4], bfr[4];
        #pragma unroll
        for (int m = 0; m < 4; m++){
            int row = wm * 64 + m * 16 + rr;
            int s = kq ^ ((row >> 1) & 3);
            af[m] = *reinterpret_cast<const bf16x8*>(As + row * 32 + s * 8);
        }
        #pragma unroll
        for (int n = 0; n < 4; n++){
            int row = wn * 64 + n * 16 + rr;
            int s = kq ^ ((row >> 1) & 3);
            bfr[n] = *reinterpret_cast<const bf16x8*>(Bs + row * 32 + s * 8);
        }
        #pragma unroll
        for (int m = 0; m < 4; m++)
            #pragma unroll
            for (int n = 0; n < 4; n++)
                acc[m][n] = __builtin_amdgcn_mfma_f32_16x16x32_bf16(af[m], bfr[n], acc[m][n], 0, 0, 0);
        __syncthreads();
    }

    // epilogue: C frag layout col=lane&15, row=(lane>>4)*4+reg
    #pragma unroll
    for (int m = 0; m < 4; m++){
        #pragma unroll
        for (int n = 0; n < 4; n++){
            int col = col0 + wn * 64 + n * 16 + rr;
            int rbase = row0 + wm * 64 + m * 16 + kq * 4;
            #pragma unroll
            for (int j = 0; j < 4; j++){
                int r = rbase + j;
                float v = acc[m][n][j];
                size_t o = (size_t)r * O + col;
                if constexpr (MODE == M_PLAIN){
                    ((unsigned short*)out0)[o] = f2bf(v);
                } else if constexpr (MODE == M_KV){
                    if (col < 256) ((unsigned short*)out0)[(size_t)r * 256 + col] = f2bf(v);
                    else           ((unsigned short*)out1)[(size_t)r * 256 + col - 256] = f2bf(v);
                } else if constexpr (MODE == M_BIAS_GELU){
                    ((unsigned short*)out0)[o] = f2bf(gelu_f(v + bias[col]));
                } else if constexpr (MODE == M_BIAS_ADD2){
                    ((unsigned short*)out0)[o] = f2bf(v + bias[col] + 2.0f * bf2f(((const unsigned short*)add)[o]));
                } else if constexpr (MODE == M_BIAS){
                    ((float*)out0)[o] = v + bias[col];
                } else if constexpr (MODE == M_BIAS_BF16){
                    ((unsigned short*)out0)[o] = f2bf(v + bias[col]);
                } else if constexpr (MODE == M_BIAS_ADDX){
                    ((float*)out0)[o] = v + bias[col] + ((const float*)add)[o];
                }
            }
        }
    }
}

extern "C" void kernel_launch(void* const* d_in, const int* in_sizes, int n_in,
                              void* d_out, int out_size, void* d_ws, size_t ws_size,
                              hipStream_t stream){
    const float* x     = (const float*)d_in[0];
    const float* cor   = (const float*)d_in[1];
    const float* q_w   = (const float*)d_in[2];
    const float* kv_w  = (const float*)d_in[3];
    const float* cor_w = (const float*)d_in[4];
    const float* kln_w = (const float*)d_in[5];
    const float* kln_b = (const float*)d_in[6];
    const float* vln_w = (const float*)d_in[7];
    const float* vln_b = (const float*)d_in[8];
    const float* corln_w = (const float*)d_in[9];
    const float* corln_b = (const float*)d_in[10];
    const float* op1_w = (const float*)d_in[11];
    const float* op1_b = (const float*)d_in[12];
    const float* op2_w = (const float*)d_in[13];
    const float* op2_b = (const float*)d_in[14];
    const float* om1_w = (const float*)d_in[15];
    const float* om1_b = (const float*)d_in[16];
    const float* om2_w = (const float*)d_in[17];
    const float* om2_b = (const float*)d_in[18];
    const float* n1_w  = (const float*)d_in[19];
    const float* n1_b  = (const float*)d_in[20];
    const float* n2_w  = (const float*)d_in[21];
    const float* n2_b  = (const float*)d_in[22];
    const float* fc1_w = (const float*)d_in[23];
    const float* fc1_b = (const float*)d_in[24];
    const float* dw_w  = (const float*)d_in[25];
    const float* dw_b  = (const float*)d_in[26];
    const float* fc2_w = (const float*)d_in[27];
    const float* fc2_b = (const float*)d_in[28];

    // ---- workspace layout (bf16 elements unless noted) ----
    unsigned short* XN  = (unsigned short*)d_ws;           // NTOK*256
    unsigned short* Qb  = XN  + (size_t)NTOK * 256;
    unsigned short* Kb  = Qb  + (size_t)NTOK * 256;
    unsigned short* Vb  = Kb  + (size_t)NTOK * 256;
    unsigned short* CEF = Vb  + (size_t)NTOK * 256;        // NTOK*128
    unsigned short* CE  = CEF + (size_t)NTOK * 128;
    float* KTV = (float*)(CE + (size_t)NTOK * 128);        // 32768 f32
    float* KTC = KTV + 32768;                              // 16384 f32
    unsigned short* Wb  = (unsigned short*)(KTC + 16384);  // 753664 bf16 weights
    unsigned short* H2  = Wb + 753664;                     // NTOK*768
    // overlays (disjoint live ranges):
    unsigned short* T1 = Vb;      // live 10->12
    unsigned short* T2 = Kb;      // live 12->13
    unsigned short* XB = Qb;      // live 13->16
    unsigned short* Y  = Vb;      // live 16->17
    unsigned short* TM = CE;      // live 11->14
    unsigned short* MH = CEF;     // live 14->15
    unsigned short* H1 = XN;      // spans XN+Qb+Kb = NTOK*768, live 17->18
    float* xout = (float*)d_out;
    float* mout = xout + (size_t)NTOK * 256;

    // bf16 weight segment pointers within Wb
    unsigned short* w_q   = Wb + 0;
    unsigned short* w_kv  = Wb + 65536;
    unsigned short* w_op1 = Wb + 196608;
    unsigned short* w_op2 = Wb + 262144;
    unsigned short* w_om1 = Wb + 327680;
    unsigned short* w_om2 = Wb + 344064;
    unsigned short* w_fc1 = Wb + 360448;
    unsigned short* w_fc2 = Wb + 557056;

    // 0. weights -> bf16
    wconv_kernel<<<736, 256, 0, stream>>>(q_w, kv_w, op1_w, op2_w, om1_w, om2_w, fc1_w, fc2_w, Wb);
    // 1. xn = std_ln(x, norm1)
    stdln_kernel<false><<<NTOK, 256, 0, stream>>>(x, n1_w, n1_b, XN);
    // 2. q = xn @ q_w.T
    mgemm<M_PLAIN, false, 256, 256><<<dim3(512, 2), 256, 0, stream>>>(XN, w_q, nullptr, nullptr, Qb, nullptr);
    // 3. kv = xr @ kv_w.T (swapped rows), split K,V
    mgemm<M_KV, true, 256, 512><<<dim3(512, 4), 256, 0, stream>>>(XN, w_kv, nullptr, nullptr, Kb, Vb);
    // 4. custom LN on K,V
    kvln_kernel<<<NTOK, 256, 0, stream>>>(Kb, Vb, kln_w, kln_b, vln_w, vln_b);
    // 5. ce_flat + LN(ce)
    ce_kernel<<<NTOK, 128, 0, stream>>>(cor, cor_w, corln_w, corln_b, CEF, CE);
    // 6. zero accumulators
    hipMemsetAsync(KTV, 0, (32768 + 16384) * sizeof(float), stream);
    // 7-8. ktv, ktc
    ktv_kernel<<<dim3(32, 16), 256, 0, stream>>>(Kb, Vb, KTV);
    ktc_kernel<<<dim3(32, 16), 256, 0, stream>>>(Kb, CE, KTC);
    // 9. t = q@ktv + xn
    app_kernel<<<NTOK, 256, 0, stream>>>(Qb, XN, KTV, T1);
    // 10. dm = q@ktc - ce_flat
    crev_kernel<<<NTOK, 128, 0, stream>>>(Qb, KTC, CEF, TM);
    // 11. hidden = gelu(t @ op1.T + b)
    mgemm<M_BIAS_GELU, false, 256, 256><<<dim3(512, 2), 256, 0, stream>>>(T1, w_op1, op1_b, nullptr, T2, nullptr);
    // 12. x_back = (hidden @ op2.T + b) + 2*xn
    mgemm<M_BIAS_ADD2, false, 256, 256><<<dim3(512, 2), 256, 0, stream>>>(T2, w_op2, op2_b, XN, XB, nullptr);
    // 13. mh = gelu(dm @ om1.T + b)
    mgemm<M_BIAS_GELU, false, 128, 128><<<dim3(512, 1), 256, 0, stream>>>(TM, w_om1, om1_b, nullptr, MH, nullptr);
    // 14. motion = mh @ om2.T + b -> output 1 (fp32)
    mgemm<M_BIAS, false, 128, 128><<<dim3(512, 1), 256, 0, stream>>>(MH, w_om2, om2_b, nullptr, mout, nullptr);
    // 15. y = std_ln(x_back, norm2)
    stdln_kernel<true><<<NTOK, 256, 0, stream>>>(XB, n2_w, n2_b, Y);
    // 16. h1 = y @ fc1.T + b (bf16)
    mgemm<M_BIAS_BF16, false, 256, 768><<<dim3(512, 6), 256, 0, stream>>>(Y, w_fc1, fc1_b, nullptr, H1, nullptr);
    // 17. depthwise conv + bias + gelu
    dwconv_kernel<<<NTOK, 192, 0, stream>>>(H1, dw_w, dw_b, H2);
    // 18. x_out = h2 @ fc2.T + b + x -> output 0 (fp32)
    mgemm<M_BIAS_ADDX, false, 768, 256><<<dim3(512, 2), 256, 0, stream>>>(H2, w_fc2, fc2_b, x, xout, nullptr);
}

// Round 3
// 678.344 us; speedup vs baseline: 4.1564x; 1.2464x over previous
//
#include <hip/hip_runtime.h>
#include <hip/hip_bf16.h>

#define NTOK 65536      // 4 * 16384 tokens

typedef __attribute__((ext_vector_type(4))) float f32x4;
typedef __attribute__((ext_vector_type(8))) short bf16x8;

__device__ __forceinline__ float gelu_f(float x){
    return 0.5f * x * (1.0f + erff(x * 0.70710678118654752440f));
}
__device__ __forceinline__ float bf2f(unsigned short u){
    union { unsigned int i; float f; } w; w.i = ((unsigned int)u) << 16; return w.f;
}
__device__ __forceinline__ unsigned short f2bf(float f){
    __hip_bfloat16 h = __float2bfloat16(f);
    return *reinterpret_cast<unsigned short*>(&h);
}

// ---------- weight fp32 -> bf16 conversion into contiguous Wb ----------
__global__ __launch_bounds__(256) void wconv_kernel(const float* __restrict__ q_w, const float* __restrict__ kv_w,
                                                    const float* __restrict__ op1_w, const float* __restrict__ op2_w,
                                                    const float* __restrict__ om1_w, const float* __restrict__ om2_w,
                                                    const float* __restrict__ fc1_w, const float* __restrict__ fc2_w,
                                                    unsigned short* __restrict__ Wb){
    size_t e = ((size_t)blockIdx.x * 256 + threadIdx.x) * 4;
    if (e >= 753664) return;
    const float* src; size_t off;
    if      (e <  65536){ src = q_w;   off = 0; }
    else if (e < 196608){ src = kv_w;  off = 65536; }
    else if (e < 262144){ src = op1_w; off = 196608; }
    else if (e < 327680){ src = op2_w; off = 262144; }
    else if (e < 344064){ src = om1_w; off = 327680; }
    else if (e < 360448){ src = om2_w; off = 344064; }
    else if (e < 557056){ src = fc1_w; off = 360448; }
    else                { src = fc2_w; off = 557056; }
    float4 v = *reinterpret_cast<const float4*>(src + (e - off));
    ushort4 o; o.x = f2bf(v.x); o.y = f2bf(v.y); o.z = f2bf(v.z); o.w = f2bf(v.w);
    *reinterpret_cast<ushort4*>(Wb + e) = o;
}

// ---------- std LayerNorm over 256 -> bf16 out ----------
template<bool BF16IN>
__global__ __launch_bounds__(256) void stdln_kernel(const void* __restrict__ Xp,
                                                    const float* __restrict__ w,
                                                    const float* __restrict__ b,
                                                    unsigned short* __restrict__ out){
    int r = blockIdx.x, c = threadIdx.x;
    size_t base = (size_t)r * 256;
    float v;
    if constexpr (BF16IN) v = bf2f(((const unsigned short*)Xp)[base + c]);
    else                  v = ((const float*)Xp)[base + c];
    float s = v;
    #pragma unroll
    for (int m = 1; m < 64; m <<= 1) s += __shfl_xor(s, m, 64);
    __shared__ float sm[8];
    int wid = c >> 6;
    if ((c & 63) == 0) sm[wid] = s;
    __syncthreads();
    float mean = (sm[0] + sm[1] + sm[2] + sm[3]) * (1.0f / 256.0f);
    float dv = v - mean;
    float ss = dv * dv;
    #pragma unroll
    for (int m = 1; m < 64; m <<= 1) ss += __shfl_xor(ss, m, 64);
    if ((c & 63) == 0) sm[4 + wid] = ss;
    __syncthreads();
    float var = (sm[4] + sm[5] + sm[6] + sm[7]) * (1.0f / 256.0f);
    out[base + c] = f2bf(w[c] * dv * rsqrtf(var + 1e-5f) + b[c]);
}

// ---------- ce_flat = cor @ cor_w.T (K=2) ----------
__global__ __launch_bounds__(128) void ce_kernel(const float* __restrict__ cor,
                                                 const float* __restrict__ cor_w,
                                                 unsigned short* __restrict__ CEF){
    int r = blockIdx.x, m = threadIdx.x;  // 128 threads
    float c0 = cor[(size_t)r * 2 + 0];
    float c1 = cor[(size_t)r * 2 + 1];
    float v = c0 * cor_w[m * 2 + 0] + c1 * cor_w[m * 2 + 1];
    CEF[(size_t)r * 128 + m] = f2bf(v);
}

// ---------- fused: on-the-fly custom LN of K,V,CE + ktv & ktc reductions ----------
// ktv[bh][d][e] = sum_n LN(K)[n,d] * LN(V)[n,e] / N   (32x32)
// ktc[bh][d][e] = sum_n LN(K)[n,d] * LN(CE)[n,e] / N  (32x16)
__global__ __launch_bounds__(256) void ktvc_kernel(const unsigned short* __restrict__ Kb,
                                                   const unsigned short* __restrict__ Vb,
                                                   const unsigned short* __restrict__ CEF,
                                                   const float* __restrict__ kw, const float* __restrict__ kbb,
                                                   const float* __restrict__ vw, const float* __restrict__ vbb,
                                                   const float* __restrict__ cw, const float* __restrict__ cbb,
                                                   float* __restrict__ KTV, float* __restrict__ KTC){
    int bh = blockIdx.x, b = bh >> 3, h = bh & 7;
    __shared__ float Ks[64][33];
    __shared__ float Vs[64][33];
    __shared__ float Cs[64][17];
    int t = threadIdx.x;
    int lr = t >> 2, lq = t & 3;            // row within tile, quad slot
    int d0 = (t >> 4) * 2, e0 = (t & 15) * 2, e1 = t & 15;
    // LN params for this thread's channel slice (uniform across tiles)
    float kwr[8], kbr[8], vwr[8], vbr[8], cwr[4], cbr[4];
    #pragma unroll
    for (int j = 0; j < 8; j++){
        kwr[j] = kw[h * 32 + lq * 8 + j]; kbr[j] = kbb[h * 32 + lq * 8 + j];
        vwr[j] = vw[h * 32 + lq * 8 + j]; vbr[j] = vbb[h * 32 + lq * 8 + j];
    }
    #pragma unroll
    for (int j = 0; j < 4; j++){
        cwr[j] = cw[h * 16 + lq * 4 + j]; cbr[j] = cbb[h * 16 + lq * 4 + j];
    }
    float a00 = 0, a01 = 0, a10 = 0, a11 = 0;   // ktv accum
    float c0a = 0, c1a = 0;                     // ktc accum
    size_t base = ((size_t)b << 14) + (size_t)blockIdx.y * 1024;
    for (int n0 = 0; n0 < 1024; n0 += 64){
        size_t rowi = base + n0 + lr;
        const ushort4* kp = reinterpret_cast<const ushort4*>(Kb + rowi * 256 + h * 32 + lq * 8);
        ushort4 ka = kp[0], kc = kp[1];
        const ushort4* vp = reinterpret_cast<const ushort4*>(Vb + rowi * 256 + h * 32 + lq * 8);
        ushort4 va = vp[0], vc = vp[1];
        ushort4 ca = *reinterpret_cast<const ushort4*>(CEF + rowi * 128 + h * 16 + lq * 4);
        float kvv[8] = { bf2f(ka.x), bf2f(ka.y), bf2f(ka.z), bf2f(ka.w),
                         bf2f(kc.x), bf2f(kc.y), bf2f(kc.z), bf2f(kc.w) };
        float vvv[8] = { bf2f(va.x), bf2f(va.y), bf2f(va.z), bf2f(va.w),
                         bf2f(vc.x), bf2f(vc.y), bf2f(vc.z), bf2f(vc.w) };
        float cvv[4] = { bf2f(ca.x), bf2f(ca.y), bf2f(ca.z), bf2f(ca.w) };
        // --- LN K (32 ch over quad) ---
        float s = 0;
        #pragma unroll
        for (int j = 0; j < 8; j++) s += kvv[j];
        s += __shfl_xor(s, 1, 64); s += __shfl_xor(s, 2, 64);
        float mean = s * (1.0f / 32.0f);
        float ss = 0;
        #pragma unroll
        for (int j = 0; j < 8; j++){ kvv[j] -= mean; ss = fmaf(kvv[j], kvv[j], ss); }
        ss += __shfl_xor(ss, 1, 64); ss += __shfl_xor(ss, 2, 64);
        float inv = 1.0f / (sqrtf(ss * (1.0f / 31.0f)) + 1e-5f);
        #pragma unroll
        for (int j = 0; j < 8; j++) kvv[j] = fmaf(kwr[j] * kvv[j], inv, kbr[j]);
        // --- LN V ---
        s = 0;
        #pragma unroll
        for (int j = 0; j < 8; j++) s += vvv[j];
        s += __shfl_xor(s, 1, 64); s += __shfl_xor(s, 2, 64);
        mean = s * (1.0f / 32.0f);
        ss = 0;
        #pragma unroll
        for (int j = 0; j < 8; j++){ vvv[j] -= mean; ss = fmaf(vvv[j], vvv[j], ss); }
        ss += __shfl_xor(ss, 1, 64); ss += __shfl_xor(ss, 2, 64);
        inv = 1.0f / (sqrtf(ss * (1.0f / 31.0f)) + 1e-5f);
        #pragma unroll
        for (int j = 0; j < 8; j++) vvv[j] = fmaf(vwr[j] * vvv[j], inv, vbr[j]);
        // --- LN CE (16 ch over quad) ---
        s = 0;
        #pragma unroll
        for (int j = 0; j < 4; j++) s += cvv[j];
        s += __shfl_xor(s, 1, 64); s += __shfl_xor(s, 2, 64);
        mean = s * (1.0f / 16.0f);
        ss = 0;
        #pragma unroll
        for (int j = 0; j < 4; j++){ cvv[j] -= mean; ss = fmaf(cvv[j], cvv[j], ss); }
        ss += __shfl_xor(ss, 1, 64); ss += __shfl_xor(ss, 2, 64);
        inv = 1.0f / (sqrtf(ss * (1.0f / 15.0f)) + 1e-5f);
        #pragma unroll
        for (int j = 0; j < 4; j++) cvv[j] = fmaf(cwr[j] * cvv[j], inv, cbr[j]);
        __syncthreads();
        #pragma unroll
        for (int j = 0; j < 8; j++){ Ks[lr][lq * 8 + j] = kvv[j]; Vs[lr][lq * 8 + j] = vvv[j]; }
        #pragma unroll
        for (int j = 0; j < 4; j++) Cs[lr][lq * 4 + j] = cvv[j];
        __syncthreads();
        #pragma unroll 4
        for (int n = 0; n < 64; n++){
            float k0 = Ks[n][d0], k1 = Ks[n][d0 + 1];
            float v0 = Vs[n][e0], v1 = Vs[n][e0 + 1];
            float ce = Cs[n][e1];
            a00 = fmaf(k0, v0, a00); a01 = fmaf(k0, v1, a01);
            a10 = fmaf(k1, v0, a10); a11 = fmaf(k1, v1, a11);
            c0a = fmaf(k0, ce, c0a); c1a = fmaf(k1, ce, c1a);
        }
    }
    const float sc = 1.0f / 16384.0f;
    float* o = KTV + (size_t)bh * 1024;
    atomicAdd(&o[(d0 + 0) * 32 + e0 + 0], a00 * sc);
    atomicAdd(&o[(d0 + 0) * 32 + e0 + 1], a01 * sc);
    atomicAdd(&o[(d0 + 1) * 32 + e0 + 0], a10 * sc);
    atomicAdd(&o[(d0 + 1) * 32 + e0 + 1], a11 * sc);
    float* o2 = KTC + (size_t)bh * 512;
    atomicAdd(&o2[(d0 + 0) * 16 + e1], c0a * sc);
    atomicAdd(&o2[(d0 + 1) * 16 + e1], c1a * sc);
}

// ---------- merged: t = q@ktv + xn ; dm = q@ktc - ce_flat ----------
__global__ __launch_bounds__(256) void attn_out_kernel(const unsigned short* __restrict__ Q,
                                                       const unsigned short* __restrict__ XN,
                                                       const float* __restrict__ KTV,
                                                       const float* __restrict__ KTC,
                                                       const unsigned short* __restrict__ CEF,
                                                       unsigned short* __restrict__ T1,
                                                       unsigned short* __restrict__ TM){
    int r = blockIdx.x, c = threadIdx.x;
    int b = r >> 14;
    __shared__ float qrow[256];
    size_t base = (size_t)r * 256;
    qrow[c] = bf2f(Q[base + c]);
    __syncthreads();
    {
        int h = c >> 5, e = c & 31;
        const float* kt = KTV + (size_t)(b * 8 + h) * 1024 + e;
        float acc = 0.0f;
        #pragma unroll
        for (int d = 0; d < 32; d++) acc = fmaf(qrow[h * 32 + d], kt[d * 32], acc);
        T1[base + c] = f2bf(acc + bf2f(XN[base + c]));
    }
    if (c < 128){
        int h = c >> 4, e = c & 15;
        const float* kt = KTC + (size_t)(b * 8 + h) * 512 + e;
        float acc = 0.0f;
        #pragma unroll
        for (int d = 0; d < 32; d++) acc = fmaf(qrow[h * 32 + d], kt[d * 16], acc);
        size_t idx = (size_t)r * 128 + c;
        TM[idx] = f2bf(acc - bf2f(CEF[idx]));
    }
}

// ---------- depthwise 3x3 conv (SAME) + bias + gelu, row-stationary sliding window ----------
// block = (b, y, xhalf); 192 threads * 4 ch = 768. Weights in regs, 3 loads/pixel, 1-col prefetch.
__global__ __launch_bounds__(192) void dwconv_kernel(const unsigned short* __restrict__ H1,
                                                     const float* __restrict__ dww,
                                                     const float* __restrict__ dwb,
                                                     unsigned short* __restrict__ H2){
    int blk = blockIdx.x;
    int bb = blk >> 8;
    int yy = (blk >> 1) & 127;
    int xh = blk & 1;
    int x0 = xh * 64;
    int ch = threadIdx.x * 4;
    float w[9][4];
    #pragma unroll
    for (int k = 0; k < 9; k++)
        #pragma unroll
        for (int j = 0; j < 4; j++) w[k][j] = dww[(ch + j) * 9 + k];
    float bias[4] = { dwb[ch], dwb[ch+1], dwb[ch+2], dwb[ch+3] };
    const bool r0v = (yy > 0), r2v = (yy < 127);
    size_t rowbase[3];
    rowbase[0] = ((size_t)((bb << 14) + ((yy - 1) << 7))) * 768 + ch;
    rowbase[1] = ((size_t)((bb << 14) + ( yy      << 7))) * 768 + ch;
    rowbase[2] = ((size_t)((bb << 14) + ((yy + 1) << 7))) * 768 + ch;
    size_t obase = ((size_t)((bb << 14) + (yy << 7))) * 768 + ch;

    float A[3][4], B[3][4], C[3][4], D[3][4];
    #define LOADCOL(DST, XX) do {                                             \
        int _x = (XX);                                                        \
        bool xv = ((unsigned)_x <= 127u);                                     \
        ushort4 u0 = (xv && r0v) ? *reinterpret_cast<const ushort4*>(H1 + rowbase[0] + (size_t)_x * 768) : ushort4{0,0,0,0}; \
        ushort4 u1 = (xv)        ? *reinterpret_cast<const ushort4*>(H1 + rowbase[1] + (size_t)_x * 768) : ushort4{0,0,0,0}; \
        ushort4 u2 = (xv && r2v) ? *reinterpret_cast<const ushort4*>(H1 + rowbase[2] + (size_t)_x * 768) : ushort4{0,0,0,0}; \
        DST[0][0] = bf2f(u0.x); DST[0][1] = bf2f(u0.y); DST[0][2] = bf2f(u0.z); DST[0][3] = bf2f(u0.w); \
        DST[1][0] = bf2f(u1.x); DST[1][1] = bf2f(u1.y); DST[1][2] = bf2f(u1.z); DST[1][3] = bf2f(u1.w); \
        DST[2][0] = bf2f(u2.x); DST[2][1] = bf2f(u2.y); DST[2][2] = bf2f(u2.z); DST[2][3] = bf2f(u2.w); \
    } while (0)

    #define EMIT(CA, CB, CC, XX) do {                                         \
        float acc[4];                                                         \
        _Pragma("unroll")                                                     \
        for (int j = 0; j < 4; j++){                                          \
            acc[j] = bias[j];                                                 \
            acc[j] = fmaf(CA[0][j], w[0][j], acc[j]);                         \
            acc[j] = fmaf(CB[0][j], w[1][j], acc[j]);                         \
            acc[j] = fmaf(CC[0][j], w[2][j], acc[j]);                         \
            acc[j] = fmaf(CA[1][j], w[3][j], acc[j]);                         \
            acc[j] = fmaf(CB[1][j], w[4][j], acc[j]);                         \
            acc[j] = fmaf(CC[1][j], w[5][j], acc[j]);                         \
            acc[j] = fmaf(CA[2][j], w[6][j], acc[j]);                         \
            acc[j] = fmaf(CB[2][j], w[7][j], acc[j]);                         \
            acc[j] = fmaf(CC[2][j], w[8][j], acc[j]);                         \
        }                                                                     \
        ushort4 o;                                                            \
        o.x = f2bf(gelu_f(acc[0])); o.y = f2bf(gelu_f(acc[1]));               \
        o.z = f2bf(gelu_f(acc[2])); o.w = f2bf(gelu_f(acc[3]));               \
        *reinterpret_cast<ushort4*>(H2 + obase + (size_t)(XX) * 768) = o;     \
    } while (0)

    LOADCOL(A, x0 - 1);
    LOADCOL(B, x0);
    LOADCOL(C, x0 + 1);
    int xcur = x0;
    #pragma unroll 1
    for (int g = 0; g < 16; g++){
        LOADCOL(D, xcur + 2); EMIT(A, B, C, xcur); xcur++;
        LOADCOL(A, xcur + 2); EMIT(B, C, D, xcur); xcur++;
        LOADCOL(B, xcur + 2); EMIT(C, D, A, xcur); xcur++;
        LOADCOL(C, xcur + 2); EMIT(D, A, B, xcur); xcur++;
    }
    #undef LOADCOL
    #undef EMIT
}

// ---------- bf16 MFMA GEMM: C[r][c] = dot(A[r,:K], W[c,:K]) + epilogue ----------
#define M_PLAIN     0
#define M_KV        1
#define M_BIAS_GELU 2
#define M_BIAS_ADD2 3
#define M_BIAS      4
#define M_BIAS_BF16 5
#define M_BIAS_ADDX 6

template<int MODE, bool SWAP, int K, int O>
__global__ __launch_bounds__(256) void mgemm(const unsigned short* __restrict__ A,
                                             const unsigned short* __restrict__ W,
                                             const float* __restrict__ bias,
                                             const void* __restrict__ add,
                                             void* __restrict__ out0,
                                             void* __restrict__ out1){
    __shared__ __align__(16) unsigned short As[128 * 32];
    __shared__ __align__(16) unsigned short Bs[128 * 32];
    const int t = threadIdx.x;
    const int lane = t & 63, wid = t >> 6;
    const int wm = wid >> 1, wn = wid & 1;
    const int row0 = blockIdx.x * 128;
    const int col0 = blockIdx.y * 128;
    f32x4 acc[4][4];
    #pragma unroll
    for (int i = 0; i < 4; i++)
        #pragma unroll
        for (int j = 0; j < 4; j++){ f32x4 z = {0.f, 0.f, 0.f, 0.f}; acc[i][j] = z; }

    const int lr = lane >> 2;
    const int ls = lane & 3;
    const int kq = lane >> 4;
    const int rr = lane & 15;

    for (int kb = 0; kb < K; kb += 32){
        #pragma unroll
        for (int i = 0; i < 2; i++){
            int r = i * 64 + wid * 16 + lr;
            int ko = ls ^ ((r >> 1) & 3);
            int ga = row0 + r;
            if (SWAP) ga ^= 32768;
            const unsigned short* srcA = A + (size_t)ga * K + kb + ko * 8;
            __builtin_amdgcn_global_load_lds(
                (const __attribute__((address_space(1))) unsigned int*)srcA,
                (__attribute__((address_space(3))) unsigned int*)(As + (i * 64 + wid * 16) * 32),
                16, 0, 0);
            const unsigned short* srcB = W + (size_t)(col0 + r) * K + kb + ko * 8;
            __builtin_amdgcn_global_load_lds(
                (const __attribute__((address_space(1))) unsigned int*)srcB,
                (__attribute__((address_space(3))) unsigned int*)(Bs + (i * 64 + wid * 16) * 32),
                16, 0, 0);
        }
        __syncthreads();
        bf16x8 af[4], bfr[4];
        #pragma unroll
        for (int m = 0; m < 4; m++){
            int row = wm * 64 + m * 16 + rr;
            int s = kq ^ ((row >> 1) & 3);
            af[m] = *reinterpret_cast<const bf16x8*>(As + row * 32 + s * 8);
        }
        #pragma unroll
        for (int n = 0; n < 4; n++){
            int row = wn * 64 + n * 16 + rr;
            int s = kq ^ ((row >> 1) & 3);
            bfr[n] = *reinterpret_cast<const bf16x8*>(Bs + row * 32 + s * 8);
        }
        #pragma unroll
        for (int m = 0; m < 4; m++)
            #pragma unroll
            for (int n = 0; n < 4; n++)
                acc[m][n] = __builtin_amdgcn_mfma_f32_16x16x32_bf16(af[m], bfr[n], acc[m][n], 0, 0, 0);
        __syncthreads();
    }

    #pragma unroll
    for (int m = 0; m < 4; m++){
        #pragma unroll
        for (int n = 0; n < 4; n++){
            int col = col0 + wn * 64 + n * 16 + rr;
            int rbase = row0 + wm * 64 + m * 16 + kq * 4;
            #pragma unroll
            for (int j = 0; j < 4; j++){
                int r = rbase + j;
                float v = acc[m][n][j];
                size_t o = (size_t)r * O + col;
                if constexpr (MODE == M_PLAIN){
                    ((unsigned short*)out0)[o] = f2bf(v);
                } else if constexpr (MODE == M_KV){
                    if (col < 256) ((unsigned short*)out0)[(size_t)r * 256 + col] = f2bf(v);
                    else           ((unsigned short*)out1)[(size_t)r * 256 + col - 256] = f2bf(v);
                } else if constexpr (MODE == M_BIAS_GELU){
                    ((unsigned short*)out0)[o] = f2bf(gelu_f(v + bias[col]));
                } else if constexpr (MODE == M_BIAS_ADD2){
                    ((unsigned short*)out0)[o] = f2bf(v + bias[col] + 2.0f * bf2f(((const unsigned short*)add)[o]));
                } else if constexpr (MODE == M_BIAS){
                    ((float*)out0)[o] = v + bias[col];
                } else if constexpr (MODE == M_BIAS_BF16){
                    ((unsigned short*)out0)[o] = f2bf(v + bias[col]);
                } else if constexpr (MODE == M_BIAS_ADDX){
                    ((float*)out0)[o] = v + bias[col] + ((const float*)add)[o];
                }
            }
        }
    }
}

extern "C" void kernel_launch(void* const* d_in, const int* in_sizes, int n_in,
                              void* d_out, int out_size, void* d_ws, size_t ws_size,
                              hipStream_t stream){
    const float* x     = (const float*)d_in[0];
    const float* cor   = (const float*)d_in[1];
    const float* q_w   = (const float*)d_in[2];
    const float* kv_w  = (const float*)d_in[3];
    const float* cor_w = (const float*)d_in[4];
    const float* kln_w = (const float*)d_in[5];
    const float* kln_b = (const float*)d_in[6];
    const float* vln_w = (const float*)d_in[7];
    const float* vln_b = (const float*)d_in[8];
    const float* corln_w = (const float*)d_in[9];
    const float* corln_b = (const float*)d_in[10];
    const float* op1_w = (const float*)d_in[11];
    const float* op1_b = (const float*)d_in[12];
    const float* op2_w = (const float*)d_in[13];
    const float* op2_b = (const float*)d_in[14];
    const float* om1_w = (const float*)d_in[15];
    const float* om1_b = (const float*)d_in[16];
    const float* om2_w = (const float*)d_in[17];
    const float* om2_b = (const float*)d_in[18];
    const float* n1_w  = (const float*)d_in[19];
    const float* n1_b  = (const float*)d_in[20];
    const float* n2_w  = (const float*)d_in[21];
    const float* n2_b  = (const float*)d_in[22];
    const float* fc1_w = (const float*)d_in[23];
    const float* fc1_b = (const float*)d_in[24];
    const float* dw_w  = (const float*)d_in[25];
    const float* dw_b  = (const float*)d_in[26];
    const float* fc2_w = (const float*)d_in[27];
    const float* fc2_b = (const float*)d_in[28];

    // ---- workspace layout (bf16 elements unless noted) ----
    unsigned short* XN  = (unsigned short*)d_ws;           // NTOK*256
    unsigned short* Qb  = XN  + (size_t)NTOK * 256;
    unsigned short* Kb  = Qb  + (size_t)NTOK * 256;
    unsigned short* Vb  = Kb  + (size_t)NTOK * 256;
    unsigned short* CEF = Vb  + (size_t)NTOK * 256;        // NTOK*128
    unsigned short* CE  = CEF + (size_t)NTOK * 128;        // (unused this round)
    float* KTV = (float*)(CE + (size_t)NTOK * 128);        // 32768 f32
    float* KTC = KTV + 32768;                              // 16384 f32
    unsigned short* Wb  = (unsigned short*)(KTC + 16384);  // 753664 bf16 weights
    unsigned short* H2  = Wb + 753664;                     // NTOK*768
    // overlays (disjoint live ranges):
    unsigned short* T1 = Vb;      // written after ktvc consumes Vb
    unsigned short* T2 = Kb;
    unsigned short* XB = Qb;
    unsigned short* Y  = Vb;
    unsigned short* TM = CE;
    unsigned short* MH = CEF;
    unsigned short* H1 = XN;      // spans XN+Qb+Kb = NTOK*768
    float* xout = (float*)d_out;
    float* mout = xout + (size_t)NTOK * 256;

    unsigned short* w_q   = Wb + 0;
    unsigned short* w_kv  = Wb + 65536;
    unsigned short* w_op1 = Wb + 196608;
    unsigned short* w_op2 = Wb + 262144;
    unsigned short* w_om1 = Wb + 327680;
    unsigned short* w_om2 = Wb + 344064;
    unsigned short* w_fc1 = Wb + 360448;
    unsigned short* w_fc2 = Wb + 557056;

    // 0. weights -> bf16
    wconv_kernel<<<736, 256, 0, stream>>>(q_w, kv_w, op1_w, op2_w, om1_w, om2_w, fc1_w, fc2_w, Wb);
    // 1. xn = std_ln(x, norm1)
    stdln_kernel<false><<<NTOK, 256, 0, stream>>>(x, n1_w, n1_b, XN);
    // 2. q = xn @ q_w.T
    mgemm<M_PLAIN, false, 256, 256><<<dim3(512, 2), 256, 0, stream>>>(XN, w_q, nullptr, nullptr, Qb, nullptr);
    // 3. kv = xr @ kv_w.T (swapped rows), split K,V  (UN-normalized)
    mgemm<M_KV, true, 256, 512><<<dim3(512, 4), 256, 0, stream>>>(XN, w_kv, nullptr, nullptr, Kb, Vb);
    // 4. ce_flat
    ce_kernel<<<NTOK, 128, 0, stream>>>(cor, cor_w, CEF);
    // 5. zero accumulators
    hipMemsetAsync(KTV, 0, (32768 + 16384) * sizeof(float), stream);
    // 6. fused LN + ktv + ktc
    ktvc_kernel<<<dim3(32, 16), 256, 0, stream>>>(Kb, Vb, CEF, kln_w, kln_b, vln_w, vln_b,
                                                  corln_w, corln_b, KTV, KTC);
    // 7. t = q@ktv + xn ; dm = q@ktc - ce_flat
    attn_out_kernel<<<NTOK, 256, 0, stream>>>(Qb, XN, KTV, KTC, CEF, T1, TM);
    // 8. hidden = gelu(t @ op1.T + b)
    mgemm<M_BIAS_GELU, false, 256, 256><<<dim3(512, 2), 256, 0, stream>>>(T1, w_op1, op1_b, nullptr, T2, nullptr);
    // 9. x_back = (hidden @ op2.T + b) + 2*xn
    mgemm<M_BIAS_ADD2, false, 256, 256><<<dim3(512, 2), 256, 0, stream>>>(T2, w_op2, op2_b, XN, XB, nullptr);
    // 10. mh = gelu(dm @ om1.T + b)
    mgemm<M_BIAS_GELU, false, 128, 128><<<dim3(512, 1), 256, 0, stream>>>(TM, w_om1, om1_b, nullptr, MH, nullptr);
    // 11. motion = mh @ om2.T + b -> output 1 (fp32)
    mgemm<M_BIAS, false, 128, 128><<<dim3(512, 1), 256, 0, stream>>>(MH, w_om2, om2_b, nullptr, mout, nullptr);
    // 12. y = std_ln(x_back, norm2)
    stdln_kernel<true><<<NTOK, 256, 0, stream>>>(XB, n2_w, n2_b, Y);
    // 13. h1 = y @ fc1.T + b (bf16)
    mgemm<M_BIAS_BF16, false, 256, 768><<<dim3(512, 6), 256, 0, stream>>>(Y, w_fc1, fc1_b, nullptr, H1, nullptr);
    // 14. depthwise conv + bias + gelu (row-stationary)
    dwconv_kernel<<<1024, 192, 0, stream>>>(H1, dw_w, dw_b, H2);
    // 15. x_out = h2 @ fc2.T + b + x -> output 0 (fp32)
    mgemm<M_BIAS_ADDX, false, 768, 256><<<dim3(512, 2), 256, 0, stream>>>(H2, w_fc2, fc2_b, x, xout, nullptr);
}

// Round 4
// 546.963 us; speedup vs baseline: 5.1548x; 1.2402x over previous
//
#include <hip/hip_runtime.h>
#include <hip/hip_bf16.h>

#define NTOK 65536      // 4 * 16384 tokens

typedef __attribute__((ext_vector_type(4))) float f32x4;
typedef __attribute__((ext_vector_type(8))) short bf16x8;

__device__ __forceinline__ float gelu_f(float x){
    return 0.5f * x * (1.0f + erff(x * 0.70710678118654752440f));
}
__device__ __forceinline__ float bf2f(unsigned short u){
    union { unsigned int i; float f; } w; w.i = ((unsigned int)u) << 16; return w.f;
}
__device__ __forceinline__ unsigned short f2bf(float f){
    __hip_bfloat16 h = __float2bfloat16(f);
    return *reinterpret_cast<unsigned short*>(&h);
}

// ---------- weight fp32 -> bf16 conversion into contiguous Wb ----------
__global__ __launch_bounds__(256) void wconv_kernel(const float* __restrict__ q_w, const float* __restrict__ kv_w,
                                                    const float* __restrict__ op1_w, const float* __restrict__ op2_w,
                                                    const float* __restrict__ om1_w, const float* __restrict__ om2_w,
                                                    const float* __restrict__ fc1_w, const float* __restrict__ fc2_w,
                                                    unsigned short* __restrict__ Wb){
    size_t e = ((size_t)blockIdx.x * 256 + threadIdx.x) * 4;
    if (e >= 753664) return;
    const float* src; size_t off;
    if      (e <  65536){ src = q_w;   off = 0; }
    else if (e < 196608){ src = kv_w;  off = 65536; }
    else if (e < 262144){ src = op1_w; off = 196608; }
    else if (e < 327680){ src = op2_w; off = 262144; }
    else if (e < 344064){ src = om1_w; off = 327680; }
    else if (e < 360448){ src = om2_w; off = 344064; }
    else if (e < 557056){ src = fc1_w; off = 360448; }
    else                { src = fc2_w; off = 557056; }
    float4 v = *reinterpret_cast<const float4*>(src + (e - off));
    ushort4 o; o.x = f2bf(v.x); o.y = f2bf(v.y); o.z = f2bf(v.z); o.w = f2bf(v.w);
    *reinterpret_cast<ushort4*>(Wb + e) = o;
}

// ---------- std LayerNorm over 256 -> bf16 out; wave-per-token, 8 tokens/wave ----------
template<bool BF16IN>
__global__ __launch_bounds__(256) void stdln_kernel(const void* __restrict__ Xp,
                                                    const float* __restrict__ w,
                                                    const float* __restrict__ b,
                                                    unsigned short* __restrict__ out){
    int wv = threadIdx.x >> 6, lane = threadIdx.x & 63;
    int tok0 = (blockIdx.x * 4 + wv) * 8;
    int c0 = lane * 4;
    float4 w4 = *reinterpret_cast<const float4*>(w + c0);
    float4 b4 = *reinterpret_cast<const float4*>(b + c0);
    #pragma unroll 2
    for (int j = 0; j < 8; j++){
        size_t base = (size_t)(tok0 + j) * 256 + c0;
        float v[4];
        if constexpr (BF16IN){
            ushort4 u = *reinterpret_cast<const ushort4*>((const unsigned short*)Xp + base);
            v[0] = bf2f(u.x); v[1] = bf2f(u.y); v[2] = bf2f(u.z); v[3] = bf2f(u.w);
        } else {
            float4 f = *reinterpret_cast<const float4*>((const float*)Xp + base);
            v[0] = f.x; v[1] = f.y; v[2] = f.z; v[3] = f.w;
        }
        float s = v[0] + v[1] + v[2] + v[3];
        #pragma unroll
        for (int m = 1; m < 64; m <<= 1) s += __shfl_xor(s, m, 64);
        float mean = s * (1.0f / 256.0f);
        float ss = 0;
        #pragma unroll
        for (int k = 0; k < 4; k++){ v[k] -= mean; ss = fmaf(v[k], v[k], ss); }
        #pragma unroll
        for (int m = 1; m < 64; m <<= 1) ss += __shfl_xor(ss, m, 64);
        float inv = rsqrtf(ss * (1.0f / 256.0f) + 1e-5f);
        ushort4 o;
        o.x = f2bf(w4.x * v[0] * inv + b4.x);
        o.y = f2bf(w4.y * v[1] * inv + b4.y);
        o.z = f2bf(w4.z * v[2] * inv + b4.z);
        o.w = f2bf(w4.w * v[3] * inv + b4.w);
        *reinterpret_cast<ushort4*>(out + base) = o;
    }
}

// ---------- ce_flat = cor @ cor_w.T (K=2), token-blocked ----------
__global__ __launch_bounds__(256) void ce_kernel(const float* __restrict__ cor,
                                                 const float* __restrict__ cor_w,
                                                 unsigned short* __restrict__ CEF){
    int m = threadIdx.x & 127, half = threadIdx.x >> 7;
    float w0 = cor_w[m * 2 + 0], w1 = cor_w[m * 2 + 1];
    #pragma unroll 4
    for (int it = 0; it < 16; it++){
        int tok = blockIdx.x * 32 + it * 2 + half;
        float c0 = cor[(size_t)tok * 2 + 0];
        float c1 = cor[(size_t)tok * 2 + 1];
        CEF[(size_t)tok * 128 + m] = f2bf(c0 * w0 + c1 * w1);
    }
}

// ---------- fused: on-the-fly custom LN of K,V,CE + ktv & ktc reductions ----------
__global__ __launch_bounds__(256) void ktvc_kernel(const unsigned short* __restrict__ Kb,
                                                   const unsigned short* __restrict__ Vb,
                                                   const unsigned short* __restrict__ CEF,
                                                   const float* __restrict__ kw, const float* __restrict__ kbb,
                                                   const float* __restrict__ vw, const float* __restrict__ vbb,
                                                   const float* __restrict__ cw, const float* __restrict__ cbb,
                                                   float* __restrict__ KTV, float* __restrict__ KTC){
    int bh = blockIdx.x, b = bh >> 3, h = bh & 7;
    __shared__ float Ks[64][33];
    __shared__ float Vs[64][33];
    __shared__ float Cs[64][17];
    int t = threadIdx.x;
    int lr = t >> 2, lq = t & 3;
    int d0 = (t >> 4) * 2, e0 = (t & 15) * 2, e1 = t & 15;
    float kwr[8], kbr[8], vwr[8], vbr[8], cwr[4], cbr[4];
    #pragma unroll
    for (int j = 0; j < 8; j++){
        kwr[j] = kw[h * 32 + lq * 8 + j]; kbr[j] = kbb[h * 32 + lq * 8 + j];
        vwr[j] = vw[h * 32 + lq * 8 + j]; vbr[j] = vbb[h * 32 + lq * 8 + j];
    }
    #pragma unroll
    for (int j = 0; j < 4; j++){
        cwr[j] = cw[h * 16 + lq * 4 + j]; cbr[j] = cbb[h * 16 + lq * 4 + j];
    }
    float a00 = 0, a01 = 0, a10 = 0, a11 = 0;
    float c0a = 0, c1a = 0;
    size_t base = ((size_t)b << 14) + (size_t)blockIdx.y * 1024;
    for (int n0 = 0; n0 < 1024; n0 += 64){
        size_t rowi = base + n0 + lr;
        const ushort4* kp = reinterpret_cast<const ushort4*>(Kb + rowi * 256 + h * 32 + lq * 8);
        ushort4 ka = kp[0], kc = kp[1];
        const ushort4* vp = reinterpret_cast<const ushort4*>(Vb + rowi * 256 + h * 32 + lq * 8);
        ushort4 va = vp[0], vc = vp[1];
        ushort4 ca = *reinterpret_cast<const ushort4*>(CEF + rowi * 128 + h * 16 + lq * 4);
        float kvv[8] = { bf2f(ka.x), bf2f(ka.y), bf2f(ka.z), bf2f(ka.w),
                         bf2f(kc.x), bf2f(kc.y), bf2f(kc.z), bf2f(kc.w) };
        float vvv[8] = { bf2f(va.x), bf2f(va.y), bf2f(va.z), bf2f(va.w),
                         bf2f(vc.x), bf2f(vc.y), bf2f(vc.z), bf2f(vc.w) };
        float cvv[4] = { bf2f(ca.x), bf2f(ca.y), bf2f(ca.z), bf2f(ca.w) };
        float s = 0;
        #pragma unroll
        for (int j = 0; j < 8; j++) s += kvv[j];
        s += __shfl_xor(s, 1, 64); s += __shfl_xor(s, 2, 64);
        float mean = s * (1.0f / 32.0f);
        float ss = 0;
        #pragma unroll
        for (int j = 0; j < 8; j++){ kvv[j] -= mean; ss = fmaf(kvv[j], kvv[j], ss); }
        ss += __shfl_xor(ss, 1, 64); ss += __shfl_xor(ss, 2, 64);
        float inv = 1.0f / (sqrtf(ss * (1.0f / 31.0f)) + 1e-5f);
        #pragma unroll
        for (int j = 0; j < 8; j++) kvv[j] = fmaf(kwr[j] * kvv[j], inv, kbr[j]);
        s = 0;
        #pragma unroll
        for (int j = 0; j < 8; j++) s += vvv[j];
        s += __shfl_xor(s, 1, 64); s += __shfl_xor(s, 2, 64);
        mean = s * (1.0f / 32.0f);
        ss = 0;
        #pragma unroll
        for (int j = 0; j < 8; j++){ vvv[j] -= mean; ss = fmaf(vvv[j], vvv[j], ss); }
        ss += __shfl_xor(ss, 1, 64); ss += __shfl_xor(ss, 2, 64);
        inv = 1.0f / (sqrtf(ss * (1.0f / 31.0f)) + 1e-5f);
        #pragma unroll
        for (int j = 0; j < 8; j++) vvv[j] = fmaf(vwr[j] * vvv[j], inv, vbr[j]);
        s = 0;
        #pragma unroll
        for (int j = 0; j < 4; j++) s += cvv[j];
        s += __shfl_xor(s, 1, 64); s += __shfl_xor(s, 2, 64);
        mean = s * (1.0f / 16.0f);
        ss = 0;
        #pragma unroll
        for (int j = 0; j < 4; j++){ cvv[j] -= mean; ss = fmaf(cvv[j], cvv[j], ss); }
        ss += __shfl_xor(ss, 1, 64); ss += __shfl_xor(ss, 2, 64);
        inv = 1.0f / (sqrtf(ss * (1.0f / 15.0f)) + 1e-5f);
        #pragma unroll
        for (int j = 0; j < 4; j++) cvv[j] = fmaf(cwr[j] * cvv[j], inv, cbr[j]);
        __syncthreads();
        #pragma unroll
        for (int j = 0; j < 8; j++){ Ks[lr][lq * 8 + j] = kvv[j]; Vs[lr][lq * 8 + j] = vvv[j]; }
        #pragma unroll
        for (int j = 0; j < 4; j++) Cs[lr][lq * 4 + j] = cvv[j];
        __syncthreads();
        #pragma unroll 4
        for (int n = 0; n < 64; n++){
            float k0 = Ks[n][d0], k1 = Ks[n][d0 + 1];
            float v0 = Vs[n][e0], v1 = Vs[n][e0 + 1];
            float ce = Cs[n][e1];
            a00 = fmaf(k0, v0, a00); a01 = fmaf(k0, v1, a01);
            a10 = fmaf(k1, v0, a10); a11 = fmaf(k1, v1, a11);
            c0a = fmaf(k0, ce, c0a); c1a = fmaf(k1, ce, c1a);
        }
    }
    const float sc = 1.0f / 16384.0f;
    float* o = KTV + (size_t)bh * 1024;
    atomicAdd(&o[(d0 + 0) * 32 + e0 + 0], a00 * sc);
    atomicAdd(&o[(d0 + 0) * 32 + e0 + 1], a01 * sc);
    atomicAdd(&o[(d0 + 1) * 32 + e0 + 0], a10 * sc);
    atomicAdd(&o[(d0 + 1) * 32 + e0 + 1], a11 * sc);
    float* o2 = KTC + (size_t)bh * 512;
    atomicAdd(&o2[(d0 + 0) * 16 + e1], c0a * sc);
    atomicAdd(&o2[(d0 + 1) * 16 + e1], c1a * sc);
}

// ---------- merged, token-blocked: t = q@ktv + xn ; dm = q@ktc - ce_flat ----------
// 512 blocks x 128 tokens; KTV/KTC columns in registers; Q staged via double-buffered LDS.
__global__ __launch_bounds__(256) void attn_out_kernel(const unsigned short* __restrict__ Q,
                                                       const unsigned short* __restrict__ XN,
                                                       const float* __restrict__ KTV,
                                                       const float* __restrict__ KTC,
                                                       const unsigned short* __restrict__ CEF,
                                                       unsigned short* __restrict__ T1,
                                                       unsigned short* __restrict__ TM){
    __shared__ float qs[2][4][256];
    int blk = blockIdx.x;
    int b = blk >> 7;
    int tok0 = blk * 128;
    int c = threadIdx.x;
    int h = c >> 5, e = c & 31;
    int m = c & 127, h2 = m >> 4, e2 = m & 15, jj = c >> 7;
    float ktvcol[32], ktccol[32];
    {
        const float* kt = KTV + ((size_t)(b * 8 + h) << 10) + e;
        #pragma unroll
        for (int d = 0; d < 32; d++) ktvcol[d] = kt[d * 32];
        const float* kt2 = KTC + ((size_t)(b * 8 + h2) << 9) + e2;
        #pragma unroll
        for (int d = 0; d < 32; d++) ktccol[d] = kt2[d * 16];
    }
    int lrow = c >> 6, lcol = (c & 63) * 4;
    ushort4 u = *reinterpret_cast<const ushort4*>(Q + (size_t)(tok0 + lrow) * 256 + lcol);
    int pp = 0;
    #pragma unroll 1
    for (int ch = 0; ch < 32; ch++){
        int tok = tok0 + ch * 4;
        qs[pp][lrow][lcol + 0] = bf2f(u.x);
        qs[pp][lrow][lcol + 1] = bf2f(u.y);
        qs[pp][lrow][lcol + 2] = bf2f(u.z);
        qs[pp][lrow][lcol + 3] = bf2f(u.w);
        if (ch < 31)
            u = *reinterpret_cast<const ushort4*>(Q + (size_t)(tok + 4 + lrow) * 256 + lcol);
        __syncthreads();
        #pragma unroll
        for (int j = 0; j < 4; j++){
            const float4* qp = reinterpret_cast<const float4*>(&qs[pp][j][h * 32]);
            float acc = 0;
            #pragma unroll
            for (int d4 = 0; d4 < 8; d4++){
                float4 qv = qp[d4];
                acc = fmaf(qv.x, ktvcol[d4 * 4 + 0], acc);
                acc = fmaf(qv.y, ktvcol[d4 * 4 + 1], acc);
                acc = fmaf(qv.z, ktvcol[d4 * 4 + 2], acc);
                acc = fmaf(qv.w, ktvcol[d4 * 4 + 3], acc);
            }
            size_t o = (size_t)(tok + j) * 256 + c;
            T1[o] = f2bf(acc + bf2f(XN[o]));
        }
        #pragma unroll
        for (int rep = 0; rep < 2; rep++){
            int j = jj + rep * 2;
            const float4* qp = reinterpret_cast<const float4*>(&qs[pp][j][h2 * 32]);
            float acc = 0;
            #pragma unroll
            for (int d4 = 0; d4 < 8; d4++){
                float4 qv = qp[d4];
                acc = fmaf(qv.x, ktccol[d4 * 4 + 0], acc);
                acc = fmaf(qv.y, ktccol[d4 * 4 + 1], acc);
                acc = fmaf(qv.z, ktccol[d4 * 4 + 2], acc);
                acc = fmaf(qv.w, ktccol[d4 * 4 + 3], acc);
            }
            size_t o = (size_t)(tok + j) * 128 + m;
            TM[o] = f2bf(acc - bf2f(CEF[o]));
        }
        pp ^= 1;
    }
}

// ---------- depthwise 3x3 conv (SAME) + bias + gelu, row-stationary sliding window ----------
__global__ __launch_bounds__(192) void dwconv_kernel(const unsigned short* __restrict__ H1,
                                                     const float* __restrict__ dww,
                                                     const float* __restrict__ dwb,
                                                     unsigned short* __restrict__ H2){
    int blk = blockIdx.x;
    int bb = blk >> 8;
    int yy = (blk >> 1) & 127;
    int xh = blk & 1;
    int x0 = xh * 64;
    int ch = threadIdx.x * 4;
    float w[9][4];
    #pragma unroll
    for (int k = 0; k < 9; k++)
        #pragma unroll
        for (int j = 0; j < 4; j++) w[k][j] = dww[(ch + j) * 9 + k];
    float bias[4] = { dwb[ch], dwb[ch+1], dwb[ch+2], dwb[ch+3] };
    const bool r0v = (yy > 0), r2v = (yy < 127);
    size_t rowbase[3];
    rowbase[0] = ((size_t)((bb << 14) + ((yy - 1) << 7))) * 768 + ch;
    rowbase[1] = ((size_t)((bb << 14) + ( yy      << 7))) * 768 + ch;
    rowbase[2] = ((size_t)((bb << 14) + ((yy + 1) << 7))) * 768 + ch;
    size_t obase = ((size_t)((bb << 14) + (yy << 7))) * 768 + ch;

    float A[3][4], B[3][4], C[3][4], D[3][4];
    #define LOADCOL(DST, XX) do {                                             \
        int _x = (XX);                                                        \
        bool xv = ((unsigned)_x <= 127u);                                     \
        ushort4 u0 = (xv && r0v) ? *reinterpret_cast<const ushort4*>(H1 + rowbase[0] + (size_t)_x * 768) : ushort4{0,0,0,0}; \
        ushort4 u1 = (xv)        ? *reinterpret_cast<const ushort4*>(H1 + rowbase[1] + (size_t)_x * 768) : ushort4{0,0,0,0}; \
        ushort4 u2 = (xv && r2v) ? *reinterpret_cast<const ushort4*>(H1 + rowbase[2] + (size_t)_x * 768) : ushort4{0,0,0,0}; \
        DST[0][0] = bf2f(u0.x); DST[0][1] = bf2f(u0.y); DST[0][2] = bf2f(u0.z); DST[0][3] = bf2f(u0.w); \
        DST[1][0] = bf2f(u1.x); DST[1][1] = bf2f(u1.y); DST[1][2] = bf2f(u1.z); DST[1][3] = bf2f(u1.w); \
        DST[2][0] = bf2f(u2.x); DST[2][1] = bf2f(u2.y); DST[2][2] = bf2f(u2.z); DST[2][3] = bf2f(u2.w); \
    } while (0)

    #define EMIT(CA, CB, CC, XX) do {                                         \
        float acc[4];                                                         \
        _Pragma("unroll")                                                     \
        for (int j = 0; j < 4; j++){                                          \
            acc[j] = bias[j];                                                 \
            acc[j] = fmaf(CA[0][j], w[0][j], acc[j]);                         \
            acc[j] = fmaf(CB[0][j], w[1][j], acc[j]);                         \
            acc[j] = fmaf(CC[0][j], w[2][j], acc[j]);                         \
            acc[j] = fmaf(CA[1][j], w[3][j], acc[j]);                         \
            acc[j] = fmaf(CB[1][j], w[4][j], acc[j]);                         \
            acc[j] = fmaf(CC[1][j], w[5][j], acc[j]);                         \
            acc[j] = fmaf(CA[2][j], w[6][j], acc[j]);                         \
            acc[j] = fmaf(CB[2][j], w[7][j], acc[j]);                         \
            acc[j] = fmaf(CC[2][j], w[8][j], acc[j]);                         \
        }                                                                     \
        ushort4 o;                                                            \
        o.x = f2bf(gelu_f(acc[0])); o.y = f2bf(gelu_f(acc[1]));               \
        o.z = f2bf(gelu_f(acc[2])); o.w = f2bf(gelu_f(acc[3]));               \
        *reinterpret_cast<ushort4*>(H2 + obase + (size_t)(XX) * 768) = o;     \
    } while (0)

    LOADCOL(A, x0 - 1);
    LOADCOL(B, x0);
    LOADCOL(C, x0 + 1);
    int xcur = x0;
    #pragma unroll 1
    for (int g = 0; g < 16; g++){
        LOADCOL(D, xcur + 2); EMIT(A, B, C, xcur); xcur++;
        LOADCOL(A, xcur + 2); EMIT(B, C, D, xcur); xcur++;
        LOADCOL(B, xcur + 2); EMIT(C, D, A, xcur); xcur++;
        LOADCOL(C, xcur + 2); EMIT(D, A, B, xcur); xcur++;
    }
    #undef LOADCOL
    #undef EMIT
}

// ---------- bf16 MFMA GEMM ----------
#define M_PLAIN     0
#define M_KV        1
#define M_BIAS_GELU 2
#define M_BIAS_ADD2 3
#define M_BIAS      4
#define M_BIAS_BF16 5
#define M_BIAS_ADDX 6

template<int MODE, bool SWAP, int K, int O>
__global__ __launch_bounds__(256) void mgemm(const unsigned short* __restrict__ A,
                                             const unsigned short* __restrict__ W,
                                             const float* __restrict__ bias,
                                             const void* __restrict__ add,
                                             void* __restrict__ out0,
                                             void* __restrict__ out1){
    __shared__ __align__(16) unsigned short As[128 * 32];
    __shared__ __align__(16) unsigned short Bs[128 * 32];
    const int t = threadIdx.x;
    const int lane = t & 63, wid = t >> 6;
    const int wm = wid >> 1, wn = wid & 1;
    const int row0 = blockIdx.x * 128;
    const int col0 = blockIdx.y * 128;
    f32x4 acc[4][4];
    #pragma unroll
    for (int i = 0; i < 4; i++)
        #pragma unroll
        for (int j = 0; j < 4; j++){ f32x4 z = {0.f, 0.f, 0.f, 0.f}; acc[i][j] = z; }

    const int lr = lane >> 2;
    const int ls = lane & 3;
    const int kq = lane >> 4;
    const int rr = lane & 15;

    for (int kb = 0; kb < K; kb += 32){
        #pragma unroll
        for (int i = 0; i < 2; i++){
            int r = i * 64 + wid * 16 + lr;
            int ko = ls ^ ((r >> 1) & 3);
            int ga = row0 + r;
            if (SWAP) ga ^= 32768;
            const unsigned short* srcA = A + (size_t)ga * K + kb + ko * 8;
            __builtin_amdgcn_global_load_lds(
                (const __attribute__((address_space(1))) unsigned int*)srcA,
                (__attribute__((address_space(3))) unsigned int*)(As + (i * 64 + wid * 16) * 32),
                16, 0, 0);
            const unsigned short* srcB = W + (size_t)(col0 + r) * K + kb + ko * 8;
            __builtin_amdgcn_global_load_lds(
                (const __attribute__((address_space(1))) unsigned int*)srcB,
                (__attribute__((address_space(3))) unsigned int*)(Bs + (i * 64 + wid * 16) * 32),
                16, 0, 0);
        }
        __syncthreads();
        bf16x8 af[4], bfr[4];
        #pragma unroll
        for (int m = 0; m < 4; m++){
            int row = wm * 64 + m * 16 + rr;
            int s = kq ^ ((row >> 1) & 3);
            af[m] = *reinterpret_cast<const bf16x8*>(As + row * 32 + s * 8);
        }
        #pragma unroll
        for (int n = 0; n < 4; n++){
            int row = wn * 64 + n * 16 + rr;
            int s = kq ^ ((row >> 1) & 3);
            bfr[n] = *reinterpret_cast<const bf16x8*>(Bs + row * 32 + s * 8);
        }
        #pragma unroll
        for (int m = 0; m < 4; m++)
            #pragma unroll
            for (int n = 0; n < 4; n++)
                acc[m][n] = __builtin_amdgcn_mfma_f32_16x16x32_bf16(af[m], bfr[n], acc[m][n], 0, 0, 0);
        __syncthreads();
    }

    #pragma unroll
    for (int m = 0; m < 4; m++){
        #pragma unroll
        for (int n = 0; n < 4; n++){
            int col = col0 + wn * 64 + n * 16 + rr;
            int rbase = row0 + wm * 64 + m * 16 + kq * 4;
            #pragma unroll
            for (int j = 0; j < 4; j++){
                int r = rbase + j;
                float v = acc[m][n][j];
                size_t o = (size_t)r * O + col;
                if constexpr (MODE == M_PLAIN){
                    ((unsigned short*)out0)[o] = f2bf(v);
                } else if constexpr (MODE == M_KV){
                    if (col < 256) ((unsigned short*)out0)[(size_t)r * 256 + col] = f2bf(v);
                    else           ((unsigned short*)out1)[(size_t)r * 256 + col - 256] = f2bf(v);
                } else if constexpr (MODE == M_BIAS_GELU){
                    ((unsigned short*)out0)[o] = f2bf(gelu_f(v + bias[col]));
                } else if constexpr (MODE == M_BIAS_ADD2){
                    ((unsigned short*)out0)[o] = f2bf(v + bias[col] + 2.0f * bf2f(((const unsigned short*)add)[o]));
                } else if constexpr (MODE == M_BIAS){
                    ((float*)out0)[o] = v + bias[col];
                } else if constexpr (MODE == M_BIAS_BF16){
                    ((unsigned short*)out0)[o] = f2bf(v + bias[col]);
                } else if constexpr (MODE == M_BIAS_ADDX){
                    ((float*)out0)[o] = v + bias[col] + ((const float*)add)[o];
                }
            }
        }
    }
}

extern "C" void kernel_launch(void* const* d_in, const int* in_sizes, int n_in,
                              void* d_out, int out_size, void* d_ws, size_t ws_size,
                              hipStream_t stream){
    const float* x     = (const float*)d_in[0];
    const float* cor   = (const float*)d_in[1];
    const float* q_w   = (const float*)d_in[2];
    const float* kv_w  = (const float*)d_in[3];
    const float* cor_w = (const float*)d_in[4];
    const float* kln_w = (const float*)d_in[5];
    const float* kln_b = (const float*)d_in[6];
    const float* vln_w = (const float*)d_in[7];
    const float* vln_b = (const float*)d_in[8];
    const float* corln_w = (const float*)d_in[9];
    const float* corln_b = (const float*)d_in[10];
    const float* op1_w = (const float*)d_in[11];
    const float* op1_b = (const float*)d_in[12];
    const float* op2_w = (const float*)d_in[13];
    const float* op2_b = (const float*)d_in[14];
    const float* om1_w = (const float*)d_in[15];
    const float* om1_b = (const float*)d_in[16];
    const float* om2_w = (const float*)d_in[17];
    const float* om2_b = (const float*)d_in[18];
    const float* n1_w  = (const float*)d_in[19];
    const float* n1_b  = (const float*)d_in[20];
    const float* n2_w  = (const float*)d_in[21];
    const float* n2_b  = (const float*)d_in[22];
    const float* fc1_w = (const float*)d_in[23];
    const float* fc1_b = (const float*)d_in[24];
    const float* dw_w  = (const float*)d_in[25];
    const float* dw_b  = (const float*)d_in[26];
    const float* fc2_w = (const float*)d_in[27];
    const float* fc2_b = (const float*)d_in[28];

    // ---- workspace layout (bf16 elements unless noted) ----
    unsigned short* XN  = (unsigned short*)d_ws;           // NTOK*256
    unsigned short* Qb  = XN  + (size_t)NTOK * 256;
    unsigned short* Kb  = Qb  + (size_t)NTOK * 256;
    unsigned short* Vb  = Kb  + (size_t)NTOK * 256;
    unsigned short* CEF = Vb  + (size_t)NTOK * 256;        // NTOK*128
    unsigned short* CE  = CEF + (size_t)NTOK * 128;
    float* KTV = (float*)(CE + (size_t)NTOK * 128);        // 32768 f32
    float* KTC = KTV + 32768;                              // 16384 f32
    unsigned short* Wb  = (unsigned short*)(KTC + 16384);  // 753664 bf16 weights
    unsigned short* H2  = Wb + 753664;                     // NTOK*768
    // overlays (disjoint live ranges):
    unsigned short* T1 = Vb;
    unsigned short* T2 = Kb;
    unsigned short* XB = Qb;
    unsigned short* Y  = Vb;
    unsigned short* TM = CE;
    unsigned short* MH = CEF;
    unsigned short* H1 = XN;      // spans XN+Qb+Kb = NTOK*768
    float* xout = (float*)d_out;
    float* mout = xout + (size_t)NTOK * 256;

    unsigned short* w_q   = Wb + 0;
    unsigned short* w_kv  = Wb + 65536;
    unsigned short* w_op1 = Wb + 196608;
    unsigned short* w_op2 = Wb + 262144;
    unsigned short* w_om1 = Wb + 327680;
    unsigned short* w_om2 = Wb + 344064;
    unsigned short* w_fc1 = Wb + 360448;
    unsigned short* w_fc2 = Wb + 557056;

    // 0. weights -> bf16
    wconv_kernel<<<736, 256, 0, stream>>>(q_w, kv_w, op1_w, op2_w, om1_w, om2_w, fc1_w, fc2_w, Wb);
    // 1. xn = std_ln(x, norm1)
    stdln_kernel<false><<<2048, 256, 0, stream>>>(x, n1_w, n1_b, XN);
    // 2. q = xn @ q_w.T
    mgemm<M_PLAIN, false, 256, 256><<<dim3(512, 2), 256, 0, stream>>>(XN, w_q, nullptr, nullptr, Qb, nullptr);
    // 3. kv = xr @ kv_w.T (swapped rows), split K,V (un-normalized)
    mgemm<M_KV, true, 256, 512><<<dim3(512, 4), 256, 0, stream>>>(XN, w_kv, nullptr, nullptr, Kb, Vb);
    // 4. ce_flat
    ce_kernel<<<2048, 256, 0, stream>>>(cor, cor_w, CEF);
    // 5. zero accumulators
    hipMemsetAsync(KTV, 0, (32768 + 16384) * sizeof(float), stream);
    // 6. fused LN + ktv + ktc
    ktvc_kernel<<<dim3(32, 16), 256, 0, stream>>>(Kb, Vb, CEF, kln_w, kln_b, vln_w, vln_b,
                                                  corln_w, corln_b, KTV, KTC);
    // 7. t = q@ktv + xn ; dm = q@ktc - ce_flat (token-blocked)
    attn_out_kernel<<<512, 256, 0, stream>>>(Qb, XN, KTV, KTC, CEF, T1, TM);
    // 8. hidden = gelu(t @ op1.T + b)
    mgemm<M_BIAS_GELU, false, 256, 256><<<dim3(512, 2), 256, 0, stream>>>(T1, w_op1, op1_b, nullptr, T2, nullptr);
    // 9. x_back = (hidden @ op2.T + b) + 2*xn
    mgemm<M_BIAS_ADD2, false, 256, 256><<<dim3(512, 2), 256, 0, stream>>>(T2, w_op2, op2_b, XN, XB, nullptr);
    // 10. mh = gelu(dm @ om1.T + b)
    mgemm<M_BIAS_GELU, false, 128, 128><<<dim3(512, 1), 256, 0, stream>>>(TM, w_om1, om1_b, nullptr, MH, nullptr);
    // 11. motion = mh @ om2.T + b -> output 1 (fp32)
    mgemm<M_BIAS, false, 128, 128><<<dim3(512, 1), 256, 0, stream>>>(MH, w_om2, om2_b, nullptr, mout, nullptr);
    // 12. y = std_ln(x_back, norm2)
    stdln_kernel<true><<<2048, 256, 0, stream>>>(XB, n2_w, n2_b, Y);
    // 13. h1 = y @ fc1.T + b (bf16)
    mgemm<M_BIAS_BF16, false, 256, 768><<<dim3(512, 6), 256, 0, stream>>>(Y, w_fc1, fc1_b, nullptr, H1, nullptr);
    // 14. depthwise conv + bias + gelu (row-stationary)
    dwconv_kernel<<<1024, 192, 0, stream>>>(H1, dw_w, dw_b, H2);
    // 15. x_out = h2 @ fc2.T + b + x -> output 0 (fp32)
    mgemm<M_BIAS_ADDX, false, 768, 256><<<dim3(512, 2), 256, 0, stream>>>(H2, w_fc2, fc2_b, x, xout, nullptr);
}

// Round 5
// 521.581 us; speedup vs baseline: 5.4056x; 1.0487x over previous
//
#include <hip/hip_runtime.h>
#include <hip/hip_bf16.h>

#define NTOK 65536      // 4 * 16384 tokens

typedef __attribute__((ext_vector_type(4))) float f32x4;
typedef __attribute__((ext_vector_type(8))) short bf16x8;

__device__ __forceinline__ float gelu_f(float x){
    // tanh-form gelu: max abs dev from erf-form ~3e-4, far below bf16 rounding here
    float u = 0.7978845608028654f * fmaf(0.044715f * x * x, x, x);
    float e = __expf(2.0f * u);
    float t = 1.0f - 2.0f / (e + 1.0f);
    return 0.5f * x * (1.0f + t);
}
__device__ __forceinline__ float bf2f(unsigned short u){
    union { unsigned int i; float f; } w; w.i = ((unsigned int)u) << 16; return w.f;
}
__device__ __forceinline__ unsigned short f2bf(float f){
    __hip_bfloat16 h = __float2bfloat16(f);
    return *reinterpret_cast<unsigned short*>(&h);
}

// ---------- weight fp32 -> bf16 conversion into contiguous Wb ----------
__global__ __launch_bounds__(256) void wconv_kernel(const float* __restrict__ q_w, const float* __restrict__ kv_w,
                                                    const float* __restrict__ op1_w, const float* __restrict__ op2_w,
                                                    const float* __restrict__ om1_w, const float* __restrict__ om2_w,
                                                    const float* __restrict__ fc1_w, const float* __restrict__ fc2_w,
                                                    unsigned short* __restrict__ Wb){
    size_t e = ((size_t)blockIdx.x * 256 + threadIdx.x) * 4;
    if (e >= 753664) return;
    const float* src; size_t off;
    if      (e <  65536){ src = q_w;   off = 0; }
    else if (e < 196608){ src = kv_w;  off = 65536; }
    else if (e < 262144){ src = op1_w; off = 196608; }
    else if (e < 327680){ src = op2_w; off = 262144; }
    else if (e < 344064){ src = om1_w; off = 327680; }
    else if (e < 360448){ src = om2_w; off = 344064; }
    else if (e < 557056){ src = fc1_w; off = 360448; }
    else                { src = fc2_w; off = 557056; }
    float4 v = *reinterpret_cast<const float4*>(src + (e - off));
    ushort4 o; o.x = f2bf(v.x); o.y = f2bf(v.y); o.z = f2bf(v.z); o.w = f2bf(v.w);
    *reinterpret_cast<ushort4*>(Wb + e) = o;
}

// ---------- std LayerNorm over 256 -> bf16 out; wave-per-token, 8 tokens/wave ----------
template<bool BF16IN>
__global__ __launch_bounds__(256) void stdln_kernel(const void* __restrict__ Xp,
                                                    const float* __restrict__ w,
                                                    const float* __restrict__ b,
                                                    unsigned short* __restrict__ out){
    int wv = threadIdx.x >> 6, lane = threadIdx.x & 63;
    int tok0 = (blockIdx.x * 4 + wv) * 8;
    int c0 = lane * 4;
    float4 w4 = *reinterpret_cast<const float4*>(w + c0);
    float4 b4 = *reinterpret_cast<const float4*>(b + c0);
    #pragma unroll 2
    for (int j = 0; j < 8; j++){
        size_t base = (size_t)(tok0 + j) * 256 + c0;
        float v[4];
        if constexpr (BF16IN){
            ushort4 u = *reinterpret_cast<const ushort4*>((const unsigned short*)Xp + base);
            v[0] = bf2f(u.x); v[1] = bf2f(u.y); v[2] = bf2f(u.z); v[3] = bf2f(u.w);
        } else {
            float4 f = *reinterpret_cast<const float4*>((const float*)Xp + base);
            v[0] = f.x; v[1] = f.y; v[2] = f.z; v[3] = f.w;
        }
        float s = v[0] + v[1] + v[2] + v[3];
        #pragma unroll
        for (int m = 1; m < 64; m <<= 1) s += __shfl_xor(s, m, 64);
        float mean = s * (1.0f / 256.0f);
        float ss = 0;
        #pragma unroll
        for (int k = 0; k < 4; k++){ v[k] -= mean; ss = fmaf(v[k], v[k], ss); }
        #pragma unroll
        for (int m = 1; m < 64; m <<= 1) ss += __shfl_xor(ss, m, 64);
        float inv = rsqrtf(ss * (1.0f / 256.0f) + 1e-5f);
        ushort4 o;
        o.x = f2bf(w4.x * v[0] * inv + b4.x);
        o.y = f2bf(w4.y * v[1] * inv + b4.y);
        o.z = f2bf(w4.z * v[2] * inv + b4.z);
        o.w = f2bf(w4.w * v[3] * inv + b4.w);
        *reinterpret_cast<ushort4*>(out + base) = o;
    }
}

// ---------- ce_flat = cor @ cor_w.T (K=2), token-blocked ----------
__global__ __launch_bounds__(256) void ce_kernel(const float* __restrict__ cor,
                                                 const float* __restrict__ cor_w,
                                                 unsigned short* __restrict__ CEF){
    int m = threadIdx.x & 127, half = threadIdx.x >> 7;
    float w0 = cor_w[m * 2 + 0], w1 = cor_w[m * 2 + 1];
    #pragma unroll 4
    for (int it = 0; it < 16; it++){
        int tok = blockIdx.x * 32 + it * 2 + half;
        float c0 = cor[(size_t)tok * 2 + 0];
        float c1 = cor[(size_t)tok * 2 + 1];
        CEF[(size_t)tok * 128 + m] = f2bf(c0 * w0 + c1 * w1);
    }
}

// ---------- fused: on-the-fly custom LN of K,V,CE + ktv & ktc reductions ----------
__global__ __launch_bounds__(256) void ktvc_kernel(const unsigned short* __restrict__ Kb,
                                                   const unsigned short* __restrict__ Vb,
                                                   const unsigned short* __restrict__ CEF,
                                                   const float* __restrict__ kw, const float* __restrict__ kbb,
                                                   const float* __restrict__ vw, const float* __restrict__ vbb,
                                                   const float* __restrict__ cw, const float* __restrict__ cbb,
                                                   float* __restrict__ KTV, float* __restrict__ KTC){
    int bh = blockIdx.x, b = bh >> 3, h = bh & 7;
    __shared__ float Ks[64][33];
    __shared__ float Vs[64][33];
    __shared__ float Cs[64][17];
    int t = threadIdx.x;
    int lr = t >> 2, lq = t & 3;
    int d0 = (t >> 4) * 2, e0 = (t & 15) * 2, e1 = t & 15;
    float kwr[8], kbr[8], vwr[8], vbr[8], cwr[4], cbr[4];
    #pragma unroll
    for (int j = 0; j < 8; j++){
        kwr[j] = kw[h * 32 + lq * 8 + j]; kbr[j] = kbb[h * 32 + lq * 8 + j];
        vwr[j] = vw[h * 32 + lq * 8 + j]; vbr[j] = vbb[h * 32 + lq * 8 + j];
    }
    #pragma unroll
    for (int j = 0; j < 4; j++){
        cwr[j] = cw[h * 16 + lq * 4 + j]; cbr[j] = cbb[h * 16 + lq * 4 + j];
    }
    float a00 = 0, a01 = 0, a10 = 0, a11 = 0;
    float c0a = 0, c1a = 0;
    size_t base = ((size_t)b << 14) + (size_t)blockIdx.y * 1024;
    for (int n0 = 0; n0 < 1024; n0 += 64){
        size_t rowi = base + n0 + lr;
        const ushort4* kp = reinterpret_cast<const ushort4*>(Kb + rowi * 256 + h * 32 + lq * 8);
        ushort4 ka = kp[0], kc = kp[1];
        const ushort4* vp = reinterpret_cast<const ushort4*>(Vb + rowi * 256 + h * 32 + lq * 8);
        ushort4 va = vp[0], vc = vp[1];
        ushort4 ca = *reinterpret_cast<const ushort4*>(CEF + rowi * 128 + h * 16 + lq * 4);
        float kvv[8] = { bf2f(ka.x), bf2f(ka.y), bf2f(ka.z), bf2f(ka.w),
                         bf2f(kc.x), bf2f(kc.y), bf2f(kc.z), bf2f(kc.w) };
        float vvv[8] = { bf2f(va.x), bf2f(va.y), bf2f(va.z), bf2f(va.w),
                         bf2f(vc.x), bf2f(vc.y), bf2f(vc.z), bf2f(vc.w) };
        float cvv[4] = { bf2f(ca.x), bf2f(ca.y), bf2f(ca.z), bf2f(ca.w) };
        float s = 0;
        #pragma unroll
        for (int j = 0; j < 8; j++) s += kvv[j];
        s += __shfl_xor(s, 1, 64); s += __shfl_xor(s, 2, 64);
        float mean = s * (1.0f / 32.0f);
        float ss = 0;
        #pragma unroll
        for (int j = 0; j < 8; j++){ kvv[j] -= mean; ss = fmaf(kvv[j], kvv[j], ss); }
        ss += __shfl_xor(ss, 1, 64); ss += __shfl_xor(ss, 2, 64);
        float inv = 1.0f / (sqrtf(ss * (1.0f / 31.0f)) + 1e-5f);
        #pragma unroll
        for (int j = 0; j < 8; j++) kvv[j] = fmaf(kwr[j] * kvv[j], inv, kbr[j]);
        s = 0;
        #pragma unroll
        for (int j = 0; j < 8; j++) s += vvv[j];
        s += __shfl_xor(s, 1, 64); s += __shfl_xor(s, 2, 64);
        mean = s * (1.0f / 32.0f);
        ss = 0;
        #pragma unroll
        for (int j = 0; j < 8; j++){ vvv[j] -= mean; ss = fmaf(vvv[j], vvv[j], ss); }
        ss += __shfl_xor(ss, 1, 64); ss += __shfl_xor(ss, 2, 64);
        inv = 1.0f / (sqrtf(ss * (1.0f / 31.0f)) + 1e-5f);
        #pragma unroll
        for (int j = 0; j < 8; j++) vvv[j] = fmaf(vwr[j] * vvv[j], inv, vbr[j]);
        s = 0;
        #pragma unroll
        for (int j = 0; j < 4; j++) s += cvv[j];
        s += __shfl_xor(s, 1, 64); s += __shfl_xor(s, 2, 64);
        mean = s * (1.0f / 16.0f);
        ss = 0;
        #pragma unroll
        for (int j = 0; j < 4; j++){ cvv[j] -= mean; ss = fmaf(cvv[j], cvv[j], ss); }
        ss += __shfl_xor(ss, 1, 64); ss += __shfl_xor(ss, 2, 64);
        inv = 1.0f / (sqrtf(ss * (1.0f / 15.0f)) + 1e-5f);
        #pragma unroll
        for (int j = 0; j < 4; j++) cvv[j] = fmaf(cwr[j] * cvv[j], inv, cbr[j]);
        __syncthreads();
        #pragma unroll
        for (int j = 0; j < 8; j++){ Ks[lr][lq * 8 + j] = kvv[j]; Vs[lr][lq * 8 + j] = vvv[j]; }
        #pragma unroll
        for (int j = 0; j < 4; j++) Cs[lr][lq * 4 + j] = cvv[j];
        __syncthreads();
        #pragma unroll 4
        for (int n = 0; n < 64; n++){
            float k0 = Ks[n][d0], k1 = Ks[n][d0 + 1];
            float v0 = Vs[n][e0], v1 = Vs[n][e0 + 1];
            float ce = Cs[n][e1];
            a00 = fmaf(k0, v0, a00); a01 = fmaf(k0, v1, a01);
            a10 = fmaf(k1, v0, a10); a11 = fmaf(k1, v1, a11);
            c0a = fmaf(k0, ce, c0a); c1a = fmaf(k1, ce, c1a);
        }
    }
    const float sc = 1.0f / 16384.0f;
    float* o = KTV + (size_t)bh * 1024;
    atomicAdd(&o[(d0 + 0) * 32 + e0 + 0], a00 * sc);
    atomicAdd(&o[(d0 + 0) * 32 + e0 + 1], a01 * sc);
    atomicAdd(&o[(d0 + 1) * 32 + e0 + 0], a10 * sc);
    atomicAdd(&o[(d0 + 1) * 32 + e0 + 1], a11 * sc);
    float* o2 = KTC + (size_t)bh * 512;
    atomicAdd(&o2[(d0 + 0) * 16 + e1], c0a * sc);
    atomicAdd(&o2[(d0 + 1) * 16 + e1], c1a * sc);
}

// ---------- combined attention weights: WTC[b][c][i], c<256: q_w^T·ktv ; c>=256: q_w^T·ktc ----------
__global__ __launch_bounds__(256) void wcomb_kernel(const float* __restrict__ q_w,
                                                    const float* __restrict__ KTV,
                                                    const float* __restrict__ KTC,
                                                    unsigned short* __restrict__ WTC){
    int c = blockIdx.x;       // 0..383
    int b = blockIdx.y;       // 0..3
    int i = threadIdx.x;      // 0..255
    __shared__ float coef[32];
    int h = (c < 256) ? (c >> 5) : ((c - 256) >> 4);
    if (i < 32){
        if (c < 256) coef[i] = KTV[(size_t)((b * 8 + h) << 10) + i * 32 + (c & 31)];
        else         coef[i] = KTC[(size_t)((b * 8 + h) << 9)  + i * 16 + ((c - 256) & 15)];
    }
    __syncthreads();
    float acc = 0;
    #pragma unroll
    for (int d = 0; d < 32; d++) acc = fmaf(q_w[(size_t)(h * 32 + d) * 256 + i], coef[d], acc);
    WTC[((size_t)b * 384 + c) * 256 + i] = f2bf(acc);
}

// ---------- depthwise 3x3 conv (SAME) + bias + gelu, row-stationary sliding window ----------
// block = (b, y, xquarter); 2048 blocks; weights in regs, 3 loads/pixel, 1-col prefetch.
__global__ __launch_bounds__(192) void dwconv_kernel(const unsigned short* __restrict__ H1,
                                                     const float* __restrict__ dww,
                                                     const float* __restrict__ dwb,
                                                     unsigned short* __restrict__ H2){
    int blk = blockIdx.x;
    int bb = blk >> 9;
    int yy = (blk >> 2) & 127;
    int xq = blk & 3;
    int x0 = xq * 32;
    int ch = threadIdx.x * 4;
    float w[9][4];
    #pragma unroll
    for (int k = 0; k < 9; k++)
        #pragma unroll
        for (int j = 0; j < 4; j++) w[k][j] = dww[(ch + j) * 9 + k];
    float bias[4] = { dwb[ch], dwb[ch+1], dwb[ch+2], dwb[ch+3] };
    const bool r0v = (yy > 0), r2v = (yy < 127);
    size_t rowbase[3];
    rowbase[0] = ((size_t)((bb << 14) + ((yy - 1) << 7))) * 768 + ch;
    rowbase[1] = ((size_t)((bb << 14) + ( yy      << 7))) * 768 + ch;
    rowbase[2] = ((size_t)((bb << 14) + ((yy + 1) << 7))) * 768 + ch;
    size_t obase = ((size_t)((bb << 14) + (yy << 7))) * 768 + ch;

    float A[3][4], B[3][4], C[3][4], D[3][4];
    #define LOADCOL(DST, XX) do {                                             \
        int _x = (XX);                                                        \
        bool xv = ((unsigned)_x <= 127u);                                     \
        ushort4 u0 = (xv && r0v) ? *reinterpret_cast<const ushort4*>(H1 + rowbase[0] + (size_t)_x * 768) : ushort4{0,0,0,0}; \
        ushort4 u1 = (xv)        ? *reinterpret_cast<const ushort4*>(H1 + rowbase[1] + (size_t)_x * 768) : ushort4{0,0,0,0}; \
        ushort4 u2 = (xv && r2v) ? *reinterpret_cast<const ushort4*>(H1 + rowbase[2] + (size_t)_x * 768) : ushort4{0,0,0,0}; \
        DST[0][0] = bf2f(u0.x); DST[0][1] = bf2f(u0.y); DST[0][2] = bf2f(u0.z); DST[0][3] = bf2f(u0.w); \
        DST[1][0] = bf2f(u1.x); DST[1][1] = bf2f(u1.y); DST[1][2] = bf2f(u1.z); DST[1][3] = bf2f(u1.w); \
        DST[2][0] = bf2f(u2.x); DST[2][1] = bf2f(u2.y); DST[2][2] = bf2f(u2.z); DST[2][3] = bf2f(u2.w); \
    } while (0)

    #define EMIT(CA, CB, CC, XX) do {                                         \
        float acc[4];                                                         \
        _Pragma("unroll")                                                     \
        for (int j = 0; j < 4; j++){                                          \
            acc[j] = bias[j];                                                 \
            acc[j] = fmaf(CA[0][j], w[0][j], acc[j]);                         \
            acc[j] = fmaf(CB[0][j], w[1][j], acc[j]);                         \
            acc[j] = fmaf(CC[0][j], w[2][j], acc[j]);                         \
            acc[j] = fmaf(CA[1][j], w[3][j], acc[j]);                         \
            acc[j] = fmaf(CB[1][j], w[4][j], acc[j]);                         \
            acc[j] = fmaf(CC[1][j], w[5][j], acc[j]);                         \
            acc[j] = fmaf(CA[2][j], w[6][j], acc[j]);                         \
            acc[j] = fmaf(CB[2][j], w[7][j], acc[j]);                         \
            acc[j] = fmaf(CC[2][j], w[8][j], acc[j]);                         \
        }                                                                     \
        ushort4 o;                                                            \
        o.x = f2bf(gelu_f(acc[0])); o.y = f2bf(gelu_f(acc[1]));               \
        o.z = f2bf(gelu_f(acc[2])); o.w = f2bf(gelu_f(acc[3]));               \
        *reinterpret_cast<ushort4*>(H2 + obase + (size_t)(XX) * 768) = o;     \
    } while (0)

    LOADCOL(A, x0 - 1);
    LOADCOL(B, x0);
    LOADCOL(C, x0 + 1);
    int xcur = x0;
    #pragma unroll 1
    for (int g = 0; g < 8; g++){
        LOADCOL(D, xcur + 2); EMIT(A, B, C, xcur); xcur++;
        LOADCOL(A, xcur + 2); EMIT(B, C, D, xcur); xcur++;
        LOADCOL(B, xcur + 2); EMIT(C, D, A, xcur); xcur++;
        LOADCOL(C, xcur + 2); EMIT(D, A, B, xcur); xcur++;
    }
    #undef LOADCOL
    #undef EMIT
}

// ---------- bf16 MFMA GEMM ----------
#define M_KV        1
#define M_BIAS_GELU 2
#define M_BIAS_ADD2 3
#define M_BIAS      4
#define M_BIAS_BF16 5
#define M_BIAS_ADDX 6
#define M_ATTN      7

template<int MODE, bool SWAP, int K, int O>
__global__ __launch_bounds__(256) void mgemm(const unsigned short* __restrict__ A,
                                             const unsigned short* __restrict__ Wp,
                                             const float* __restrict__ bias,
                                             const void* __restrict__ add,
                                             void* __restrict__ out0,
                                             void* __restrict__ out1){
    __shared__ __align__(16) unsigned short As[128 * 32];
    __shared__ __align__(16) unsigned short Bs[128 * 32];
    const int t = threadIdx.x;
    const int lane = t & 63, wid = t >> 6;
    const int wm = wid >> 1, wn = wid & 1;
    const int row0 = blockIdx.x * 128;
    const int col0 = blockIdx.y * 128;
    const unsigned short* W = Wp;
    if constexpr (MODE == M_ATTN) W += (size_t)(row0 >> 14) * (384 * 256);
    f32x4 acc[4][4];
    #pragma unroll
    for (int i = 0; i < 4; i++)
        #pragma unroll
        for (int j = 0; j < 4; j++){ f32x4 z = {0.f, 0.f, 0.f, 0.f}; acc[i][j] = z; }

    const int lr = lane >> 2;
    const int ls = lane & 3;
    const int kq = lane >> 4;
    const int rr = lane & 15;

    for (int kb = 0; kb < K; kb += 32){
        #pragma unroll
        for (int i = 0; i < 2; i++){
            int r = i * 64 + wid * 16 + lr;
            int ko = ls ^ ((r >> 1) & 3);
            int ga = row0 + r;
            if (SWAP) ga ^= 32768;
            const unsigned short* srcA = A + (size_t)ga * K + kb + ko * 8;
            __builtin_amdgcn_global_load_lds(
                (const __attribute__((address_space(1))) unsigned int*)srcA,
                (__attribute__((address_space(3))) unsigned int*)(As + (i * 64 + wid * 16) * 32),
                16, 0, 0);
            const unsigned short* srcB = W + (size_t)(col0 + r) * K + kb + ko * 8;
            __builtin_amdgcn_global_load_lds(
                (const __attribute__((address_space(1))) unsigned int*)srcB,
                (__attribute__((address_space(3))) unsigned int*)(Bs + (i * 64 + wid * 16) * 32),
                16, 0, 0);
        }
        __syncthreads();
        bf16x8 af[4], bfr[4];
        #pragma unroll
        for (int m = 0; m < 4; m++){
            int row = wm * 64 + m * 16 + rr;
            int s = kq ^ ((row >> 1) & 3);
            af[m] = *reinterpret_cast<const bf16x8*>(As + row * 32 + s * 8);
        }
        #pragma unroll
        for (int n = 0; n < 4; n++){
            int row = wn * 64 + n * 16 + rr;
            int s = kq ^ ((row >> 1) & 3);
            bfr[n] = *reinterpret_cast<const bf16x8*>(Bs + row * 32 + s * 8);
        }
        #pragma unroll
        for (int m = 0; m < 4; m++)
            #pragma unroll
            for (int n = 0; n < 4; n++)
                acc[m][n] = __builtin_amdgcn_mfma_f32_16x16x32_bf16(af[m], bfr[n], acc[m][n], 0, 0, 0);
        __syncthreads();
    }

    #pragma unroll
    for (int m = 0; m < 4; m++){
        #pragma unroll
        for (int n = 0; n < 4; n++){
            int col = col0 + wn * 64 + n * 16 + rr;
            int rbase = row0 + wm * 64 + m * 16 + kq * 4;
            #pragma unroll
            for (int j = 0; j < 4; j++){
                int r = rbase + j;
                float v = acc[m][n][j];
                size_t o = (size_t)r * O + col;
                if constexpr (MODE == M_KV){
                    if (col < 256) ((unsigned short*)out0)[(size_t)r * 256 + col] = f2bf(v);
                    else           ((unsigned short*)out1)[(size_t)r * 256 + col - 256] = f2bf(v);
                } else if constexpr (MODE == M_BIAS_GELU){
                    ((unsigned short*)out0)[o] = f2bf(gelu_f(v + bias[col]));
                } else if constexpr (MODE == M_BIAS_ADD2){
                    ((unsigned short*)out0)[o] = f2bf(v + bias[col] + 2.0f * bf2f(((const unsigned short*)add)[o]));
                } else if constexpr (MODE == M_BIAS){
                    ((float*)out0)[o] = v + bias[col];
                } else if constexpr (MODE == M_BIAS_BF16){
                    ((unsigned short*)out0)[o] = f2bf(v + bias[col]);
                } else if constexpr (MODE == M_BIAS_ADDX){
                    ((float*)out0)[o] = v + bias[col] + ((const float*)add)[o];
                } else if constexpr (MODE == M_ATTN){
                    if (col < 256){
                        size_t o1 = (size_t)r * 256 + col;
                        ((unsigned short*)out0)[o1] = f2bf(v + bf2f(((const unsigned short*)add)[o1]));
                    } else {
                        size_t o2 = (size_t)r * 128 + (col - 256);
                        ((unsigned short*)out1)[o2] = f2bf(v - bf2f(((const unsigned short*)bias)[o2]));
                    }
                }
            }
        }
    }
}

extern "C" void kernel_launch(void* const* d_in, const int* in_sizes, int n_in,
                              void* d_out, int out_size, void* d_ws, size_t ws_size,
                              hipStream_t stream){
    const float* x     = (const float*)d_in[0];
    const float* cor   = (const float*)d_in[1];
    const float* q_w   = (const float*)d_in[2];
    const float* kv_w  = (const float*)d_in[3];
    const float* cor_w = (const float*)d_in[4];
    const float* kln_w = (const float*)d_in[5];
    const float* kln_b = (const float*)d_in[6];
    const float* vln_w = (const float*)d_in[7];
    const float* vln_b = (const float*)d_in[8];
    const float* corln_w = (const float*)d_in[9];
    const float* corln_b = (const float*)d_in[10];
    const float* op1_w = (const float*)d_in[11];
    const float* op1_b = (const float*)d_in[12];
    const float* op2_w = (const float*)d_in[13];
    const float* op2_b = (const float*)d_in[14];
    const float* om1_w = (const float*)d_in[15];
    const float* om1_b = (const float*)d_in[16];
    const float* om2_w = (const float*)d_in[17];
    const float* om2_b = (const float*)d_in[18];
    const float* n1_w  = (const float*)d_in[19];
    const float* n1_b  = (const float*)d_in[20];
    const float* n2_w  = (const float*)d_in[21];
    const float* n2_b  = (const float*)d_in[22];
    const float* fc1_w = (const float*)d_in[23];
    const float* fc1_b = (const float*)d_in[24];
    const float* dw_w  = (const float*)d_in[25];
    const float* dw_b  = (const float*)d_in[26];
    const float* fc2_w = (const float*)d_in[27];
    const float* fc2_b = (const float*)d_in[28];

    // ---- workspace layout (bf16 elements unless noted) ----
    unsigned short* XN  = (unsigned short*)d_ws;           // NTOK*256
    unsigned short* Qb  = XN  + (size_t)NTOK * 256;        // (Q gemm removed; reused as XB)
    unsigned short* Kb  = Qb  + (size_t)NTOK * 256;
    unsigned short* Vb  = Kb  + (size_t)NTOK * 256;
    unsigned short* CEF = Vb  + (size_t)NTOK * 256;        // NTOK*128
    unsigned short* CE  = CEF + (size_t)NTOK * 128;
    float* KTV = (float*)(CE + (size_t)NTOK * 128);        // 32768 f32
    float* KTC = KTV + 32768;                              // 16384 f32
    unsigned short* WTC = (unsigned short*)(KTC + 16384);  // 4*384*256 bf16
    unsigned short* Wb  = WTC + 4 * 384 * 256;             // 753664 bf16 weights
    unsigned short* H2  = Wb + 753664;                     // NTOK*768
    // overlays (disjoint live ranges):
    unsigned short* T1 = Vb;
    unsigned short* T2 = Kb;
    unsigned short* XB = Qb;
    unsigned short* Y  = Vb;
    unsigned short* TM = CE;
    unsigned short* MH = CEF;
    unsigned short* H1 = XN;      // spans XN+Qb+Kb = NTOK*768
    float* xout = (float*)d_out;
    float* mout = xout + (size_t)NTOK * 256;

    unsigned short* w_kv  = Wb + 65536;
    unsigned short* w_op1 = Wb + 196608;
    unsigned short* w_op2 = Wb + 262144;
    unsigned short* w_om1 = Wb + 327680;
    unsigned short* w_om2 = Wb + 344064;
    unsigned short* w_fc1 = Wb + 360448;
    unsigned short* w_fc2 = Wb + 557056;

    // 0. weights -> bf16
    wconv_kernel<<<736, 256, 0, stream>>>(q_w, kv_w, op1_w, op2_w, om1_w, om2_w, fc1_w, fc2_w, Wb);
    // 1. xn = std_ln(x, norm1)
    stdln_kernel<false><<<2048, 256, 0, stream>>>(x, n1_w, n1_b, XN);
    // 2. kv = xr @ kv_w.T (swapped rows), split K,V (un-normalized)
    mgemm<M_KV, true, 256, 512><<<dim3(512, 4), 256, 0, stream>>>(XN, w_kv, nullptr, nullptr, Kb, Vb);
    // 3. ce_flat
    ce_kernel<<<2048, 256, 0, stream>>>(cor, cor_w, CEF);
    // 4. zero accumulators
    hipMemsetAsync(KTV, 0, (32768 + 16384) * sizeof(float), stream);
    // 5. fused LN + ktv + ktc
    ktvc_kernel<<<dim3(32, 16), 256, 0, stream>>>(Kb, Vb, CEF, kln_w, kln_b, vln_w, vln_b,
                                                  corln_w, corln_b, KTV, KTC);
    // 6. combined attention weights WTC[b] = q_w^T · blockdiag(ktv|ktc)
    wcomb_kernel<<<dim3(384, 4), 256, 0, stream>>>(q_w, KTV, KTC, WTC);
    // 7. [t | dm] = xn @ WTC[b] (+xn | -ce_flat)
    mgemm<M_ATTN, false, 256, 384><<<dim3(512, 3), 256, 0, stream>>>(XN, WTC, (const float*)CEF, XN, T1, TM);
    // 8. hidden = gelu(t @ op1.T + b)
    mgemm<M_BIAS_GELU, false, 256, 256><<<dim3(512, 2), 256, 0, stream>>>(T1, w_op1, op1_b, nullptr, T2, nullptr);
    // 9. x_back = (hidden @ op2.T + b) + 2*xn
    mgemm<M_BIAS_ADD2, false, 256, 256><<<dim3(512, 2), 256, 0, stream>>>(T2, w_op2, op2_b, XN, XB, nullptr);
    // 10. mh = gelu(dm @ om1.T + b)
    mgemm<M_BIAS_GELU, false, 128, 128><<<dim3(512, 1), 256, 0, stream>>>(TM, w_om1, om1_b, nullptr, MH, nullptr);
    // 11. motion = mh @ om2.T + b -> output 1 (fp32)
    mgemm<M_BIAS, false, 128, 128><<<dim3(512, 1), 256, 0, stream>>>(MH, w_om2, om2_b, nullptr, mout, nullptr);
    // 12. y = std_ln(x_back, norm2)
    stdln_kernel<true><<<2048, 256, 0, stream>>>(XB, n2_w, n2_b, Y);
    // 13. h1 = y @ fc1.T + b (bf16)
    mgemm<M_BIAS_BF16, false, 256, 768><<<dim3(512, 6), 256, 0, stream>>>(Y, w_fc1, fc1_b, nullptr, H1, nullptr);
    // 14. depthwise conv + bias + gelu (row-stationary, 2048 blocks)
    dwconv_kernel<<<2048, 192, 0, stream>>>(H1, dw_w, dw_b, H2);
    // 15. x_out = h2 @ fc2.T + b + x -> output 0 (fp32)
    mgemm<M_BIAS_ADDX, false, 768, 256><<<dim3(512, 2), 256, 0, stream>>>(H2, w_fc2, fc2_b, x, xout, nullptr);
}

// Round 6
// 494.996 us; speedup vs baseline: 5.6959x; 1.0537x over previous
//
#include <hip/hip_runtime.h>
#include <hip/hip_bf16.h>

#define NTOK 65536      // 4 * 16384 tokens

typedef __attribute__((ext_vector_type(4))) float f32x4;
typedef __attribute__((ext_vector_type(8))) short bf16x8;

__device__ __forceinline__ float gelu_f(float x){
    // tanh-form gelu, x * sigmoid(1.5957691*(x+0.044715x^3)), exp2-folded, raw v_rcp
    float z = -2.30234438f * fmaf(0.044715f * x * x, x, x);
    float e = exp2f(z);
    return x * __builtin_amdgcn_rcpf(1.0f + e);
}
__device__ __forceinline__ float bf2f(unsigned short u){
    union { unsigned int i; float f; } w; w.i = ((unsigned int)u) << 16; return w.f;
}
__device__ __forceinline__ unsigned short f2bf(float f){
    __hip_bfloat16 h = __float2bfloat16(f);
    return *reinterpret_cast<unsigned short*>(&h);
}

// ---------- weight fp32 -> bf16 conversion into contiguous Wb ----------
__global__ __launch_bounds__(256) void wconv_kernel(const float* __restrict__ q_w, const float* __restrict__ kv_w,
                                                    const float* __restrict__ op1_w, const float* __restrict__ op2_w,
                                                    const float* __restrict__ om1_w, const float* __restrict__ om2_w,
                                                    const float* __restrict__ fc1_w, const float* __restrict__ fc2_w,
                                                    unsigned short* __restrict__ Wb){
    size_t e = ((size_t)blockIdx.x * 256 + threadIdx.x) * 4;
    if (e >= 753664) return;
    const float* src; size_t off;
    if      (e <  65536){ src = q_w;   off = 0; }
    else if (e < 196608){ src = kv_w;  off = 65536; }
    else if (e < 262144){ src = op1_w; off = 196608; }
    else if (e < 327680){ src = op2_w; off = 262144; }
    else if (e < 344064){ src = om1_w; off = 327680; }
    else if (e < 360448){ src = om2_w; off = 344064; }
    else if (e < 557056){ src = fc1_w; off = 360448; }
    else                { src = fc2_w; off = 557056; }
    float4 v = *reinterpret_cast<const float4*>(src + (e - off));
    ushort4 o; o.x = f2bf(v.x); o.y = f2bf(v.y); o.z = f2bf(v.z); o.w = f2bf(v.w);
    *reinterpret_cast<ushort4*>(Wb + e) = o;
}

// ---------- std LayerNorm over 256 -> bf16 out; wave-per-token, 8 tokens/wave ----------
template<bool BF16IN>
__global__ __launch_bounds__(256) void stdln_kernel(const void* __restrict__ Xp,
                                                    const float* __restrict__ w,
                                                    const float* __restrict__ b,
                                                    unsigned short* __restrict__ out){
    int wv = threadIdx.x >> 6, lane = threadIdx.x & 63;
    int tok0 = (blockIdx.x * 4 + wv) * 8;
    int c0 = lane * 4;
    float4 w4 = *reinterpret_cast<const float4*>(w + c0);
    float4 b4 = *reinterpret_cast<const float4*>(b + c0);
    #pragma unroll 2
    for (int j = 0; j < 8; j++){
        size_t base = (size_t)(tok0 + j) * 256 + c0;
        float v[4];
        if constexpr (BF16IN){
            ushort4 u = *reinterpret_cast<const ushort4*>((const unsigned short*)Xp + base);
            v[0] = bf2f(u.x); v[1] = bf2f(u.y); v[2] = bf2f(u.z); v[3] = bf2f(u.w);
        } else {
            float4 f = *reinterpret_cast<const float4*>((const float*)Xp + base);
            v[0] = f.x; v[1] = f.y; v[2] = f.z; v[3] = f.w;
        }
        float s = v[0] + v[1] + v[2] + v[3];
        #pragma unroll
        for (int m = 1; m < 64; m <<= 1) s += __shfl_xor(s, m, 64);
        float mean = s * (1.0f / 256.0f);
        float ss = 0;
        #pragma unroll
        for (int k = 0; k < 4; k++){ v[k] -= mean; ss = fmaf(v[k], v[k], ss); }
        #pragma unroll
        for (int m = 1; m < 64; m <<= 1) ss += __shfl_xor(ss, m, 64);
        float inv = rsqrtf(ss * (1.0f / 256.0f) + 1e-5f);
        ushort4 o;
        o.x = f2bf(w4.x * v[0] * inv + b4.x);
        o.y = f2bf(w4.y * v[1] * inv + b4.y);
        o.z = f2bf(w4.z * v[2] * inv + b4.z);
        o.w = f2bf(w4.w * v[3] * inv + b4.w);
        *reinterpret_cast<ushort4*>(out + base) = o;
    }
}

// ---------- ce_flat = cor @ cor_w.T (K=2), token-blocked ----------
__global__ __launch_bounds__(256) void ce_kernel(const float* __restrict__ cor,
                                                 const float* __restrict__ cor_w,
                                                 unsigned short* __restrict__ CEF){
    int m = threadIdx.x & 127, half = threadIdx.x >> 7;
    float w0 = cor_w[m * 2 + 0], w1 = cor_w[m * 2 + 1];
    #pragma unroll 4
    for (int it = 0; it < 16; it++){
        int tok = blockIdx.x * 32 + it * 2 + half;
        float c0 = cor[(size_t)tok * 2 + 0];
        float c1 = cor[(size_t)tok * 2 + 1];
        CEF[(size_t)tok * 128 + m] = f2bf(c0 * w0 + c1 * w1);
    }
}

// ---------- fused: on-the-fly custom LN of K,V,CE + ktv & ktc reductions ----------
__global__ __launch_bounds__(256) void ktvc_kernel(const unsigned short* __restrict__ Kb,
                                                   const unsigned short* __restrict__ Vb,
                                                   const unsigned short* __restrict__ CEF,
                                                   const float* __restrict__ kw, const float* __restrict__ kbb,
                                                   const float* __restrict__ vw, const float* __restrict__ vbb,
                                                   const float* __restrict__ cw, const float* __restrict__ cbb,
                                                   float* __restrict__ KTV, float* __restrict__ KTC){
    int bh = blockIdx.x, b = bh >> 3, h = bh & 7;
    __shared__ float Ks[64][33];
    __shared__ float Vs[64][33];
    __shared__ float Cs[64][17];
    int t = threadIdx.x;
    int lr = t >> 2, lq = t & 3;
    int d0 = (t >> 4) * 2, e0 = (t & 15) * 2, e1 = t & 15;
    float kwr[8], kbr[8], vwr[8], vbr[8], cwr[4], cbr[4];
    #pragma unroll
    for (int j = 0; j < 8; j++){
        kwr[j] = kw[h * 32 + lq * 8 + j]; kbr[j] = kbb[h * 32 + lq * 8 + j];
        vwr[j] = vw[h * 32 + lq * 8 + j]; vbr[j] = vbb[h * 32 + lq * 8 + j];
    }
    #pragma unroll
    for (int j = 0; j < 4; j++){
        cwr[j] = cw[h * 16 + lq * 4 + j]; cbr[j] = cbb[h * 16 + lq * 4 + j];
    }
    float a00 = 0, a01 = 0, a10 = 0, a11 = 0;
    float c0a = 0, c1a = 0;
    size_t base = ((size_t)b << 14) + (size_t)blockIdx.y * 1024;
    for (int n0 = 0; n0 < 1024; n0 += 64){
        size_t rowi = base + n0 + lr;
        const ushort4* kp = reinterpret_cast<const ushort4*>(Kb + rowi * 256 + h * 32 + lq * 8);
        ushort4 ka = kp[0], kc = kp[1];
        const ushort4* vp = reinterpret_cast<const ushort4*>(Vb + rowi * 256 + h * 32 + lq * 8);
        ushort4 va = vp[0], vc = vp[1];
        ushort4 ca = *reinterpret_cast<const ushort4*>(CEF + rowi * 128 + h * 16 + lq * 4);
        float kvv[8] = { bf2f(ka.x), bf2f(ka.y), bf2f(ka.z), bf2f(ka.w),
                         bf2f(kc.x), bf2f(kc.y), bf2f(kc.z), bf2f(kc.w) };
        float vvv[8] = { bf2f(va.x), bf2f(va.y), bf2f(va.z), bf2f(va.w),
                         bf2f(vc.x), bf2f(vc.y), bf2f(vc.z), bf2f(vc.w) };
        float cvv[4] = { bf2f(ca.x), bf2f(ca.y), bf2f(ca.z), bf2f(ca.w) };
        float s = 0;
        #pragma unroll
        for (int j = 0; j < 8; j++) s += kvv[j];
        s += __shfl_xor(s, 1, 64); s += __shfl_xor(s, 2, 64);
        float mean = s * (1.0f / 32.0f);
        float ss = 0;
        #pragma unroll
        for (int j = 0; j < 8; j++){ kvv[j] -= mean; ss = fmaf(kvv[j], kvv[j], ss); }
        ss += __shfl_xor(ss, 1, 64); ss += __shfl_xor(ss, 2, 64);
        float inv = 1.0f / (sqrtf(ss * (1.0f / 31.0f)) + 1e-5f);
        #pragma unroll
        for (int j = 0; j < 8; j++) kvv[j] = fmaf(kwr[j] * kvv[j], inv, kbr[j]);
        s = 0;
        #pragma unroll
        for (int j = 0; j < 8; j++) s += vvv[j];
        s += __shfl_xor(s, 1, 64); s += __shfl_xor(s, 2, 64);
        mean = s * (1.0f / 32.0f);
        ss = 0;
        #pragma unroll
        for (int j = 0; j < 8; j++){ vvv[j] -= mean; ss = fmaf(vvv[j], vvv[j], ss); }
        ss += __shfl_xor(ss, 1, 64); ss += __shfl_xor(ss, 2, 64);
        inv = 1.0f / (sqrtf(ss * (1.0f / 31.0f)) + 1e-5f);
        #pragma unroll
        for (int j = 0; j < 8; j++) vvv[j] = fmaf(vwr[j] * vvv[j], inv, vbr[j]);
        s = 0;
        #pragma unroll
        for (int j = 0; j < 4; j++) s += cvv[j];
        s += __shfl_xor(s, 1, 64); s += __shfl_xor(s, 2, 64);
        mean = s * (1.0f / 16.0f);
        ss = 0;
        #pragma unroll
        for (int j = 0; j < 4; j++){ cvv[j] -= mean; ss = fmaf(cvv[j], cvv[j], ss); }
        ss += __shfl_xor(ss, 1, 64); ss += __shfl_xor(ss, 2, 64);
        inv = 1.0f / (sqrtf(ss * (1.0f / 15.0f)) + 1e-5f);
        #pragma unroll
        for (int j = 0; j < 4; j++) cvv[j] = fmaf(cwr[j] * cvv[j], inv, cbr[j]);
        __syncthreads();
        #pragma unroll
        for (int j = 0; j < 8; j++){ Ks[lr][lq * 8 + j] = kvv[j]; Vs[lr][lq * 8 + j] = vvv[j]; }
        #pragma unroll
        for (int j = 0; j < 4; j++) Cs[lr][lq * 4 + j] = cvv[j];
        __syncthreads();
        #pragma unroll 4
        for (int n = 0; n < 64; n++){
            float k0 = Ks[n][d0], k1 = Ks[n][d0 + 1];
            float v0 = Vs[n][e0], v1 = Vs[n][e0 + 1];
            float ce = Cs[n][e1];
            a00 = fmaf(k0, v0, a00); a01 = fmaf(k0, v1, a01);
            a10 = fmaf(k1, v0, a10); a11 = fmaf(k1, v1, a11);
            c0a = fmaf(k0, ce, c0a); c1a = fmaf(k1, ce, c1a);
        }
    }
    const float sc = 1.0f / 16384.0f;
    float* o = KTV + (size_t)bh * 1024;
    atomicAdd(&o[(d0 + 0) * 32 + e0 + 0], a00 * sc);
    atomicAdd(&o[(d0 + 0) * 32 + e0 + 1], a01 * sc);
    atomicAdd(&o[(d0 + 1) * 32 + e0 + 0], a10 * sc);
    atomicAdd(&o[(d0 + 1) * 32 + e0 + 1], a11 * sc);
    float* o2 = KTC + (size_t)bh * 512;
    atomicAdd(&o2[(d0 + 0) * 16 + e1], c0a * sc);
    atomicAdd(&o2[(d0 + 1) * 16 + e1], c1a * sc);
}

// ---------- combined attention weights: WTC[b][c][i], c<256: q_w^T·ktv ; c>=256: q_w^T·ktc ----------
__global__ __launch_bounds__(256) void wcomb_kernel(const float* __restrict__ q_w,
                                                    const float* __restrict__ KTV,
                                                    const float* __restrict__ KTC,
                                                    unsigned short* __restrict__ WTC){
    int c = blockIdx.x;       // 0..383
    int b = blockIdx.y;       // 0..3
    int i = threadIdx.x;      // 0..255
    __shared__ float coef[32];
    int h = (c < 256) ? (c >> 5) : ((c - 256) >> 4);
    if (i < 32){
        if (c < 256) coef[i] = KTV[(size_t)((b * 8 + h) << 10) + i * 32 + (c & 31)];
        else         coef[i] = KTC[(size_t)((b * 8 + h) << 9)  + i * 16 + ((c - 256) & 15)];
    }
    __syncthreads();
    float acc = 0;
    #pragma unroll
    for (int d = 0; d < 32; d++) acc = fmaf(q_w[(size_t)(h * 32 + d) * 256 + i], coef[d], acc);
    WTC[((size_t)b * 384 + c) * 256 + i] = f2bf(acc);
}

// ---------- depthwise 3x3 conv (SAME) + bias + gelu ----------
// 384-thread blocks (two 192-thread subgroups, each a 32-col chunk of one row).
// Raw-ushort4 4-column ring, loads issued 2 pixels ahead of use.
__global__ __launch_bounds__(384) void dwconv_kernel(const unsigned short* __restrict__ H1,
                                                     const float* __restrict__ dww,
                                                     const float* __restrict__ dwb,
                                                     unsigned short* __restrict__ H2){
    int blk = blockIdx.x;                 // 1024 = 4b * 128y * 2pair
    int sub = threadIdx.x >= 192;
    int tid = threadIdx.x - (sub ? 192 : 0);
    int bb = blk >> 8;
    int yy = (blk >> 1) & 127;
    int xq = ((blk & 1) << 1) | sub;
    int x0 = xq * 32;
    int ch = tid * 4;
    float w[9][4];
    #pragma unroll
    for (int k = 0; k < 9; k++)
        #pragma unroll
        for (int j = 0; j < 4; j++) w[k][j] = dww[(ch + j) * 9 + k];
    float bias[4] = { dwb[ch], dwb[ch+1], dwb[ch+2], dwb[ch+3] };
    const bool r0v = (yy > 0), r2v = (yy < 127);
    size_t rowbase0 = ((size_t)((bb << 14) + ((yy - 1) << 7))) * 768 + ch;
    size_t rowbase1 = ((size_t)((bb << 14) + ( yy      << 7))) * 768 + ch;
    size_t rowbase2 = ((size_t)((bb << 14) + ((yy + 1) << 7))) * 768 + ch;
    size_t obase = ((size_t)((bb << 14) + (yy << 7))) * 768 + ch;

    ushort4 rA[3], rB[3], rC[3], rD[3];
    #define LOADR(DST, XX) do {                                               \
        int _x = (XX);                                                        \
        bool xv = ((unsigned)_x <= 127u);                                     \
        DST[0] = (xv && r0v) ? *reinterpret_cast<const ushort4*>(H1 + rowbase0 + (size_t)_x * 768) : ushort4{0,0,0,0}; \
        DST[1] = (xv)        ? *reinterpret_cast<const ushort4*>(H1 + rowbase1 + (size_t)_x * 768) : ushort4{0,0,0,0}; \
        DST[2] = (xv && r2v) ? *reinterpret_cast<const ushort4*>(H1 + rowbase2 + (size_t)_x * 768) : ushort4{0,0,0,0}; \
    } while (0)

    #define EMITX(SA, SB, SC, XX) do {                                        \
        float acc[4];                                                         \
        _Pragma("unroll")                                                     \
        for (int j = 0; j < 4; j++) acc[j] = bias[j];                         \
        _Pragma("unroll")                                                     \
        for (int r = 0; r < 3; r++){                                          \
            float a0=bf2f(SA[r].x),a1=bf2f(SA[r].y),a2=bf2f(SA[r].z),a3=bf2f(SA[r].w); \
            float b0=bf2f(SB[r].x),b1=bf2f(SB[r].y),b2=bf2f(SB[r].z),b3=bf2f(SB[r].w); \
            float c0=bf2f(SC[r].x),c1=bf2f(SC[r].y),c2=bf2f(SC[r].z),c3=bf2f(SC[r].w); \
            acc[0]=fmaf(a0,w[r*3+0][0],acc[0]); acc[0]=fmaf(b0,w[r*3+1][0],acc[0]); acc[0]=fmaf(c0,w[r*3+2][0],acc[0]); \
            acc[1]=fmaf(a1,w[r*3+0][1],acc[1]); acc[1]=fmaf(b1,w[r*3+1][1],acc[1]); acc[1]=fmaf(c1,w[r*3+2][1],acc[1]); \
            acc[2]=fmaf(a2,w[r*3+0][2],acc[2]); acc[2]=fmaf(b2,w[r*3+1][2],acc[2]); acc[2]=fmaf(c2,w[r*3+2][2],acc[2]); \
            acc[3]=fmaf(a3,w[r*3+0][3],acc[3]); acc[3]=fmaf(b3,w[r*3+1][3],acc[3]); acc[3]=fmaf(c3,w[r*3+2][3],acc[3]); \
        }                                                                     \
        ushort4 o;                                                            \
        o.x = f2bf(gelu_f(acc[0])); o.y = f2bf(gelu_f(acc[1]));               \
        o.z = f2bf(gelu_f(acc[2])); o.w = f2bf(gelu_f(acc[3]));               \
        *reinterpret_cast<ushort4*>(H2 + obase + (size_t)(XX) * 768) = o;     \
    } while (0)

    LOADR(rD, x0 - 1);
    LOADR(rA, x0);
    LOADR(rB, x0 + 1);
    LOADR(rC, x0 + 2);
    #pragma unroll 1
    for (int g = 0; g < 8; g++){
        int x = x0 + g * 4;
        EMITX(rD, rA, rB, x);     LOADR(rD, x + 3);
        EMITX(rA, rB, rC, x + 1); LOADR(rA, x + 4);
        EMITX(rB, rC, rD, x + 2); LOADR(rB, x + 5);
        EMITX(rC, rD, rA, x + 3); LOADR(rC, x + 6);
    }
    #undef LOADR
    #undef EMITX
}

// ---------- bf16 MFMA GEMM, double-buffered LDS (STAGE next || MFMA cur) ----------
#define M_KV        1
#define M_BIAS_GELU 2
#define M_BIAS_ADD2 3
#define M_BIAS      4
#define M_BIAS_BF16 5
#define M_BIAS_ADDX 6
#define M_ATTN      7

template<int MODE, bool SWAP, int K, int O>
__global__ __launch_bounds__(256) void mgemm(const unsigned short* __restrict__ A,
                                             const unsigned short* __restrict__ Wp,
                                             const float* __restrict__ bias,
                                             const void* __restrict__ add,
                                             void* __restrict__ out0,
                                             void* __restrict__ out1){
    __shared__ __align__(16) unsigned short As[2][128 * 32];
    __shared__ __align__(16) unsigned short Bs[2][128 * 32];
    const int t = threadIdx.x;
    const int lane = t & 63, wid = t >> 6;
    const int wm = wid >> 1, wn = wid & 1;
    const int row0 = blockIdx.x * 128;
    const int col0 = blockIdx.y * 128;
    const unsigned short* W = Wp;
    if constexpr (MODE == M_ATTN) W += (size_t)(row0 >> 14) * (384 * 256);
    f32x4 acc[4][4];
    #pragma unroll
    for (int i = 0; i < 4; i++)
        #pragma unroll
        for (int j = 0; j < 4; j++){ f32x4 z = {0.f, 0.f, 0.f, 0.f}; acc[i][j] = z; }

    const int lr = lane >> 2;
    const int ls = lane & 3;
    const int kq = lane >> 4;
    const int rr = lane & 15;

    auto STAGE = [&](int buf, int kb){
        #pragma unroll
        for (int i = 0; i < 2; i++){
            int r = i * 64 + wid * 16 + lr;
            int ko = ls ^ ((r >> 1) & 3);
            int ga = row0 + r;
            if (SWAP) ga ^= 32768;
            __builtin_amdgcn_global_load_lds(
                (const __attribute__((address_space(1))) unsigned int*)(A + (size_t)ga * K + kb + ko * 8),
                (__attribute__((address_space(3))) unsigned int*)(As[buf] + (i * 64 + wid * 16) * 32),
                16, 0, 0);
            __builtin_amdgcn_global_load_lds(
                (const __attribute__((address_space(1))) unsigned int*)(W + (size_t)(col0 + r) * K + kb + ko * 8),
                (__attribute__((address_space(3))) unsigned int*)(Bs[buf] + (i * 64 + wid * 16) * 32),
                16, 0, 0);
        }
    };

    constexpr int NT = K / 32;
    STAGE(0, 0);
    asm volatile("s_waitcnt vmcnt(0)" ::: "memory");
    __builtin_amdgcn_s_barrier();
    #pragma unroll 1
    for (int tt = 0; tt < NT; tt++){
        int cur = tt & 1;
        if (tt + 1 < NT) STAGE(cur ^ 1, (tt + 1) * 32);
        bf16x8 af[4], bfr[4];
        #pragma unroll
        for (int m = 0; m < 4; m++){
            int row = wm * 64 + m * 16 + rr;
            int s = kq ^ ((row >> 1) & 3);
            af[m] = *reinterpret_cast<const bf16x8*>(As[cur] + row * 32 + s * 8);
        }
        #pragma unroll
        for (int n = 0; n < 4; n++){
            int row = wn * 64 + n * 16 + rr;
            int s = kq ^ ((row >> 1) & 3);
            bfr[n] = *reinterpret_cast<const bf16x8*>(Bs[cur] + row * 32 + s * 8);
        }
        #pragma unroll
        for (int m = 0; m < 4; m++)
            #pragma unroll
            for (int n = 0; n < 4; n++)
                acc[m][n] = __builtin_amdgcn_mfma_f32_16x16x32_bf16(af[m], bfr[n], acc[m][n], 0, 0, 0);
        if (tt + 1 < NT){
            asm volatile("s_waitcnt vmcnt(0)" ::: "memory");
            __builtin_amdgcn_s_barrier();
        }
    }

    #pragma unroll
    for (int m = 0; m < 4; m++){
        #pragma unroll
        for (int n = 0; n < 4; n++){
            int col = col0 + wn * 64 + n * 16 + rr;
            int rbase = row0 + wm * 64 + m * 16 + kq * 4;
            #pragma unroll
            for (int j = 0; j < 4; j++){
                int r = rbase + j;
                float v = acc[m][n][j];
                size_t o = (size_t)r * O + col;
                if constexpr (MODE == M_KV){
                    if (col < 256) ((unsigned short*)out0)[(size_t)r * 256 + col] = f2bf(v);
                    else           ((unsigned short*)out1)[(size_t)r * 256 + col - 256] = f2bf(v);
                } else if constexpr (MODE == M_BIAS_GELU){
                    ((unsigned short*)out0)[o] = f2bf(gelu_f(v + bias[col]));
                } else if constexpr (MODE == M_BIAS_ADD2){
                    ((unsigned short*)out0)[o] = f2bf(v + bias[col] + 2.0f * bf2f(((const unsigned short*)add)[o]));
                } else if constexpr (MODE == M_BIAS){
                    ((float*)out0)[o] = v + bias[col];
                } else if constexpr (MODE == M_BIAS_BF16){
                    ((unsigned short*)out0)[o] = f2bf(v + bias[col]);
                } else if constexpr (MODE == M_BIAS_ADDX){
                    ((float*)out0)[o] = v + bias[col] + ((const float*)add)[o];
                } else if constexpr (MODE == M_ATTN){
                    if (col < 256){
                        size_t o1 = (size_t)r * 256 + col;
                        ((unsigned short*)out0)[o1] = f2bf(v + bf2f(((const unsigned short*)add)[o1]));
                    } else {
                        size_t o2 = (size_t)r * 128 + (col - 256);
                        ((unsigned short*)out1)[o2] = f2bf(v - bf2f(((const unsigned short*)bias)[o2]));
                    }
                }
            }
        }
    }
}

extern "C" void kernel_launch(void* const* d_in, const int* in_sizes, int n_in,
                              void* d_out, int out_size, void* d_ws, size_t ws_size,
                              hipStream_t stream){
    const float* x     = (const float*)d_in[0];
    const float* cor   = (const float*)d_in[1];
    const float* q_w   = (const float*)d_in[2];
    const float* kv_w  = (const float*)d_in[3];
    const float* cor_w = (const float*)d_in[4];
    const float* kln_w = (const float*)d_in[5];
    const float* kln_b = (const float*)d_in[6];
    const float* vln_w = (const float*)d_in[7];
    const float* vln_b = (const float*)d_in[8];
    const float* corln_w = (const float*)d_in[9];
    const float* corln_b = (const float*)d_in[10];
    const float* op1_w = (const float*)d_in[11];
    const float* op1_b = (const float*)d_in[12];
    const float* op2_w = (const float*)d_in[13];
    const float* op2_b = (const float*)d_in[14];
    const float* om1_w = (const float*)d_in[15];
    const float* om1_b = (const float*)d_in[16];
    const float* om2_w = (const float*)d_in[17];
    const float* om2_b = (const float*)d_in[18];
    const float* n1_w  = (const float*)d_in[19];
    const float* n1_b  = (const float*)d_in[20];
    const float* n2_w  = (const float*)d_in[21];
    const float* n2_b  = (const float*)d_in[22];
    const float* fc1_w = (const float*)d_in[23];
    const float* fc1_b = (const float*)d_in[24];
    const float* dw_w  = (const float*)d_in[25];
    const float* dw_b  = (const float*)d_in[26];
    const float* fc2_w = (const float*)d_in[27];
    const float* fc2_b = (const float*)d_in[28];

    // ---- workspace layout (bf16 elements unless noted) ----
    unsigned short* XN  = (unsigned short*)d_ws;           // NTOK*256
    unsigned short* Qb  = XN  + (size_t)NTOK * 256;
    unsigned short* Kb  = Qb  + (size_t)NTOK * 256;
    unsigned short* Vb  = Kb  + (size_t)NTOK * 256;
    unsigned short* CEF = Vb  + (size_t)NTOK * 256;        // NTOK*128
    unsigned short* CE  = CEF + (size_t)NTOK * 128;
    float* KTV = (float*)(CE + (size_t)NTOK * 128);        // 32768 f32
    float* KTC = KTV + 32768;                              // 16384 f32
    unsigned short* WTC = (unsigned short*)(KTC + 16384);  // 4*384*256 bf16
    unsigned short* Wb  = WTC + 4 * 384 * 256;             // 753664 bf16 weights
    unsigned short* H2  = Wb + 753664;                     // NTOK*768
    // overlays (disjoint live ranges):
    unsigned short* T1 = Vb;
    unsigned short* T2 = Kb;
    unsigned short* XB = Qb;
    unsigned short* Y  = Vb;
    unsigned short* TM = CE;
    unsigned short* MH = CEF;
    unsigned short* H1 = XN;      // spans XN+Qb+Kb = NTOK*768
    float* xout = (float*)d_out;
    float* mout = xout + (size_t)NTOK * 256;

    unsigned short* w_kv  = Wb + 65536;
    unsigned short* w_op1 = Wb + 196608;
    unsigned short* w_op2 = Wb + 262144;
    unsigned short* w_om1 = Wb + 327680;
    unsigned short* w_om2 = Wb + 344064;
    unsigned short* w_fc1 = Wb + 360448;
    unsigned short* w_fc2 = Wb + 557056;

    // 0. weights -> bf16
    wconv_kernel<<<736, 256, 0, stream>>>(q_w, kv_w, op1_w, op2_w, om1_w, om2_w, fc1_w, fc2_w, Wb);
    // 1. xn = std_ln(x, norm1)
    stdln_kernel<false><<<2048, 256, 0, stream>>>(x, n1_w, n1_b, XN);
    // 2. kv = xr @ kv_w.T (swapped rows), split K,V (un-normalized)
    mgemm<M_KV, true, 256, 512><<<dim3(512, 4), 256, 0, stream>>>(XN, w_kv, nullptr, nullptr, Kb, Vb);
    // 3. ce_flat
    ce_kernel<<<2048, 256, 0, stream>>>(cor, cor_w, CEF);
    // 4. zero accumulators
    hipMemsetAsync(KTV, 0, (32768 + 16384) * sizeof(float), stream);
    // 5. fused LN + ktv + ktc
    ktvc_kernel<<<dim3(32, 16), 256, 0, stream>>>(Kb, Vb, CEF, kln_w, kln_b, vln_w, vln_b,
                                                  corln_w, corln_b, KTV, KTC);
    // 6. combined attention weights WTC[b] = q_w^T · blockdiag(ktv|ktc)
    wcomb_kernel<<<dim3(384, 4), 256, 0, stream>>>(q_w, KTV, KTC, WTC);
    // 7. [t | dm] = xn @ WTC[b] (+xn | -ce_flat)
    mgemm<M_ATTN, false, 256, 384><<<dim3(512, 3), 256, 0, stream>>>(XN, WTC, (const float*)CEF, XN, T1, TM);
    // 8. hidden = gelu(t @ op1.T + b)
    mgemm<M_BIAS_GELU, false, 256, 256><<<dim3(512, 2), 256, 0, stream>>>(T1, w_op1, op1_b, nullptr, T2, nullptr);
    // 9. x_back = (hidden @ op2.T + b) + 2*xn
    mgemm<M_BIAS_ADD2, false, 256, 256><<<dim3(512, 2), 256, 0, stream>>>(T2, w_op2, op2_b, XN, XB, nullptr);
    // 10. mh = gelu(dm @ om1.T + b)
    mgemm<M_BIAS_GELU, false, 128, 128><<<dim3(512, 1), 256, 0, stream>>>(TM, w_om1, om1_b, nullptr, MH, nullptr);
    // 11. motion = mh @ om2.T + b -> output 1 (fp32)
    mgemm<M_BIAS, false, 128, 128><<<dim3(512, 1), 256, 0, stream>>>(MH, w_om2, om2_b, nullptr, mout, nullptr);
    // 12. y = std_ln(x_back, norm2)
    stdln_kernel<true><<<2048, 256, 0, stream>>>(XB, n2_w, n2_b, Y);
    // 13. h1 = y @ fc1.T + b (bf16)
    mgemm<M_BIAS_BF16, false, 256, 768><<<dim3(512, 6), 256, 0, stream>>>(Y, w_fc1, fc1_b, nullptr, H1, nullptr);
    // 14. depthwise conv + bias + gelu (deep-prefetch, 384-thread blocks)
    dwconv_kernel<<<1024, 384, 0, stream>>>(H1, dw_w, dw_b, H2);
    // 15. x_out = h2 @ fc2.T + b + x -> output 0 (fp32)
    mgemm<M_BIAS_ADDX, false, 768, 256><<<dim3(512, 2), 256, 0, stream>>>(H2, w_fc2, fc2_b, x, xout, nullptr);
}

// Round 7
// 443.813 us; speedup vs baseline: 6.3528x; 1.1153x over previous
//
#include <hip/hip_runtime.h>
#include <hip/hip_bf16.h>

#define NTOK 65536      // 4 * 16384 tokens

typedef __attribute__((ext_vector_type(4))) float f32x4;
typedef __attribute__((ext_vector_type(8))) short bf16x8;

__device__ __forceinline__ float gelu_f(float x){
    float z = -2.30234438f * fmaf(0.044715f * x * x, x, x);
    float e = exp2f(z);
    return x * __builtin_amdgcn_rcpf(1.0f + e);
}
__device__ __forceinline__ float bf2f(unsigned short u){
    union { unsigned int i; float f; } w; w.i = ((unsigned int)u) << 16; return w.f;
}
__device__ __forceinline__ unsigned short f2bf(float f){
    __hip_bfloat16 h = __float2bfloat16(f);
    return *reinterpret_cast<unsigned short*>(&h);
}

// ---------- weight fp32 -> bf16 conversion into contiguous Wb ----------
__global__ __launch_bounds__(256) void wconv_kernel(const float* __restrict__ q_w, const float* __restrict__ kv_w,
                                                    const float* __restrict__ op1_w, const float* __restrict__ op2_w,
                                                    const float* __restrict__ om1_w, const float* __restrict__ om2_w,
                                                    const float* __restrict__ fc1_w, const float* __restrict__ fc2_w,
                                                    unsigned short* __restrict__ Wb){
    size_t e = ((size_t)blockIdx.x * 256 + threadIdx.x) * 4;
    if (e >= 753664) return;
    const float* src; size_t off;
    if      (e <  65536){ src = q_w;   off = 0; }
    else if (e < 196608){ src = kv_w;  off = 65536; }
    else if (e < 262144){ src = op1_w; off = 196608; }
    else if (e < 327680){ src = op2_w; off = 262144; }
    else if (e < 344064){ src = om1_w; off = 327680; }
    else if (e < 360448){ src = om2_w; off = 344064; }
    else if (e < 557056){ src = fc1_w; off = 360448; }
    else                { src = fc2_w; off = 557056; }
    float4 v = *reinterpret_cast<const float4*>(src + (e - off));
    ushort4 o; o.x = f2bf(v.x); o.y = f2bf(v.y); o.z = f2bf(v.z); o.w = f2bf(v.w);
    *reinterpret_cast<ushort4*>(Wb + e) = o;
}

// ---------- std LayerNorm over 256 -> bf16 out; wave-per-token, 8 tokens/wave ----------
template<bool BF16IN>
__global__ __launch_bounds__(256) void stdln_kernel(const void* __restrict__ Xp,
                                                    const float* __restrict__ w,
                                                    const float* __restrict__ b,
                                                    unsigned short* __restrict__ out){
    int wv = threadIdx.x >> 6, lane = threadIdx.x & 63;
    int tok0 = (blockIdx.x * 4 + wv) * 8;
    int c0 = lane * 4;
    float4 w4 = *reinterpret_cast<const float4*>(w + c0);
    float4 b4 = *reinterpret_cast<const float4*>(b + c0);
    #pragma unroll 2
    for (int j = 0; j < 8; j++){
        size_t base = (size_t)(tok0 + j) * 256 + c0;
        float v[4];
        if constexpr (BF16IN){
            ushort4 u = *reinterpret_cast<const ushort4*>((const unsigned short*)Xp + base);
            v[0] = bf2f(u.x); v[1] = bf2f(u.y); v[2] = bf2f(u.z); v[3] = bf2f(u.w);
        } else {
            float4 f = *reinterpret_cast<const float4*>((const float*)Xp + base);
            v[0] = f.x; v[1] = f.y; v[2] = f.z; v[3] = f.w;
        }
        float s = v[0] + v[1] + v[2] + v[3];
        #pragma unroll
        for (int m = 1; m < 64; m <<= 1) s += __shfl_xor(s, m, 64);
        float mean = s * (1.0f / 256.0f);
        float ss = 0;
        #pragma unroll
        for (int k = 0; k < 4; k++){ v[k] -= mean; ss = fmaf(v[k], v[k], ss); }
        #pragma unroll
        for (int m = 1; m < 64; m <<= 1) ss += __shfl_xor(ss, m, 64);
        float inv = rsqrtf(ss * (1.0f / 256.0f) + 1e-5f);
        ushort4 o;
        o.x = f2bf(w4.x * v[0] * inv + b4.x);
        o.y = f2bf(w4.y * v[1] * inv + b4.y);
        o.z = f2bf(w4.z * v[2] * inv + b4.z);
        o.w = f2bf(w4.w * v[3] * inv + b4.w);
        *reinterpret_cast<ushort4*>(out + base) = o;
    }
}

// ---------- ce_flat = cor @ cor_w.T (K=2), token-blocked ----------
__global__ __launch_bounds__(256) void ce_kernel(const float* __restrict__ cor,
                                                 const float* __restrict__ cor_w,
                                                 unsigned short* __restrict__ CEF){
    int m = threadIdx.x & 127, half = threadIdx.x >> 7;
    float w0 = cor_w[m * 2 + 0], w1 = cor_w[m * 2 + 1];
    #pragma unroll 4
    for (int it = 0; it < 16; it++){
        int tok = blockIdx.x * 32 + it * 2 + half;
        float c0 = cor[(size_t)tok * 2 + 0];
        float c1 = cor[(size_t)tok * 2 + 1];
        CEF[(size_t)tok * 128 + m] = f2bf(c0 * w0 + c1 * w1);
    }
}

// ---------- fused: on-the-fly custom LN of K,V,CE + ktv & ktc reductions ----------
__global__ __launch_bounds__(256) void ktvc_kernel(const unsigned short* __restrict__ Kb,
                                                   const unsigned short* __restrict__ Vb,
                                                   const unsigned short* __restrict__ CEF,
                                                   const float* __restrict__ kw, const float* __restrict__ kbb,
                                                   const float* __restrict__ vw, const float* __restrict__ vbb,
                                                   const float* __restrict__ cw, const float* __restrict__ cbb,
                                                   float* __restrict__ KTV, float* __restrict__ KTC){
    int bh = blockIdx.x, b = bh >> 3, h = bh & 7;
    __shared__ float Ks[64][33];
    __shared__ float Vs[64][33];
    __shared__ float Cs[64][17];
    int t = threadIdx.x;
    int lr = t >> 2, lq = t & 3;
    int d0 = (t >> 4) * 2, e0 = (t & 15) * 2, e1 = t & 15;
    float kwr[8], kbr[8], vwr[8], vbr[8], cwr[4], cbr[4];
    #pragma unroll
    for (int j = 0; j < 8; j++){
        kwr[j] = kw[h * 32 + lq * 8 + j]; kbr[j] = kbb[h * 32 + lq * 8 + j];
        vwr[j] = vw[h * 32 + lq * 8 + j]; vbr[j] = vbb[h * 32 + lq * 8 + j];
    }
    #pragma unroll
    for (int j = 0; j < 4; j++){
        cwr[j] = cw[h * 16 + lq * 4 + j]; cbr[j] = cbb[h * 16 + lq * 4 + j];
    }
    float a00 = 0, a01 = 0, a10 = 0, a11 = 0;
    float c0a = 0, c1a = 0;
    size_t base = ((size_t)b << 14) + (size_t)blockIdx.y * 1024;
    for (int n0 = 0; n0 < 1024; n0 += 64){
        size_t rowi = base + n0 + lr;
        const ushort4* kp = reinterpret_cast<const ushort4*>(Kb + rowi * 256 + h * 32 + lq * 8);
        ushort4 ka = kp[0], kc = kp[1];
        const ushort4* vp = reinterpret_cast<const ushort4*>(Vb + rowi * 256 + h * 32 + lq * 8);
        ushort4 va = vp[0], vc = vp[1];
        ushort4 ca = *reinterpret_cast<const ushort4*>(CEF + rowi * 128 + h * 16 + lq * 4);
        float kvv[8] = { bf2f(ka.x), bf2f(ka.y), bf2f(ka.z), bf2f(ka.w),
                         bf2f(kc.x), bf2f(kc.y), bf2f(kc.z), bf2f(kc.w) };
        float vvv[8] = { bf2f(va.x), bf2f(va.y), bf2f(va.z), bf2f(va.w),
                         bf2f(vc.x), bf2f(vc.y), bf2f(vc.z), bf2f(vc.w) };
        float cvv[4] = { bf2f(ca.x), bf2f(ca.y), bf2f(ca.z), bf2f(ca.w) };
        float s = 0;
        #pragma unroll
        for (int j = 0; j < 8; j++) s += kvv[j];
        s += __shfl_xor(s, 1, 64); s += __shfl_xor(s, 2, 64);
        float mean = s * (1.0f / 32.0f);
        float ss = 0;
        #pragma unroll
        for (int j = 0; j < 8; j++){ kvv[j] -= mean; ss = fmaf(kvv[j], kvv[j], ss); }
        ss += __shfl_xor(ss, 1, 64); ss += __shfl_xor(ss, 2, 64);
        float inv = 1.0f / (sqrtf(ss * (1.0f / 31.0f)) + 1e-5f);
        #pragma unroll
        for (int j = 0; j < 8; j++) kvv[j] = fmaf(kwr[j] * kvv[j], inv, kbr[j]);
        s = 0;
        #pragma unroll
        for (int j = 0; j < 8; j++) s += vvv[j];
        s += __shfl_xor(s, 1, 64); s += __shfl_xor(s, 2, 64);
        mean = s * (1.0f / 32.0f);
        ss = 0;
        #pragma unroll
        for (int j = 0; j < 8; j++){ vvv[j] -= mean; ss = fmaf(vvv[j], vvv[j], ss); }
        ss += __shfl_xor(ss, 1, 64); ss += __shfl_xor(ss, 2, 64);
        inv = 1.0f / (sqrtf(ss * (1.0f / 31.0f)) + 1e-5f);
        #pragma unroll
        for (int j = 0; j < 8; j++) vvv[j] = fmaf(vwr[j] * vvv[j], inv, vbr[j]);
        s = 0;
        #pragma unroll
        for (int j = 0; j < 4; j++) s += cvv[j];
        s += __shfl_xor(s, 1, 64); s += __shfl_xor(s, 2, 64);
        mean = s * (1.0f / 16.0f);
        ss = 0;
        #pragma unroll
        for (int j = 0; j < 4; j++){ cvv[j] -= mean; ss = fmaf(cvv[j], cvv[j], ss); }
        ss += __shfl_xor(ss, 1, 64); ss += __shfl_xor(ss, 2, 64);
        inv = 1.0f / (sqrtf(ss * (1.0f / 15.0f)) + 1e-5f);
        #pragma unroll
        for (int j = 0; j < 4; j++) cvv[j] = fmaf(cwr[j] * cvv[j], inv, cbr[j]);
        __syncthreads();
        #pragma unroll
        for (int j = 0; j < 8; j++){ Ks[lr][lq * 8 + j] = kvv[j]; Vs[lr][lq * 8 + j] = vvv[j]; }
        #pragma unroll
        for (int j = 0; j < 4; j++) Cs[lr][lq * 4 + j] = cvv[j];
        __syncthreads();
        #pragma unroll 4
        for (int n = 0; n < 64; n++){
            float k0 = Ks[n][d0], k1 = Ks[n][d0 + 1];
            float v0 = Vs[n][e0], v1 = Vs[n][e0 + 1];
            float ce = Cs[n][e1];
            a00 = fmaf(k0, v0, a00); a01 = fmaf(k0, v1, a01);
            a10 = fmaf(k1, v0, a10); a11 = fmaf(k1, v1, a11);
            c0a = fmaf(k0, ce, c0a); c1a = fmaf(k1, ce, c1a);
        }
    }
    const float sc = 1.0f / 16384.0f;
    float* o = KTV + (size_t)bh * 1024;
    atomicAdd(&o[(d0 + 0) * 32 + e0 + 0], a00 * sc);
    atomicAdd(&o[(d0 + 0) * 32 + e0 + 1], a01 * sc);
    atomicAdd(&o[(d0 + 1) * 32 + e0 + 0], a10 * sc);
    atomicAdd(&o[(d0 + 1) * 32 + e0 + 1], a11 * sc);
    float* o2 = KTC + (size_t)bh * 512;
    atomicAdd(&o2[(d0 + 0) * 16 + e1], c0a * sc);
    atomicAdd(&o2[(d0 + 1) * 16 + e1], c1a * sc);
}

// ---------- combined attention weights: WTC[b][c][i], c<256: q_w^T·ktv ; c>=256: q_w^T·ktc ----------
__global__ __launch_bounds__(256) void wcomb_kernel(const float* __restrict__ q_w,
                                                    const float* __restrict__ KTV,
                                                    const float* __restrict__ KTC,
                                                    unsigned short* __restrict__ WTC){
    int c = blockIdx.x;
    int b = blockIdx.y;
    int i = threadIdx.x;
    __shared__ float coef[32];
    int h = (c < 256) ? (c >> 5) : ((c - 256) >> 4);
    if (i < 32){
        if (c < 256) coef[i] = KTV[(size_t)((b * 8 + h) << 10) + i * 32 + (c & 31)];
        else         coef[i] = KTC[(size_t)((b * 8 + h) << 9)  + i * 16 + ((c - 256) & 15)];
    }
    __syncthreads();
    float acc = 0;
    #pragma unroll
    for (int d = 0; d < 32; d++) acc = fmaf(q_w[(size_t)(h * 32 + d) * 256 + i], coef[d], acc);
    WTC[((size_t)b * 384 + c) * 256 + i] = f2bf(acc);
}

// ---------- depthwise 3x3 conv (SAME) + bias + gelu, y-banded (4 rows/block) ----------
// 512 blocks = 4b x 32yband x 4xq; 192 threads x 4 ch; ring of 4 cols x 6 rows in regs.
// 6 loads per x-step produce 4 output rows -> 1.5 loads/pixel.
__global__ __launch_bounds__(192) void dwconv_kernel(const unsigned short* __restrict__ H1,
                                                     const float* __restrict__ dww,
                                                     const float* __restrict__ dwb,
                                                     unsigned short* __restrict__ H2){
    int blk = blockIdx.x;
    int xq = blk & 3;
    int yb = (blk >> 2) & 31;
    int bb = blk >> 7;
    int y0 = yb * 4, x0 = xq * 32;
    int ch = threadIdx.x * 4;
    float w[9][4];
    #pragma unroll
    for (int k = 0; k < 9; k++)
        #pragma unroll
        for (int j = 0; j < 4; j++) w[k][j] = dww[(ch + j) * 9 + k];
    float bias[4] = { dwb[ch], dwb[ch+1], dwb[ch+2], dwb[ch+3] };
    size_t rb[6]; bool rv[6];
    #pragma unroll
    for (int r = 0; r < 6; r++){
        int yr = y0 - 1 + r;
        rv[r] = ((unsigned)yr <= 127u);
        int yc = yr < 0 ? 0 : (yr > 127 ? 127 : yr);
        rb[r] = ((size_t)((bb << 14) + (yc << 7))) * 768 + ch;
    }
    size_t ob[4];
    #pragma unroll
    for (int j = 0; j < 4; j++) ob[j] = ((size_t)((bb << 14) + ((y0 + j) << 7))) * 768 + ch;

    ushort4 cA[6], cB[6], cC[6], cD[6];
    const ushort4 Z = {0, 0, 0, 0};
    #define LOADR(DST, XX) do {                                               \
        int _x = (XX);                                                        \
        bool xv = ((unsigned)_x <= 127u);                                     \
        _Pragma("unroll")                                                     \
        for (int r = 0; r < 6; r++)                                           \
            DST[r] = (xv && rv[r]) ? *reinterpret_cast<const ushort4*>(H1 + rb[r] + (size_t)_x * 768) : Z; \
    } while (0)

    // output row j uses input ring rows j..j+2; SA=col x-1, SB=col x, SC=col x+1
    #define EMITB(SA, SB, SC, XX) do {                                        \
        _Pragma("unroll")                                                     \
        for (int j = 0; j < 4; j++){                                          \
            float acc[4];                                                     \
            _Pragma("unroll")                                                 \
            for (int q = 0; q < 4; q++) acc[q] = bias[q];                     \
            _Pragma("unroll")                                                 \
            for (int rr2 = 0; rr2 < 3; rr2++){                                \
                int ri = j + rr2;                                             \
                float a0=bf2f(SA[ri].x),a1=bf2f(SA[ri].y),a2=bf2f(SA[ri].z),a3=bf2f(SA[ri].w); \
                float b0=bf2f(SB[ri].x),b1=bf2f(SB[ri].y),b2=bf2f(SB[ri].z),b3=bf2f(SB[ri].w); \
                float c0=bf2f(SC[ri].x),c1=bf2f(SC[ri].y),c2=bf2f(SC[ri].z),c3=bf2f(SC[ri].w); \
                acc[0]=fmaf(a0,w[rr2*3+0][0],acc[0]); acc[0]=fmaf(b0,w[rr2*3+1][0],acc[0]); acc[0]=fmaf(c0,w[rr2*3+2][0],acc[0]); \
                acc[1]=fmaf(a1,w[rr2*3+0][1],acc[1]); acc[1]=fmaf(b1,w[rr2*3+1][1],acc[1]); acc[1]=fmaf(c1,w[rr2*3+2][1],acc[1]); \
                acc[2]=fmaf(a2,w[rr2*3+0][2],acc[2]); acc[2]=fmaf(b2,w[rr2*3+1][2],acc[2]); acc[2]=fmaf(c2,w[rr2*3+2][2],acc[2]); \
                acc[3]=fmaf(a3,w[rr2*3+0][3],acc[3]); acc[3]=fmaf(b3,w[rr2*3+1][3],acc[3]); acc[3]=fmaf(c3,w[rr2*3+2][3],acc[3]); \
            }                                                                 \
            ushort4 o;                                                        \
            o.x = f2bf(gelu_f(acc[0])); o.y = f2bf(gelu_f(acc[1]));           \
            o.z = f2bf(gelu_f(acc[2])); o.w = f2bf(gelu_f(acc[3]));           \
            *reinterpret_cast<ushort4*>(H2 + ob[j] + (size_t)(XX) * 768) = o; \
        }                                                                     \
    } while (0)

    LOADR(cD, x0 - 1);
    LOADR(cA, x0);
    LOADR(cB, x0 + 1);
    LOADR(cC, x0 + 2);
    #pragma unroll 1
    for (int g = 0; g < 8; g++){
        int x = x0 + g * 4;
        EMITB(cD, cA, cB, x);     LOADR(cD, x + 3);
        EMITB(cA, cB, cC, x + 1); LOADR(cA, x + 4);
        EMITB(cB, cC, cD, x + 2); LOADR(cB, x + 5);
        EMITB(cC, cD, cA, x + 3); LOADR(cC, x + 6);
    }
    #undef LOADR
    #undef EMITB
}

// ---------- bf16 MFMA GEMM, wide-N blocks (A staged once per block), double-buffered LDS ----------
#define M_KV        1
#define M_BIAS_GELU 2
#define M_BIAS_ADD2 3
#define M_BIAS      4
#define M_BIAS_BF16 5
#define M_BIAS_ADDX 6
#define M_ATTN      7

template<int MODE, bool SWAP, int K, int O, int WN>
__global__ __launch_bounds__(128 * WN) void mgemm(const unsigned short* __restrict__ A,
                                                  const unsigned short* __restrict__ Wp,
                                                  const float* __restrict__ bias,
                                                  const void* __restrict__ add,
                                                  void* __restrict__ out0,
                                                  void* __restrict__ out1){
    constexpr int WAVES = 2 * WN;
    constexpr int BN = 64 * WN;
    constexpr int CH = 8 + 4 * WN;       // 16-row chunks: 8 for A, 4*WN for B
    constexpr int NT = K / 32;
    __shared__ __align__(16) unsigned short As[2][128 * 32];
    __shared__ __align__(16) unsigned short Bs[2][BN * 32];
    const int t = threadIdx.x;
    const int lane = t & 63, wid = t >> 6;
    const int wm = wid & 1, wn = wid >> 1;
    const int row0 = blockIdx.x * 128;
    const int colB = blockIdx.y * BN;
    const unsigned short* W = Wp;
    if constexpr (MODE == M_ATTN) W += (size_t)(row0 >> 14) * (384 * 256);
    f32x4 acc[4][4];
    #pragma unroll
    for (int i = 0; i < 4; i++)
        #pragma unroll
        for (int j = 0; j < 4; j++){ f32x4 z = {0.f, 0.f, 0.f, 0.f}; acc[i][j] = z; }

    const int lr = lane >> 2;
    const int ls = lane & 3;
    const int kq = lane >> 4;
    const int rr = lane & 15;

    auto STAGE = [&](int buf, int kb){
        #pragma unroll
        for (int c = wid; c < CH; c += WAVES){
            int r16 = (c < 8) ? c : (c - 8);
            int row = r16 * 16 + lr;
            int ko = ls ^ ((row >> 1) & 3);
            if (c < 8){
                int ga = row0 + row;
                if (SWAP) ga ^= 32768;
                __builtin_amdgcn_global_load_lds(
                    (const __attribute__((address_space(1))) unsigned int*)(A + (size_t)ga * K + kb + ko * 8),
                    (__attribute__((address_space(3))) unsigned int*)(As[buf] + r16 * 512),
                    16, 0, 0);
            } else {
                int gc = colB + row;
                __builtin_amdgcn_global_load_lds(
                    (const __attribute__((address_space(1))) unsigned int*)(W + (size_t)gc * K + kb + ko * 8),
                    (__attribute__((address_space(3))) unsigned int*)(Bs[buf] + r16 * 512),
                    16, 0, 0);
            }
        }
    };

    STAGE(0, 0);
    asm volatile("s_waitcnt vmcnt(0)" ::: "memory");
    __builtin_amdgcn_s_barrier();
    #pragma unroll 1
    for (int tt = 0; tt < NT; tt++){
        int cur = tt & 1;
        if (tt + 1 < NT) STAGE(cur ^ 1, (tt + 1) * 32);
        bf16x8 af[4], bfr[4];
        #pragma unroll
        for (int m = 0; m < 4; m++){
            int row = wm * 64 + m * 16 + rr;
            int s = kq ^ ((row >> 1) & 3);
            af[m] = *reinterpret_cast<const bf16x8*>(As[cur] + row * 32 + s * 8);
        }
        #pragma unroll
        for (int n = 0; n < 4; n++){
            int row = wn * 64 + n * 16 + rr;
            int s = kq ^ ((row >> 1) & 3);
            bfr[n] = *reinterpret_cast<const bf16x8*>(Bs[cur] + row * 32 + s * 8);
        }
        #pragma unroll
        for (int m = 0; m < 4; m++)
            #pragma unroll
            for (int n = 0; n < 4; n++)
                acc[m][n] = __builtin_amdgcn_mfma_f32_16x16x32_bf16(af[m], bfr[n], acc[m][n], 0, 0, 0);
        if (tt + 1 < NT){
            asm volatile("s_waitcnt vmcnt(0)" ::: "memory");
            __builtin_amdgcn_s_barrier();
        }
    }

    #pragma unroll
    for (int m = 0; m < 4; m++){
        #pragma unroll
        for (int n = 0; n < 4; n++){
            int col = colB + wn * 64 + n * 16 + rr;
            int rbase = row0 + wm * 64 + m * 16 + kq * 4;
            #pragma unroll
            for (int j = 0; j < 4; j++){
                int r = rbase + j;
                float v = acc[m][n][j];
                size_t o = (size_t)r * O + col;
                if constexpr (MODE == M_KV){
                    if (col < 256) ((unsigned short*)out0)[(size_t)r * 256 + col] = f2bf(v);
                    else           ((unsigned short*)out1)[(size_t)r * 256 + col - 256] = f2bf(v);
                } else if constexpr (MODE == M_BIAS_GELU){
                    ((unsigned short*)out0)[o] = f2bf(gelu_f(v + bias[col]));
                } else if constexpr (MODE == M_BIAS_ADD2){
                    ((unsigned short*)out0)[o] = f2bf(v + bias[col] + 2.0f * bf2f(((const unsigned short*)add)[o]));
                } else if constexpr (MODE == M_BIAS){
                    ((float*)out0)[o] = v + bias[col];
                } else if constexpr (MODE == M_BIAS_BF16){
                    ((unsigned short*)out0)[o] = f2bf(v + bias[col]);
                } else if constexpr (MODE == M_BIAS_ADDX){
                    ((float*)out0)[o] = v + bias[col] + ((const float*)add)[o];
                } else if constexpr (MODE == M_ATTN){
                    if (col < 256){
                        size_t o1 = (size_t)r * 256 + col;
                        ((unsigned short*)out0)[o1] = f2bf(v + bf2f(((const unsigned short*)add)[o1]));
                    } else {
                        size_t o2 = (size_t)r * 128 + (col - 256);
                        ((unsigned short*)out1)[o2] = f2bf(v - bf2f(((const unsigned short*)bias)[o2]));
                    }
                }
            }
        }
    }
}

extern "C" void kernel_launch(void* const* d_in, const int* in_sizes, int n_in,
                              void* d_out, int out_size, void* d_ws, size_t ws_size,
                              hipStream_t stream){
    const float* x     = (const float*)d_in[0];
    const float* cor   = (const float*)d_in[1];
    const float* q_w   = (const float*)d_in[2];
    const float* kv_w  = (const float*)d_in[3];
    const float* cor_w = (const float*)d_in[4];
    const float* kln_w = (const float*)d_in[5];
    const float* kln_b = (const float*)d_in[6];
    const float* vln_w = (const float*)d_in[7];
    const float* vln_b = (const float*)d_in[8];
    const float* corln_w = (const float*)d_in[9];
    const float* corln_b = (const float*)d_in[10];
    const float* op1_w = (const float*)d_in[11];
    const float* op1_b = (const float*)d_in[12];
    const float* op2_w = (const float*)d_in[13];
    const float* op2_b = (const float*)d_in[14];
    const float* om1_w = (const float*)d_in[15];
    const float* om1_b = (const float*)d_in[16];
    const float* om2_w = (const float*)d_in[17];
    const float* om2_b = (const float*)d_in[18];
    const float* n1_w  = (const float*)d_in[19];
    const float* n1_b  = (const float*)d_in[20];
    const float* n2_w  = (const float*)d_in[21];
    const float* n2_b  = (const float*)d_in[22];
    const float* fc1_w = (const float*)d_in[23];
    const float* fc1_b = (const float*)d_in[24];
    const float* dw_w  = (const float*)d_in[25];
    const float* dw_b  = (const float*)d_in[26];
    const float* fc2_w = (const float*)d_in[27];
    const float* fc2_b = (const float*)d_in[28];

    // ---- workspace layout (bf16 elements unless noted) ----
    unsigned short* XN  = (unsigned short*)d_ws;           // NTOK*256
    unsigned short* Qb  = XN  + (size_t)NTOK * 256;
    unsigned short* Kb  = Qb  + (size_t)NTOK * 256;
    unsigned short* Vb  = Kb  + (size_t)NTOK * 256;
    unsigned short* CEF = Vb  + (size_t)NTOK * 256;        // NTOK*128
    unsigned short* CE  = CEF + (size_t)NTOK * 128;
    float* KTV = (float*)(CE + (size_t)NTOK * 128);        // 32768 f32
    float* KTC = KTV + 32768;                              // 16384 f32
    unsigned short* WTC = (unsigned short*)(KTC + 16384);  // 4*384*256 bf16
    unsigned short* Wb  = WTC + 4 * 384 * 256;             // 753664 bf16 weights
    unsigned short* H2  = Wb + 753664;                     // NTOK*768
    // overlays (disjoint live ranges):
    unsigned short* T1 = Vb;
    unsigned short* T2 = Kb;
    unsigned short* XB = Qb;
    unsigned short* Y  = Vb;
    unsigned short* TM = CE;
    unsigned short* MH = CEF;
    unsigned short* H1 = XN;      // spans XN+Qb+Kb = NTOK*768
    float* xout = (float*)d_out;
    float* mout = xout + (size_t)NTOK * 256;

    unsigned short* w_kv  = Wb + 65536;
    unsigned short* w_op1 = Wb + 196608;
    unsigned short* w_op2 = Wb + 262144;
    unsigned short* w_om1 = Wb + 327680;
    unsigned short* w_om2 = Wb + 344064;
    unsigned short* w_fc1 = Wb + 360448;
    unsigned short* w_fc2 = Wb + 557056;

    // 0. weights -> bf16
    wconv_kernel<<<736, 256, 0, stream>>>(q_w, kv_w, op1_w, op2_w, om1_w, om2_w, fc1_w, fc2_w, Wb);
    // 1. xn = std_ln(x, norm1)
    stdln_kernel<false><<<2048, 256, 0, stream>>>(x, n1_w, n1_b, XN);
    // 2. kv = xr @ kv_w.T (swapped rows), split K,V (un-normalized)  [WN=4, y=2 -> A read 2x]
    mgemm<M_KV, true, 256, 512, 4><<<dim3(512, 2), 512, 0, stream>>>(XN, w_kv, nullptr, nullptr, Kb, Vb);
    // 3. ce_flat
    ce_kernel<<<2048, 256, 0, stream>>>(cor, cor_w, CEF);
    // 4. zero accumulators
    hipMemsetAsync(KTV, 0, (32768 + 16384) * sizeof(float), stream);
    // 5. fused LN + ktv + ktc
    ktvc_kernel<<<dim3(32, 16), 256, 0, stream>>>(Kb, Vb, CEF, kln_w, kln_b, vln_w, vln_b,
                                                  corln_w, corln_b, KTV, KTC);
    // 6. combined attention weights WTC[b] = q_w^T · blockdiag(ktv|ktc)
    wcomb_kernel<<<dim3(384, 4), 256, 0, stream>>>(q_w, KTV, KTC, WTC);
    // 7. [t | dm] = xn @ WTC[b] (+xn | -ce_flat)  [WN=6 -> full width, A read 1x]
    mgemm<M_ATTN, false, 256, 384, 6><<<dim3(512, 1), 768, 0, stream>>>(XN, WTC, (const float*)CEF, XN, T1, TM);
    // 8. hidden = gelu(t @ op1.T + b)  [WN=4 -> A read 1x]
    mgemm<M_BIAS_GELU, false, 256, 256, 4><<<dim3(512, 1), 512, 0, stream>>>(T1, w_op1, op1_b, nullptr, T2, nullptr);
    // 9. x_back = (hidden @ op2.T + b) + 2*xn
    mgemm<M_BIAS_ADD2, false, 256, 256, 4><<<dim3(512, 1), 512, 0, stream>>>(T2, w_op2, op2_b, XN, XB, nullptr);
    // 10. mh = gelu(dm @ om1.T + b)
    mgemm<M_BIAS_GELU, false, 128, 128, 2><<<dim3(512, 1), 256, 0, stream>>>(TM, w_om1, om1_b, nullptr, MH, nullptr);
    // 11. motion = mh @ om2.T + b -> output 1 (fp32)
    mgemm<M_BIAS, false, 128, 128, 2><<<dim3(512, 1), 256, 0, stream>>>(MH, w_om2, om2_b, nullptr, mout, nullptr);
    // 12. y = std_ln(x_back, norm2)
    stdln_kernel<true><<<2048, 256, 0, stream>>>(XB, n2_w, n2_b, Y);
    // 13. h1 = y @ fc1.T + b (bf16)  [WN=6, y=2 -> A read 2x vs 6x]
    mgemm<M_BIAS_BF16, false, 256, 768, 6><<<dim3(512, 2), 768, 0, stream>>>(Y, w_fc1, fc1_b, nullptr, H1, nullptr);
    // 14. depthwise conv + bias + gelu (y-banded)
    dwconv_kernel<<<512, 192, 0, stream>>>(H1, dw_w, dw_b, H2);
    // 15. x_out = h2 @ fc2.T + b + x -> output 0 (fp32)  [WN=4 -> A read 1x]
    mgemm<M_BIAS_ADDX, false, 768, 256, 4><<<dim3(512, 1), 512, 0, stream>>>(H2, w_fc2, fc2_b, x, xout, nullptr);
}

// Round 8
// 424.157 us; speedup vs baseline: 6.6472x; 1.0463x over previous
//
#include <hip/hip_runtime.h>
#include <hip/hip_bf16.h>

#define NTOK 65536      // 4 * 16384 tokens

typedef __attribute__((ext_vector_type(4))) float f32x4;
typedef __attribute__((ext_vector_type(8))) short bf16x8;

__device__ __forceinline__ float gelu_f(float x){
    float z = -2.30234438f * fmaf(0.044715f * x * x, x, x);
    float e = exp2f(z);
    return x * __builtin_amdgcn_rcpf(1.0f + e);
}
__device__ __forceinline__ float bf2f(unsigned short u){
    union { unsigned int i; float f; } w; w.i = ((unsigned int)u) << 16; return w.f;
}
__device__ __forceinline__ unsigned short f2bf(float f){
    __hip_bfloat16 h = __float2bfloat16(f);
    return *reinterpret_cast<unsigned short*>(&h);
}

// ---------- weight fp32 -> bf16 conversion into contiguous Wb ----------
__global__ __launch_bounds__(256) void wconv_kernel(const float* __restrict__ q_w, const float* __restrict__ kv_w,
                                                    const float* __restrict__ op1_w, const float* __restrict__ op2_w,
                                                    const float* __restrict__ om1_w, const float* __restrict__ om2_w,
                                                    const float* __restrict__ fc1_w, const float* __restrict__ fc2_w,
                                                    unsigned short* __restrict__ Wb){
    size_t e = ((size_t)blockIdx.x * 256 + threadIdx.x) * 4;
    if (e >= 753664) return;
    const float* src; size_t off;
    if      (e <  65536){ src = q_w;   off = 0; }
    else if (e < 196608){ src = kv_w;  off = 65536; }
    else if (e < 262144){ src = op1_w; off = 196608; }
    else if (e < 327680){ src = op2_w; off = 262144; }
    else if (e < 344064){ src = om1_w; off = 327680; }
    else if (e < 360448){ src = om2_w; off = 344064; }
    else if (e < 557056){ src = fc1_w; off = 360448; }
    else                { src = fc2_w; off = 557056; }
    float4 v = *reinterpret_cast<const float4*>(src + (e - off));
    ushort4 o; o.x = f2bf(v.x); o.y = f2bf(v.y); o.z = f2bf(v.z); o.w = f2bf(v.w);
    *reinterpret_cast<ushort4*>(Wb + e) = o;
}

// ---------- std LayerNorm over 256 -> bf16 out; wave-per-token, 8 tokens/wave ----------
template<bool BF16IN>
__global__ __launch_bounds__(256) void stdln_kernel(const void* __restrict__ Xp,
                                                    const float* __restrict__ w,
                                                    const float* __restrict__ b,
                                                    unsigned short* __restrict__ out){
    int wv = threadIdx.x >> 6, lane = threadIdx.x & 63;
    int tok0 = (blockIdx.x * 4 + wv) * 8;
    int c0 = lane * 4;
    float4 w4 = *reinterpret_cast<const float4*>(w + c0);
    float4 b4 = *reinterpret_cast<const float4*>(b + c0);
    #pragma unroll 2
    for (int j = 0; j < 8; j++){
        size_t base = (size_t)(tok0 + j) * 256 + c0;
        float v[4];
        if constexpr (BF16IN){
            ushort4 u = *reinterpret_cast<const ushort4*>((const unsigned short*)Xp + base);
            v[0] = bf2f(u.x); v[1] = bf2f(u.y); v[2] = bf2f(u.z); v[3] = bf2f(u.w);
        } else {
            float4 f = *reinterpret_cast<const float4*>((const float*)Xp + base);
            v[0] = f.x; v[1] = f.y; v[2] = f.z; v[3] = f.w;
        }
        float s = v[0] + v[1] + v[2] + v[3];
        #pragma unroll
        for (int m = 1; m < 64; m <<= 1) s += __shfl_xor(s, m, 64);
        float mean = s * (1.0f / 256.0f);
        float ss = 0;
        #pragma unroll
        for (int k = 0; k < 4; k++){ v[k] -= mean; ss = fmaf(v[k], v[k], ss); }
        #pragma unroll
        for (int m = 1; m < 64; m <<= 1) ss += __shfl_xor(ss, m, 64);
        float inv = rsqrtf(ss * (1.0f / 256.0f) + 1e-5f);
        ushort4 o;
        o.x = f2bf(w4.x * v[0] * inv + b4.x);
        o.y = f2bf(w4.y * v[1] * inv + b4.y);
        o.z = f2bf(w4.z * v[2] * inv + b4.z);
        o.w = f2bf(w4.w * v[3] * inv + b4.w);
        *reinterpret_cast<ushort4*>(out + base) = o;
    }
}

// ---------- ce_flat = cor @ cor_w.T (K=2), token-blocked ----------
__global__ __launch_bounds__(256) void ce_kernel(const float* __restrict__ cor,
                                                 const float* __restrict__ cor_w,
                                                 unsigned short* __restrict__ CEF){
    int m = threadIdx.x & 127, half = threadIdx.x >> 7;
    float w0 = cor_w[m * 2 + 0], w1 = cor_w[m * 2 + 1];
    #pragma unroll 4
    for (int it = 0; it < 16; it++){
        int tok = blockIdx.x * 32 + it * 2 + half;
        float c0 = cor[(size_t)tok * 2 + 0];
        float c1 = cor[(size_t)tok * 2 + 1];
        CEF[(size_t)tok * 128 + m] = f2bf(c0 * w0 + c1 * w1);
    }
}

// ---------- fused: on-the-fly custom LN of K,V,CE + ktv & ktc reductions ----------
// 4 groups x 64 threads; per thread 4x4 ktv + 4x2 ktc register tile via float4/float2 LDS reads.
__global__ __launch_bounds__(256) void ktvc_kernel(const unsigned short* __restrict__ Kb,
                                                   const unsigned short* __restrict__ Vb,
                                                   const unsigned short* __restrict__ CEF,
                                                   const float* __restrict__ kw, const float* __restrict__ kbb,
                                                   const float* __restrict__ vw, const float* __restrict__ vbb,
                                                   const float* __restrict__ cw, const float* __restrict__ cbb,
                                                   float* __restrict__ KTV, float* __restrict__ KTC){
    int bh = blockIdx.x, b = bh >> 3, h = bh & 7;
    __shared__ float Ks[64][36];
    __shared__ float Vs[64][36];
    __shared__ float Cs[64][20];
    __shared__ float P[2][64][24];
    int t = threadIdx.x;
    int lr = t >> 2, lq = t & 3;          // staging: row, quad slot
    int g = t >> 6, tl = t & 63;          // compute: group, lane-in-group
    int d0 = (tl >> 3) * 4, e0 = (tl & 7) * 4, e0c = (tl & 7) * 2;
    float kwr[8], kbr[8], vwr[8], vbr[8], cwr[4], cbr[4];
    #pragma unroll
    for (int j = 0; j < 8; j++){
        kwr[j] = kw[h * 32 + lq * 8 + j]; kbr[j] = kbb[h * 32 + lq * 8 + j];
        vwr[j] = vw[h * 32 + lq * 8 + j]; vbr[j] = vbb[h * 32 + lq * 8 + j];
    }
    #pragma unroll
    for (int j = 0; j < 4; j++){
        cwr[j] = cw[h * 16 + lq * 4 + j]; cbr[j] = cbb[h * 16 + lq * 4 + j];
    }
    float akv[4][4] = {};
    float akc[4][2] = {};
    size_t base = ((size_t)b << 14) + (size_t)blockIdx.y * 512;
    for (int n0 = 0; n0 < 512; n0 += 64){
        size_t rowi = base + n0 + lr;
        const ushort4* kp = reinterpret_cast<const ushort4*>(Kb + rowi * 256 + h * 32 + lq * 8);
        ushort4 ka = kp[0], kc = kp[1];
        const ushort4* vp = reinterpret_cast<const ushort4*>(Vb + rowi * 256 + h * 32 + lq * 8);
        ushort4 va = vp[0], vc = vp[1];
        ushort4 ca = *reinterpret_cast<const ushort4*>(CEF + rowi * 128 + h * 16 + lq * 4);
        float kvv[8] = { bf2f(ka.x), bf2f(ka.y), bf2f(ka.z), bf2f(ka.w),
                         bf2f(kc.x), bf2f(kc.y), bf2f(kc.z), bf2f(kc.w) };
        float vvv[8] = { bf2f(va.x), bf2f(va.y), bf2f(va.z), bf2f(va.w),
                         bf2f(vc.x), bf2f(vc.y), bf2f(vc.z), bf2f(vc.w) };
        float cvv[4] = { bf2f(ca.x), bf2f(ca.y), bf2f(ca.z), bf2f(ca.w) };
        // --- LN K (32 ch over quad) ---
        float s = 0;
        #pragma unroll
        for (int j = 0; j < 8; j++) s += kvv[j];
        s += __shfl_xor(s, 1, 64); s += __shfl_xor(s, 2, 64);
        float mean = s * (1.0f / 32.0f);
        float ss = 0;
        #pragma unroll
        for (int j = 0; j < 8; j++){ kvv[j] -= mean; ss = fmaf(kvv[j], kvv[j], ss); }
        ss += __shfl_xor(ss, 1, 64); ss += __shfl_xor(ss, 2, 64);
        float inv = 1.0f / (sqrtf(ss * (1.0f / 31.0f)) + 1e-5f);
        #pragma unroll
        for (int j = 0; j < 8; j++) kvv[j] = fmaf(kwr[j] * kvv[j], inv, kbr[j]);
        // --- LN V ---
        s = 0;
        #pragma unroll
        for (int j = 0; j < 8; j++) s += vvv[j];
        s += __shfl_xor(s, 1, 64); s += __shfl_xor(s, 2, 64);
        mean = s * (1.0f / 32.0f);
        ss = 0;
        #pragma unroll
        for (int j = 0; j < 8; j++){ vvv[j] -= mean; ss = fmaf(vvv[j], vvv[j], ss); }
        ss += __shfl_xor(ss, 1, 64); ss += __shfl_xor(ss, 2, 64);
        inv = 1.0f / (sqrtf(ss * (1.0f / 31.0f)) + 1e-5f);
        #pragma unroll
        for (int j = 0; j < 8; j++) vvv[j] = fmaf(vwr[j] * vvv[j], inv, vbr[j]);
        // --- LN CE (16 ch over quad) ---
        s = 0;
        #pragma unroll
        for (int j = 0; j < 4; j++) s += cvv[j];
        s += __shfl_xor(s, 1, 64); s += __shfl_xor(s, 2, 64);
        mean = s * (1.0f / 16.0f);
        ss = 0;
        #pragma unroll
        for (int j = 0; j < 4; j++){ cvv[j] -= mean; ss = fmaf(cvv[j], cvv[j], ss); }
        ss += __shfl_xor(ss, 1, 64); ss += __shfl_xor(ss, 2, 64);
        inv = 1.0f / (sqrtf(ss * (1.0f / 15.0f)) + 1e-5f);
        #pragma unroll
        for (int j = 0; j < 4; j++) cvv[j] = fmaf(cwr[j] * cvv[j], inv, cbr[j]);
        __syncthreads();
        #pragma unroll
        for (int j = 0; j < 8; j++){ Ks[lr][lq * 8 + j] = kvv[j]; Vs[lr][lq * 8 + j] = vvv[j]; }
        #pragma unroll
        for (int j = 0; j < 4; j++) Cs[lr][lq * 4 + j] = cvv[j];
        __syncthreads();
        // each group handles 16 contiguous rows of the 64-row tile
        #pragma unroll 4
        for (int i = 0; i < 16; i++){
            int n = g * 16 + i;
            float4 k4 = *reinterpret_cast<const float4*>(&Ks[n][d0]);
            float4 v4 = *reinterpret_cast<const float4*>(&Vs[n][e0]);
            float2 c2 = *reinterpret_cast<const float2*>(&Cs[n][e0c]);
            float kk[4] = { k4.x, k4.y, k4.z, k4.w };
            float vv[4] = { v4.x, v4.y, v4.z, v4.w };
            #pragma unroll
            for (int a = 0; a < 4; a++){
                akv[a][0] = fmaf(kk[a], vv[0], akv[a][0]);
                akv[a][1] = fmaf(kk[a], vv[1], akv[a][1]);
                akv[a][2] = fmaf(kk[a], vv[2], akv[a][2]);
                akv[a][3] = fmaf(kk[a], vv[3], akv[a][3]);
                akc[a][0] = fmaf(kk[a], c2.x, akc[a][0]);
                akc[a][1] = fmaf(kk[a], c2.y, akc[a][1]);
            }
        }
    }
    // cross-group reduce: groups 2,3 -> P, groups 0,1 add; group 1 -> P[0], group 0 adds.
    __syncthreads();
    if (g >= 2){
        float* p = &P[g - 2][tl][0];
        #pragma unroll
        for (int a = 0; a < 4; a++){
            #pragma unroll
            for (int e = 0; e < 4; e++) p[a * 4 + e] = akv[a][e];
            p[16 + a * 2 + 0] = akc[a][0];
            p[16 + a * 2 + 1] = akc[a][1];
        }
    }
    __syncthreads();
    if (g < 2){
        const float* p = &P[g][tl][0];
        #pragma unroll
        for (int a = 0; a < 4; a++){
            #pragma unroll
            for (int e = 0; e < 4; e++) akv[a][e] += p[a * 4 + e];
            akc[a][0] += p[16 + a * 2 + 0];
            akc[a][1] += p[16 + a * 2 + 1];
        }
    }
    __syncthreads();
    if (g == 1){
        float* p = &P[0][tl][0];
        #pragma unroll
        for (int a = 0; a < 4; a++){
            #pragma unroll
            for (int e = 0; e < 4; e++) p[a * 4 + e] = akv[a][e];
            p[16 + a * 2 + 0] = akc[a][0];
            p[16 + a * 2 + 1] = akc[a][1];
        }
    }
    __syncthreads();
    if (g == 0){
        const float* p = &P[0][tl][0];
        const float sc = 1.0f / 16384.0f;
        float* o = KTV + (size_t)bh * 1024;
        float* o2 = KTC + (size_t)bh * 512;
        #pragma unroll
        for (int a = 0; a < 4; a++){
            #pragma unroll
            for (int e = 0; e < 4; e++)
                atomicAdd(&o[(d0 + a) * 32 + e0 + e], (akv[a][e] + p[a * 4 + e]) * sc);
            atomicAdd(&o2[(d0 + a) * 16 + e0c + 0], (akc[a][0] + p[16 + a * 2 + 0]) * sc);
            atomicAdd(&o2[(d0 + a) * 16 + e0c + 1], (akc[a][1] + p[16 + a * 2 + 1]) * sc);
        }
    }
}

// ---------- combined attention weights: WTC[b][c][i], c<256: q_w^T·ktv ; c>=256: q_w^T·ktc ----------
__global__ __launch_bounds__(256) void wcomb_kernel(const float* __restrict__ q_w,
                                                    const float* __restrict__ KTV,
                                                    const float* __restrict__ KTC,
                                                    unsigned short* __restrict__ WTC){
    int c = blockIdx.x;
    int b = blockIdx.y;
    int i = threadIdx.x;
    __shared__ float coef[32];
    int h = (c < 256) ? (c >> 5) : ((c - 256) >> 4);
    if (i < 32){
        if (c < 256) coef[i] = KTV[(size_t)((b * 8 + h) << 10) + i * 32 + (c & 31)];
        else         coef[i] = KTC[(size_t)((b * 8 + h) << 9)  + i * 16 + ((c - 256) & 15)];
    }
    __syncthreads();
    float acc = 0;
    #pragma unroll
    for (int d = 0; d < 32; d++) acc = fmaf(q_w[(size_t)(h * 32 + d) * 256 + i], coef[d], acc);
    WTC[((size_t)b * 384 + c) * 256 + i] = f2bf(acc);
}

// ---------- depthwise 3x3 conv (SAME) + bias + gelu, y-banded (4 rows/block) ----------
__global__ __launch_bounds__(192) void dwconv_kernel(const unsigned short* __restrict__ H1,
                                                     const float* __restrict__ dww,
                                                     const float* __restrict__ dwb,
                                                     unsigned short* __restrict__ H2){
    int blk = blockIdx.x;
    int xq = blk & 3;
    int yb = (blk >> 2) & 31;
    int bb = blk >> 7;
    int y0 = yb * 4, x0 = xq * 32;
    int ch = threadIdx.x * 4;
    float w[9][4];
    #pragma unroll
    for (int k = 0; k < 9; k++)
        #pragma unroll
        for (int j = 0; j < 4; j++) w[k][j] = dww[(ch + j) * 9 + k];
    float bias[4] = { dwb[ch], dwb[ch+1], dwb[ch+2], dwb[ch+3] };
    size_t rb[6]; bool rv[6];
    #pragma unroll
    for (int r = 0; r < 6; r++){
        int yr = y0 - 1 + r;
        rv[r] = ((unsigned)yr <= 127u);
        int yc = yr < 0 ? 0 : (yr > 127 ? 127 : yr);
        rb[r] = ((size_t)((bb << 14) + (yc << 7))) * 768 + ch;
    }
    size_t ob[4];
    #pragma unroll
    for (int j = 0; j < 4; j++) ob[j] = ((size_t)((bb << 14) + ((y0 + j) << 7))) * 768 + ch;

    ushort4 cA[6], cB[6], cC[6], cD[6];
    const ushort4 Z = {0, 0, 0, 0};
    #define LOADR(DST, XX) do {                                               \
        int _x = (XX);                                                        \
        bool xv = ((unsigned)_x <= 127u);                                     \
        _Pragma("unroll")                                                     \
        for (int r = 0; r < 6; r++)                                           \
            DST[r] = (xv && rv[r]) ? *reinterpret_cast<const ushort4*>(H1 + rb[r] + (size_t)_x * 768) : Z; \
    } while (0)

    #define EMITB(SA, SB, SC, XX) do {                                        \
        _Pragma("unroll")                                                     \
        for (int j = 0; j < 4; j++){                                          \
            float acc[4];                                                     \
            _Pragma("unroll")                                                 \
            for (int q = 0; q < 4; q++) acc[q] = bias[q];                     \
            _Pragma("unroll")                                                 \
            for (int rr2 = 0; rr2 < 3; rr2++){                                \
                int ri = j + rr2;                                             \
                float a0=bf2f(SA[ri].x),a1=bf2f(SA[ri].y),a2=bf2f(SA[ri].z),a3=bf2f(SA[ri].w); \
                float b0=bf2f(SB[ri].x),b1=bf2f(SB[ri].y),b2=bf2f(SB[ri].z),b3=bf2f(SB[ri].w); \
                float c0=bf2f(SC[ri].x),c1=bf2f(SC[ri].y),c2=bf2f(SC[ri].z),c3=bf2f(SC[ri].w); \
                acc[0]=fmaf(a0,w[rr2*3+0][0],acc[0]); acc[0]=fmaf(b0,w[rr2*3+1][0],acc[0]); acc[0]=fmaf(c0,w[rr2*3+2][0],acc[0]); \
                acc[1]=fmaf(a1,w[rr2*3+0][1],acc[1]); acc[1]=fmaf(b1,w[rr2*3+1][1],acc[1]); acc[1]=fmaf(c1,w[rr2*3+2][1],acc[1]); \
                acc[2]=fmaf(a2,w[rr2*3+0][2],acc[2]); acc[2]=fmaf(b2,w[rr2*3+1][2],acc[2]); acc[2]=fmaf(c2,w[rr2*3+2][2],acc[2]); \
                acc[3]=fmaf(a3,w[rr2*3+0][3],acc[3]); acc[3]=fmaf(b3,w[rr2*3+1][3],acc[3]); acc[3]=fmaf(c3,w[rr2*3+2][3],acc[3]); \
            }                                                                 \
            ushort4 o;                                                        \
            o.x = f2bf(gelu_f(acc[0])); o.y = f2bf(gelu_f(acc[1]));           \
            o.z = f2bf(gelu_f(acc[2])); o.w = f2bf(gelu_f(acc[3]));           \
            *reinterpret_cast<ushort4*>(H2 + ob[j] + (size_t)(XX) * 768) = o; \
        }                                                                     \
    } while (0)

    LOADR(cD, x0 - 1);
    LOADR(cA, x0);
    LOADR(cB, x0 + 1);
    LOADR(cC, x0 + 2);
    #pragma unroll 1
    for (int g = 0; g < 8; g++){
        int x = x0 + g * 4;
        EMITB(cD, cA, cB, x);     LOADR(cD, x + 3);
        EMITB(cA, cB, cC, x + 1); LOADR(cA, x + 4);
        EMITB(cB, cC, cD, x + 2); LOADR(cB, x + 5);
        EMITB(cC, cD, cA, x + 3); LOADR(cC, x + 6);
    }
    #undef LOADR
    #undef EMITB
}

// ---------- bf16 MFMA GEMM, wide-N blocks (A staged once per block), double-buffered LDS ----------
#define M_KV        1
#define M_BIAS_GELU 2
#define M_BIAS_ADD2 3
#define M_BIAS      4
#define M_BIAS_BF16 5
#define M_BIAS_ADDX 6
#define M_ATTN      7

template<int MODE, bool SWAP, int K, int O, int WN>
__global__ __launch_bounds__(128 * WN) void mgemm(const unsigned short* __restrict__ A,
                                                  const unsigned short* __restrict__ Wp,
                                                  const float* __restrict__ bias,
                                                  const void* __restrict__ add,
                                                  void* __restrict__ out0,
                                                  void* __restrict__ out1){
    constexpr int WAVES = 2 * WN;
    constexpr int BN = 64 * WN;
    constexpr int CH = 8 + 4 * WN;
    constexpr int NT = K / 32;
    __shared__ __align__(16) unsigned short As[2][128 * 32];
    __shared__ __align__(16) unsigned short Bs[2][BN * 32];
    const int t = threadIdx.x;
    const int lane = t & 63, wid = t >> 6;
    const int wm = wid & 1, wn = wid >> 1;
    const int row0 = blockIdx.x * 128;
    const int colB = blockIdx.y * BN;
    const unsigned short* W = Wp;
    if constexpr (MODE == M_ATTN) W += (size_t)(row0 >> 14) * (384 * 256);
    f32x4 acc[4][4];
    #pragma unroll
    for (int i = 0; i < 4; i++)
        #pragma unroll
        for (int j = 0; j < 4; j++){ f32x4 z = {0.f, 0.f, 0.f, 0.f}; acc[i][j] = z; }

    const int lr = lane >> 2;
    const int ls = lane & 3;
    const int kq = lane >> 4;
    const int rr = lane & 15;

    auto STAGE = [&](int buf, int kb){
        #pragma unroll
        for (int c = wid; c < CH; c += WAVES){
            int r16 = (c < 8) ? c : (c - 8);
            int row = r16 * 16 + lr;
            int ko = ls ^ ((row >> 1) & 3);
            if (c < 8){
                int ga = row0 + row;
                if (SWAP) ga ^= 32768;
                __builtin_amdgcn_global_load_lds(
                    (const __attribute__((address_space(1))) unsigned int*)(A + (size_t)ga * K + kb + ko * 8),
                    (__attribute__((address_space(3))) unsigned int*)(As[buf] + r16 * 512),
                    16, 0, 0);
            } else {
                int gc = colB + row;
                __builtin_amdgcn_global_load_lds(
                    (const __attribute__((address_space(1))) unsigned int*)(W + (size_t)gc * K + kb + ko * 8),
                    (__attribute__((address_space(3))) unsigned int*)(Bs[buf] + r16 * 512),
                    16, 0, 0);
            }
        }
    };

    STAGE(0, 0);
    asm volatile("s_waitcnt vmcnt(0)" ::: "memory");
    __builtin_amdgcn_s_barrier();
    #pragma unroll 1
    for (int tt = 0; tt < NT; tt++){
        int cur = tt & 1;
        if (tt + 1 < NT) STAGE(cur ^ 1, (tt + 1) * 32);
        bf16x8 af[4], bfr[4];
        #pragma unroll
        for (int m = 0; m < 4; m++){
            int row = wm * 64 + m * 16 + rr;
            int s = kq ^ ((row >> 1) & 3);
            af[m] = *reinterpret_cast<const bf16x8*>(As[cur] + row * 32 + s * 8);
        }
        #pragma unroll
        for (int n = 0; n < 4; n++){
            int row = wn * 64 + n * 16 + rr;
            int s = kq ^ ((row >> 1) & 3);
            bfr[n] = *reinterpret_cast<const bf16x8*>(Bs[cur] + row * 32 + s * 8);
        }
        #pragma unroll
        for (int m = 0; m < 4; m++)
            #pragma unroll
            for (int n = 0; n < 4; n++)
                acc[m][n] = __builtin_amdgcn_mfma_f32_16x16x32_bf16(af[m], bfr[n], acc[m][n], 0, 0, 0);
        if (tt + 1 < NT){
            asm volatile("s_waitcnt vmcnt(0)" ::: "memory");
            __builtin_amdgcn_s_barrier();
        }
    }

    #pragma unroll
    for (int m = 0; m < 4; m++){
        #pragma unroll
        for (int n = 0; n < 4; n++){
            int col = colB + wn * 64 + n * 16 + rr;
            int rbase = row0 + wm * 64 + m * 16 + kq * 4;
            #pragma unroll
            for (int j = 0; j < 4; j++){
                int r = rbase + j;
                float v = acc[m][n][j];
                size_t o = (size_t)r * O + col;
                if constexpr (MODE == M_KV){
                    if (col < 256) ((unsigned short*)out0)[(size_t)r * 256 + col] = f2bf(v);
                    else           ((unsigned short*)out1)[(size_t)r * 256 + col - 256] = f2bf(v);
                } else if constexpr (MODE == M_BIAS_GELU){
                    ((unsigned short*)out0)[o] = f2bf(gelu_f(v + bias[col]));
                } else if constexpr (MODE == M_BIAS_ADD2){
                    ((unsigned short*)out0)[o] = f2bf(v + bias[col] + 2.0f * bf2f(((const unsigned short*)add)[o]));
                } else if constexpr (MODE == M_BIAS){
                    ((float*)out0)[o] = v + bias[col];
                } else if constexpr (MODE == M_BIAS_BF16){
                    ((unsigned short*)out0)[o] = f2bf(v + bias[col]);
                } else if constexpr (MODE == M_BIAS_ADDX){
                    ((float*)out0)[o] = v + bias[col] + ((const float*)add)[o];
                } else if constexpr (MODE == M_ATTN){
                    if (col < 256){
                        size_t o1 = (size_t)r * 256 + col;
                        ((unsigned short*)out0)[o1] = f2bf(v + bf2f(((const unsigned short*)add)[o1]));
                    } else {
                        size_t o2 = (size_t)r * 128 + (col - 256);
                        ((unsigned short*)out1)[o2] = f2bf(v - bf2f(((const unsigned short*)bias)[o2]));
                    }
                }
            }
        }
    }
}

extern "C" void kernel_launch(void* const* d_in, const int* in_sizes, int n_in,
                              void* d_out, int out_size, void* d_ws, size_t ws_size,
                              hipStream_t stream){
    const float* x     = (const float*)d_in[0];
    const float* cor   = (const float*)d_in[1];
    const float* q_w   = (const float*)d_in[2];
    const float* kv_w  = (const float*)d_in[3];
    const float* cor_w = (const float*)d_in[4];
    const float* kln_w = (const float*)d_in[5];
    const float* kln_b = (const float*)d_in[6];
    const float* vln_w = (const float*)d_in[7];
    const float* vln_b = (const float*)d_in[8];
    const float* corln_w = (const float*)d_in[9];
    const float* corln_b = (const float*)d_in[10];
    const float* op1_w = (const float*)d_in[11];
    const float* op1_b = (const float*)d_in[12];
    const float* op2_w = (const float*)d_in[13];
    const float* op2_b = (const float*)d_in[14];
    const float* om1_w = (const float*)d_in[15];
    const float* om1_b = (const float*)d_in[16];
    const float* om2_w = (const float*)d_in[17];
    const float* om2_b = (const float*)d_in[18];
    const float* n1_w  = (const float*)d_in[19];
    const float* n1_b  = (const float*)d_in[20];
    const float* n2_w  = (const float*)d_in[21];
    const float* n2_b  = (const float*)d_in[22];
    const float* fc1_w = (const float*)d_in[23];
    const float* fc1_b = (const float*)d_in[24];
    const float* dw_w  = (const float*)d_in[25];
    const float* dw_b  = (const float*)d_in[26];
    const float* fc2_w = (const float*)d_in[27];
    const float* fc2_b = (const float*)d_in[28];

    // ---- workspace layout (bf16 elements unless noted) ----
    unsigned short* XN  = (unsigned short*)d_ws;           // NTOK*256
    unsigned short* Qb  = XN  + (size_t)NTOK * 256;
    unsigned short* Kb  = Qb  + (size_t)NTOK * 256;
    unsigned short* Vb  = Kb  + (size_t)NTOK * 256;
    unsigned short* CEF = Vb  + (size_t)NTOK * 256;        // NTOK*128
    unsigned short* CE  = CEF + (size_t)NTOK * 128;
    float* KTV = (float*)(CE + (size_t)NTOK * 128);        // 32768 f32
    float* KTC = KTV + 32768;                              // 16384 f32
    unsigned short* WTC = (unsigned short*)(KTC + 16384);  // 4*384*256 bf16
    unsigned short* Wb  = WTC + 4 * 384 * 256;             // 753664 bf16 weights
    unsigned short* H2  = Wb + 753664;                     // NTOK*768
    // overlays (disjoint live ranges):
    unsigned short* T1 = Vb;
    unsigned short* T2 = Kb;
    unsigned short* XB = Qb;
    unsigned short* Y  = Vb;
    unsigned short* TM = CE;
    unsigned short* MH = CEF;
    unsigned short* H1 = XN;      // spans XN+Qb+Kb = NTOK*768
    float* xout = (float*)d_out;
    float* mout = xout + (size_t)NTOK * 256;

    unsigned short* w_kv  = Wb + 65536;
    unsigned short* w_op1 = Wb + 196608;
    unsigned short* w_op2 = Wb + 262144;
    unsigned short* w_om1 = Wb + 327680;
    unsigned short* w_om2 = Wb + 344064;
    unsigned short* w_fc1 = Wb + 360448;
    unsigned short* w_fc2 = Wb + 557056;

    // 0. weights -> bf16
    wconv_kernel<<<736, 256, 0, stream>>>(q_w, kv_w, op1_w, op2_w, om1_w, om2_w, fc1_w, fc2_w, Wb);
    // 1. xn = std_ln(x, norm1)
    stdln_kernel<false><<<2048, 256, 0, stream>>>(x, n1_w, n1_b, XN);
    // 2. kv = xr @ kv_w.T (swapped rows), split K,V (un-normalized)
    mgemm<M_KV, true, 256, 512, 4><<<dim3(512, 2), 512, 0, stream>>>(XN, w_kv, nullptr, nullptr, Kb, Vb);
    // 3. ce_flat
    ce_kernel<<<2048, 256, 0, stream>>>(cor, cor_w, CEF);
    // 4. zero accumulators
    hipMemsetAsync(KTV, 0, (32768 + 16384) * sizeof(float), stream);
    // 5. fused LN + ktv + ktc (register-tiled)
    ktvc_kernel<<<dim3(32, 32), 256, 0, stream>>>(Kb, Vb, CEF, kln_w, kln_b, vln_w, vln_b,
                                                  corln_w, corln_b, KTV, KTC);
    // 6. combined attention weights WTC[b] = q_w^T · blockdiag(ktv|ktc)
    wcomb_kernel<<<dim3(384, 4), 256, 0, stream>>>(q_w, KTV, KTC, WTC);
    // 7. [t | dm] = xn @ WTC[b] (+xn | -ce_flat)
    mgemm<M_ATTN, false, 256, 384, 6><<<dim3(512, 1), 768, 0, stream>>>(XN, WTC, (const float*)CEF, XN, T1, TM);
    // 8. hidden = gelu(t @ op1.T + b)
    mgemm<M_BIAS_GELU, false, 256, 256, 4><<<dim3(512, 1), 512, 0, stream>>>(T1, w_op1, op1_b, nullptr, T2, nullptr);
    // 9. x_back = (hidden @ op2.T + b) + 2*xn
    mgemm<M_BIAS_ADD2, false, 256, 256, 4><<<dim3(512, 1), 512, 0, stream>>>(T2, w_op2, op2_b, XN, XB, nullptr);
    // 10. mh = gelu(dm @ om1.T + b)
    mgemm<M_BIAS_GELU, false, 128, 128, 2><<<dim3(512, 1), 256, 0, stream>>>(TM, w_om1, om1_b, nullptr, MH, nullptr);
    // 11. motion = mh @ om2.T + b -> output 1 (fp32)
    mgemm<M_BIAS, false, 128, 128, 2><<<dim3(512, 1), 256, 0, stream>>>(MH, w_om2, om2_b, nullptr, mout, nullptr);
    // 12. y = std_ln(x_back, norm2)
    stdln_kernel<true><<<2048, 256, 0, stream>>>(XB, n2_w, n2_b, Y);
    // 13. h1 = y @ fc1.T + b (bf16)
    mgemm<M_BIAS_BF16, false, 256, 768, 6><<<dim3(512, 2), 768, 0, stream>>>(Y, w_fc1, fc1_b, nullptr, H1, nullptr);
    // 14. depthwise conv + bias + gelu (y-banded)
    dwconv_kernel<<<512, 192, 0, stream>>>(H1, dw_w, dw_b, H2);
    // 15. x_out = h2 @ fc2.T + b + x -> output 0 (fp32)
    mgemm<M_BIAS_ADDX, false, 768, 256, 4><<<dim3(512, 1), 512, 0, stream>>>(H2, w_fc2, fc2_b, x, xout, nullptr);
}

// Round 9
// 413.429 us; speedup vs baseline: 6.8197x; 1.0259x over previous
//
#include <hip/hip_runtime.h>
#include <hip/hip_bf16.h>

#define NTOK 65536      // 4 * 16384 tokens

typedef __attribute__((ext_vector_type(4))) float f32x4;
typedef __attribute__((ext_vector_type(8))) short bf16x8;

__device__ __forceinline__ float gelu_f(float x){
    float z = -2.30234438f * fmaf(0.044715f * x * x, x, x);
    float e = exp2f(z);
    return x * __builtin_amdgcn_rcpf(1.0f + e);
}
__device__ __forceinline__ float bf2f(unsigned short u){
    union { unsigned int i; float f; } w; w.i = ((unsigned int)u) << 16; return w.f;
}
__device__ __forceinline__ unsigned short f2bf(float f){
    __hip_bfloat16 h = __float2bfloat16(f);
    return *reinterpret_cast<unsigned short*>(&h);
}
__device__ __forceinline__ bf16x8 add_bf8(bf16x8 s, bf16x8 o, float k){
    bf16x8 r;
    #pragma unroll
    for (int i = 0; i < 8; i++)
        r[i] = (short)f2bf(fmaf(k, bf2f((unsigned short)o[i]), bf2f((unsigned short)s[i])));
    return r;
}

// ---------- weight fp32 -> bf16 conversion into contiguous Wb ----------
__global__ __launch_bounds__(256) void wconv_kernel(const float* __restrict__ q_w, const float* __restrict__ kv_w,
                                                    const float* __restrict__ op1_w, const float* __restrict__ op2_w,
                                                    const float* __restrict__ om1_w, const float* __restrict__ om2_w,
                                                    const float* __restrict__ fc1_w, const float* __restrict__ fc2_w,
                                                    unsigned short* __restrict__ Wb){
    size_t e = ((size_t)blockIdx.x * 256 + threadIdx.x) * 4;
    if (e >= 753664) return;
    const float* src; size_t off;
    if      (e <  65536){ src = q_w;   off = 0; }
    else if (e < 196608){ src = kv_w;  off = 65536; }
    else if (e < 262144){ src = op1_w; off = 196608; }
    else if (e < 327680){ src = op2_w; off = 262144; }
    else if (e < 344064){ src = om1_w; off = 327680; }
    else if (e < 360448){ src = om2_w; off = 344064; }
    else if (e < 557056){ src = fc1_w; off = 360448; }
    else                { src = fc2_w; off = 557056; }
    float4 v = *reinterpret_cast<const float4*>(src + (e - off));
    ushort4 o; o.x = f2bf(v.x); o.y = f2bf(v.y); o.z = f2bf(v.z); o.w = f2bf(v.w);
    *reinterpret_cast<ushort4*>(Wb + e) = o;
}

// ---------- std LayerNorm over 256 -> bf16 out; wave-per-token, 8 tokens/wave ----------
template<bool BF16IN>
__global__ __launch_bounds__(256) void stdln_kernel(const void* __restrict__ Xp,
                                                    const float* __restrict__ w,
                                                    const float* __restrict__ b,
                                                    unsigned short* __restrict__ out){
    int wv = threadIdx.x >> 6, lane = threadIdx.x & 63;
    int tok0 = (blockIdx.x * 4 + wv) * 8;
    int c0 = lane * 4;
    float4 w4 = *reinterpret_cast<const float4*>(w + c0);
    float4 b4 = *reinterpret_cast<const float4*>(b + c0);
    #pragma unroll 2
    for (int j = 0; j < 8; j++){
        size_t base = (size_t)(tok0 + j) * 256 + c0;
        float v[4];
        if constexpr (BF16IN){
            ushort4 u = *reinterpret_cast<const ushort4*>((const unsigned short*)Xp + base);
            v[0] = bf2f(u.x); v[1] = bf2f(u.y); v[2] = bf2f(u.z); v[3] = bf2f(u.w);
        } else {
            float4 f = *reinterpret_cast<const float4*>((const float*)Xp + base);
            v[0] = f.x; v[1] = f.y; v[2] = f.z; v[3] = f.w;
        }
        float s = v[0] + v[1] + v[2] + v[3];
        #pragma unroll
        for (int m = 1; m < 64; m <<= 1) s += __shfl_xor(s, m, 64);
        float mean = s * (1.0f / 256.0f);
        float ss = 0;
        #pragma unroll
        for (int k = 0; k < 4; k++){ v[k] -= mean; ss = fmaf(v[k], v[k], ss); }
        #pragma unroll
        for (int m = 1; m < 64; m <<= 1) ss += __shfl_xor(ss, m, 64);
        float inv = rsqrtf(ss * (1.0f / 256.0f) + 1e-5f);
        ushort4 o;
        o.x = f2bf(w4.x * v[0] * inv + b4.x);
        o.y = f2bf(w4.y * v[1] * inv + b4.y);
        o.z = f2bf(w4.z * v[2] * inv + b4.z);
        o.w = f2bf(w4.w * v[3] * inv + b4.w);
        *reinterpret_cast<ushort4*>(out + base) = o;
    }
}

// ---------- ce_flat = cor @ cor_w.T (K=2), token-blocked ----------
__global__ __launch_bounds__(256) void ce_kernel(const float* __restrict__ cor,
                                                 const float* __restrict__ cor_w,
                                                 unsigned short* __restrict__ CEF){
    int m = threadIdx.x & 127, half = threadIdx.x >> 7;
    float w0 = cor_w[m * 2 + 0], w1 = cor_w[m * 2 + 1];
    #pragma unroll 4
    for (int it = 0; it < 16; it++){
        int tok = blockIdx.x * 32 + it * 2 + half;
        float c0 = cor[(size_t)tok * 2 + 0];
        float c1 = cor[(size_t)tok * 2 + 1];
        CEF[(size_t)tok * 128 + m] = f2bf(c0 * w0 + c1 * w1);
    }
}

// ---------- fused: on-the-fly custom LN of K,V,CE + ktv & ktc reductions ----------
__global__ __launch_bounds__(256) void ktvc_kernel(const unsigned short* __restrict__ Kb,
                                                   const unsigned short* __restrict__ Vb,
                                                   const unsigned short* __restrict__ CEF,
                                                   const float* __restrict__ kw, const float* __restrict__ kbb,
                                                   const float* __restrict__ vw, const float* __restrict__ vbb,
                                                   const float* __restrict__ cw, const float* __restrict__ cbb,
                                                   float* __restrict__ KTV, float* __restrict__ KTC){
    int bh = blockIdx.x, b = bh >> 3, h = bh & 7;
    __shared__ float Ks[64][36];
    __shared__ float Vs[64][36];
    __shared__ float Cs[64][20];
    __shared__ float P[2][64][24];
    int t = threadIdx.x;
    int lr = t >> 2, lq = t & 3;
    int g = t >> 6, tl = t & 63;
    int d0 = (tl >> 3) * 4, e0 = (tl & 7) * 4, e0c = (tl & 7) * 2;
    float kwr[8], kbr[8], vwr[8], vbr[8], cwr[4], cbr[4];
    #pragma unroll
    for (int j = 0; j < 8; j++){
        kwr[j] = kw[h * 32 + lq * 8 + j]; kbr[j] = kbb[h * 32 + lq * 8 + j];
        vwr[j] = vw[h * 32 + lq * 8 + j]; vbr[j] = vbb[h * 32 + lq * 8 + j];
    }
    #pragma unroll
    for (int j = 0; j < 4; j++){
        cwr[j] = cw[h * 16 + lq * 4 + j]; cbr[j] = cbb[h * 16 + lq * 4 + j];
    }
    float akv[4][4] = {};
    float akc[4][2] = {};
    size_t base = ((size_t)b << 14) + (size_t)blockIdx.y * 512;
    for (int n0 = 0; n0 < 512; n0 += 64){
        size_t rowi = base + n0 + lr;
        const ushort4* kp = reinterpret_cast<const ushort4*>(Kb + rowi * 256 + h * 32 + lq * 8);
        ushort4 ka = kp[0], kc = kp[1];
        const ushort4* vp = reinterpret_cast<const ushort4*>(Vb + rowi * 256 + h * 32 + lq * 8);
        ushort4 va = vp[0], vc = vp[1];
        ushort4 ca = *reinterpret_cast<const ushort4*>(CEF + rowi * 128 + h * 16 + lq * 4);
        float kvv[8] = { bf2f(ka.x), bf2f(ka.y), bf2f(ka.z), bf2f(ka.w),
                         bf2f(kc.x), bf2f(kc.y), bf2f(kc.z), bf2f(kc.w) };
        float vvv[8] = { bf2f(va.x), bf2f(va.y), bf2f(va.z), bf2f(va.w),
                         bf2f(vc.x), bf2f(vc.y), bf2f(vc.z), bf2f(vc.w) };
        float cvv[4] = { bf2f(ca.x), bf2f(ca.y), bf2f(ca.z), bf2f(ca.w) };
        float s = 0;
        #pragma unroll
        for (int j = 0; j < 8; j++) s += kvv[j];
        s += __shfl_xor(s, 1, 64); s += __shfl_xor(s, 2, 64);
        float mean = s * (1.0f / 32.0f);
        float ss = 0;
        #pragma unroll
        for (int j = 0; j < 8; j++){ kvv[j] -= mean; ss = fmaf(kvv[j], kvv[j], ss); }
        ss += __shfl_xor(ss, 1, 64); ss += __shfl_xor(ss, 2, 64);
        float inv = 1.0f / (sqrtf(ss * (1.0f / 31.0f)) + 1e-5f);
        #pragma unroll
        for (int j = 0; j < 8; j++) kvv[j] = fmaf(kwr[j] * kvv[j], inv, kbr[j]);
        s = 0;
        #pragma unroll
        for (int j = 0; j < 8; j++) s += vvv[j];
        s += __shfl_xor(s, 1, 64); s += __shfl_xor(s, 2, 64);
        mean = s * (1.0f / 32.0f);
        ss = 0;
        #pragma unroll
        for (int j = 0; j < 8; j++){ vvv[j] -= mean; ss = fmaf(vvv[j], vvv[j], ss); }
        ss += __shfl_xor(ss, 1, 64); ss += __shfl_xor(ss, 2, 64);
        inv = 1.0f / (sqrtf(ss * (1.0f / 31.0f)) + 1e-5f);
        #pragma unroll
        for (int j = 0; j < 8; j++) vvv[j] = fmaf(vwr[j] * vvv[j], inv, vbr[j]);
        s = 0;
        #pragma unroll
        for (int j = 0; j < 4; j++) s += cvv[j];
        s += __shfl_xor(s, 1, 64); s += __shfl_xor(s, 2, 64);
        mean = s * (1.0f / 16.0f);
        ss = 0;
        #pragma unroll
        for (int j = 0; j < 4; j++){ cvv[j] -= mean; ss = fmaf(cvv[j], cvv[j], ss); }
        ss += __shfl_xor(ss, 1, 64); ss += __shfl_xor(ss, 2, 64);
        inv = 1.0f / (sqrtf(ss * (1.0f / 15.0f)) + 1e-5f);
        #pragma unroll
        for (int j = 0; j < 4; j++) cvv[j] = fmaf(cwr[j] * cvv[j], inv, cbr[j]);
        __syncthreads();
        #pragma unroll
        for (int j = 0; j < 8; j++){ Ks[lr][lq * 8 + j] = kvv[j]; Vs[lr][lq * 8 + j] = vvv[j]; }
        #pragma unroll
        for (int j = 0; j < 4; j++) Cs[lr][lq * 4 + j] = cvv[j];
        __syncthreads();
        #pragma unroll 4
        for (int i = 0; i < 16; i++){
            int n = g * 16 + i;
            float4 k4 = *reinterpret_cast<const float4*>(&Ks[n][d0]);
            float4 v4 = *reinterpret_cast<const float4*>(&Vs[n][e0]);
            float2 c2 = *reinterpret_cast<const float2*>(&Cs[n][e0c]);
            float kk[4] = { k4.x, k4.y, k4.z, k4.w };
            float vv[4] = { v4.x, v4.y, v4.z, v4.w };
            #pragma unroll
            for (int a = 0; a < 4; a++){
                akv[a][0] = fmaf(kk[a], vv[0], akv[a][0]);
                akv[a][1] = fmaf(kk[a], vv[1], akv[a][1]);
                akv[a][2] = fmaf(kk[a], vv[2], akv[a][2]);
                akv[a][3] = fmaf(kk[a], vv[3], akv[a][3]);
                akc[a][0] = fmaf(kk[a], c2.x, akc[a][0]);
                akc[a][1] = fmaf(kk[a], c2.y, akc[a][1]);
            }
        }
    }
    __syncthreads();
    if (g >= 2){
        float* p = &P[g - 2][tl][0];
        #pragma unroll
        for (int a = 0; a < 4; a++){
            #pragma unroll
            for (int e = 0; e < 4; e++) p[a * 4 + e] = akv[a][e];
            p[16 + a * 2 + 0] = akc[a][0];
            p[16 + a * 2 + 1] = akc[a][1];
        }
    }
    __syncthreads();
    if (g < 2){
        const float* p = &P[g][tl][0];
        #pragma unroll
        for (int a = 0; a < 4; a++){
            #pragma unroll
            for (int e = 0; e < 4; e++) akv[a][e] += p[a * 4 + e];
            akc[a][0] += p[16 + a * 2 + 0];
            akc[a][1] += p[16 + a * 2 + 1];
        }
    }
    __syncthreads();
    if (g == 1){
        float* p = &P[0][tl][0];
        #pragma unroll
        for (int a = 0; a < 4; a++){
            #pragma unroll
            for (int e = 0; e < 4; e++) p[a * 4 + e] = akv[a][e];
            p[16 + a * 2 + 0] = akc[a][0];
            p[16 + a * 2 + 1] = akc[a][1];
        }
    }
    __syncthreads();
    if (g == 0){
        const float* p = &P[0][tl][0];
        const float sc = 1.0f / 16384.0f;
        float* o = KTV + (size_t)bh * 1024;
        float* o2 = KTC + (size_t)bh * 512;
        #pragma unroll
        for (int a = 0; a < 4; a++){
            #pragma unroll
            for (int e = 0; e < 4; e++)
                atomicAdd(&o[(d0 + a) * 32 + e0 + e], (akv[a][e] + p[a * 4 + e]) * sc);
            atomicAdd(&o2[(d0 + a) * 16 + e0c + 0], (akc[a][0] + p[16 + a * 2 + 0]) * sc);
            atomicAdd(&o2[(d0 + a) * 16 + e0c + 1], (akc[a][1] + p[16 + a * 2 + 1]) * sc);
        }
    }
}

// ---------- combined attention weights ----------
__global__ __launch_bounds__(256) void wcomb_kernel(const float* __restrict__ q_w,
                                                    const float* __restrict__ KTV,
                                                    const float* __restrict__ KTC,
                                                    unsigned short* __restrict__ WTC){
    int c = blockIdx.x;
    int b = blockIdx.y;
    int i = threadIdx.x;
    __shared__ float coef[32];
    int h = (c < 256) ? (c >> 5) : ((c - 256) >> 4);
    if (i < 32){
        if (c < 256) coef[i] = KTV[(size_t)((b * 8 + h) << 10) + i * 32 + (c & 31)];
        else         coef[i] = KTC[(size_t)((b * 8 + h) << 9)  + i * 16 + ((c - 256) & 15)];
    }
    __syncthreads();
    float acc = 0;
    #pragma unroll
    for (int d = 0; d < 32; d++) acc = fmaf(q_w[(size_t)(h * 32 + d) * 256 + i], coef[d], acc);
    WTC[((size_t)b * 384 + c) * 256 + i] = f2bf(acc);
}

// ---------- depthwise 3x3 conv (SAME) + bias + gelu, y-banded (4 rows/block) ----------
__global__ __launch_bounds__(192) void dwconv_kernel(const unsigned short* __restrict__ H1,
                                                     const float* __restrict__ dww,
                                                     const float* __restrict__ dwb,
                                                     unsigned short* __restrict__ H2){
    int blk = blockIdx.x;
    int xq = blk & 3;
    int yb = (blk >> 2) & 31;
    int bb = blk >> 7;
    int y0 = yb * 4, x0 = xq * 32;
    int ch = threadIdx.x * 4;
    float w[9][4];
    #pragma unroll
    for (int k = 0; k < 9; k++)
        #pragma unroll
        for (int j = 0; j < 4; j++) w[k][j] = dww[(ch + j) * 9 + k];
    float bias[4] = { dwb[ch], dwb[ch+1], dwb[ch+2], dwb[ch+3] };
    size_t rb[6]; bool rv[6];
    #pragma unroll
    for (int r = 0; r < 6; r++){
        int yr = y0 - 1 + r;
        rv[r] = ((unsigned)yr <= 127u);
        int yc = yr < 0 ? 0 : (yr > 127 ? 127 : yr);
        rb[r] = ((size_t)((bb << 14) + (yc << 7))) * 768 + ch;
    }
    size_t ob[4];
    #pragma unroll
    for (int j = 0; j < 4; j++) ob[j] = ((size_t)((bb << 14) + ((y0 + j) << 7))) * 768 + ch;

    ushort4 cA[6], cB[6], cC[6], cD[6];
    const ushort4 Z = {0, 0, 0, 0};
    #define LOADR(DST, XX) do {                                               \
        int _x = (XX);                                                        \
        bool xv = ((unsigned)_x <= 127u);                                     \
        _Pragma("unroll")                                                     \
        for (int r = 0; r < 6; r++)                                           \
            DST[r] = (xv && rv[r]) ? *reinterpret_cast<const ushort4*>(H1 + rb[r] + (size_t)_x * 768) : Z; \
    } while (0)

    #define EMITB(SA, SB, SC, XX) do {                                        \
        _Pragma("unroll")                                                     \
        for (int j = 0; j < 4; j++){                                          \
            float acc[4];                                                     \
            _Pragma("unroll")                                                 \
            for (int q = 0; q < 4; q++) acc[q] = bias[q];                     \
            _Pragma("unroll")                                                 \
            for (int rr2 = 0; rr2 < 3; rr2++){                                \
                int ri = j + rr2;                                             \
                float a0=bf2f(SA[ri].x),a1=bf2f(SA[ri].y),a2=bf2f(SA[ri].z),a3=bf2f(SA[ri].w); \
                float b0=bf2f(SB[ri].x),b1=bf2f(SB[ri].y),b2=bf2f(SB[ri].z),b3=bf2f(SB[ri].w); \
                float c0=bf2f(SC[ri].x),c1=bf2f(SC[ri].y),c2=bf2f(SC[ri].z),c3=bf2f(SC[ri].w); \
                acc[0]=fmaf(a0,w[rr2*3+0][0],acc[0]); acc[0]=fmaf(b0,w[rr2*3+1][0],acc[0]); acc[0]=fmaf(c0,w[rr2*3+2][0],acc[0]); \
                acc[1]=fmaf(a1,w[rr2*3+0][1],acc[1]); acc[1]=fmaf(b1,w[rr2*3+1][1],acc[1]); acc[1]=fmaf(c1,w[rr2*3+2][1],acc[1]); \
                acc[2]=fmaf(a2,w[rr2*3+0][2],acc[2]); acc[2]=fmaf(b2,w[rr2*3+1][2],acc[2]); acc[2]=fmaf(c2,w[rr2*3+2][2],acc[2]); \
                acc[3]=fmaf(a3,w[rr2*3+0][3],acc[3]); acc[3]=fmaf(b3,w[rr2*3+1][3],acc[3]); acc[3]=fmaf(c3,w[rr2*3+2][3],acc[3]); \
            }                                                                 \
            ushort4 o;                                                        \
            o.x = f2bf(gelu_f(acc[0])); o.y = f2bf(gelu_f(acc[1]));           \
            o.z = f2bf(gelu_f(acc[2])); o.w = f2bf(gelu_f(acc[3]));           \
            *reinterpret_cast<ushort4*>(H2 + ob[j] + (size_t)(XX) * 768) = o; \
        }                                                                     \
    } while (0)

    LOADR(cD, x0 - 1);
    LOADR(cA, x0);
    LOADR(cB, x0 + 1);
    LOADR(cC, x0 + 2);
    #pragma unroll 1
    for (int g = 0; g < 8; g++){
        int x = x0 + g * 4;
        EMITB(cD, cA, cB, x);     LOADR(cD, x + 3);
        EMITB(cA, cB, cC, x + 1); LOADR(cA, x + 4);
        EMITB(cB, cC, cD, x + 2); LOADR(cB, x + 5);
        EMITB(cC, cD, cA, x + 3); LOADR(cC, x + 6);
    }
    #undef LOADR
    #undef EMITB
}

// ---------- bf16 MFMA GEMM, wide-N, double-buffered LDS, coalesced repack epilogue ----------
#define M_KV        1
#define M_BIAS_GELU 2
#define M_BIAS_ADD2 3
#define M_BIAS      4
#define M_BIAS_BF16 5
#define M_BIAS_ADDX 6
#define M_ATTN      7

template<int MODE, bool SWAP, int K, int O, int WN>
__global__ __launch_bounds__(128 * WN) void mgemm(const unsigned short* __restrict__ A,
                                                  const unsigned short* __restrict__ Wp,
                                                  const float* __restrict__ bias,
                                                  const void* __restrict__ add,
                                                  void* __restrict__ out0,
                                                  void* __restrict__ out1){
    constexpr int WAVES = 2 * WN;
    constexpr int BN = 64 * WN;
    constexpr int CH = 8 + 4 * WN;
    constexpr int NT = K / 32;
    constexpr bool F32OUT = (MODE == M_BIAS || MODE == M_BIAS_ADDX);
    __shared__ __align__(16) unsigned short SMEM[2 * 128 * 32 + 2 * BN * 32];
    unsigned short* As0 = SMEM;
    unsigned short* Bs0 = SMEM + 2 * 128 * 32;
    const int t = threadIdx.x;
    const int lane = t & 63, wid = t >> 6;
    const int wm = wid & 1, wn = wid >> 1;
    const int row0 = blockIdx.x * 128;
    const int colB = blockIdx.y * BN;
    const unsigned short* W = Wp;
    if constexpr (MODE == M_ATTN) W += (size_t)(row0 >> 14) * (384 * 256);
    f32x4 acc[4][4];
    #pragma unroll
    for (int i = 0; i < 4; i++)
        #pragma unroll
        for (int j = 0; j < 4; j++){ f32x4 z = {0.f, 0.f, 0.f, 0.f}; acc[i][j] = z; }

    const int lr = lane >> 2;
    const int ls = lane & 3;
    const int kq = lane >> 4;
    const int rr = lane & 15;

    auto STAGE = [&](int buf, int kb){
        #pragma unroll
        for (int c = wid; c < CH; c += WAVES){
            int r16 = (c < 8) ? c : (c - 8);
            int row = r16 * 16 + lr;
            int ko = ls ^ ((row >> 1) & 3);
            if (c < 8){
                int ga = row0 + row;
                if (SWAP) ga ^= 32768;
                __builtin_amdgcn_global_load_lds(
                    (const __attribute__((address_space(1))) unsigned int*)(A + (size_t)ga * K + kb + ko * 8),
                    (__attribute__((address_space(3))) unsigned int*)(As0 + buf * 4096 + r16 * 512),
                    16, 0, 0);
            } else {
                int gc = colB + row;
                __builtin_amdgcn_global_load_lds(
                    (const __attribute__((address_space(1))) unsigned int*)(W + (size_t)gc * K + kb + ko * 8),
                    (__attribute__((address_space(3))) unsigned int*)(Bs0 + buf * (BN * 32) + r16 * 512),
                    16, 0, 0);
            }
        }
    };

    STAGE(0, 0);
    asm volatile("s_waitcnt vmcnt(0)" ::: "memory");
    __builtin_amdgcn_s_barrier();
    #pragma unroll 1
    for (int tt = 0; tt < NT; tt++){
        int cur = tt & 1;
        if (tt + 1 < NT) STAGE(cur ^ 1, (tt + 1) * 32);
        bf16x8 af[4], bfr[4];
        #pragma unroll
        for (int m = 0; m < 4; m++){
            int row = wm * 64 + m * 16 + rr;
            int s = kq ^ ((row >> 1) & 3);
            af[m] = *reinterpret_cast<const bf16x8*>(As0 + cur * 4096 + row * 32 + s * 8);
        }
        #pragma unroll
        for (int n = 0; n < 4; n++){
            int row = wn * 64 + n * 16 + rr;
            int s = kq ^ ((row >> 1) & 3);
            bfr[n] = *reinterpret_cast<const bf16x8*>(Bs0 + cur * (BN * 32) + row * 32 + s * 8);
        }
        #pragma unroll
        for (int m = 0; m < 4; m++)
            #pragma unroll
            for (int n = 0; n < 4; n++)
                acc[m][n] = __builtin_amdgcn_mfma_f32_16x16x32_bf16(af[m], bfr[n], acc[m][n], 0, 0, 0);
        if (tt + 1 < NT){
            asm volatile("s_waitcnt vmcnt(0)" ::: "memory");
            __builtin_amdgcn_s_barrier();
        }
    }

    // ---- coalesced repack epilogue: per-wave 4.5KB scratch, pitch 68 ----
    __syncthreads();
    unsigned short* scr = SMEM + (size_t)wid * 2304;
    float* scrf = (float*)scr;
    const int rloc = lane >> 2;          // 0..15
    const int cs = (lane & 3) * 16;      // col offset within 64
    #pragma unroll
    for (int m = 0; m < 4; m++){
        // stage (epilogue-local ops applied) into scratch
        #pragma unroll
        for (int n = 0; n < 4; n++){
            int col = colB + wn * 64 + n * 16 + rr;
            #pragma unroll
            for (int j = 0; j < 4; j++){
                float v = acc[m][n][j];
                int si = (kq * 4 + j) * 68 + n * 16 + rr;
                if constexpr (MODE == M_KV)            scr[si] = f2bf(v);
                else if constexpr (MODE == M_BIAS_GELU) scr[si] = f2bf(gelu_f(v + bias[col]));
                else if constexpr (MODE == M_BIAS_ADD2) scr[si] = f2bf(v + bias[col]);
                else if constexpr (MODE == M_BIAS_BF16) scr[si] = f2bf(v + bias[col]);
                else if constexpr (MODE == M_ATTN)      scr[si] = f2bf(v);
                else if constexpr (MODE == M_BIAS)      scrf[si] = v + bias[col];
                else if constexpr (MODE == M_BIAS_ADDX) scrf[si] = v + bias[col];
            }
        }
        int r = row0 + wm * 64 + m * 16 + rloc;
        int colb = colB + wn * 64 + cs;
        if constexpr (F32OUT){
            #pragma unroll
            for (int q = 0; q < 4; q++){
                float4 vv = *reinterpret_cast<const float4*>(&scrf[rloc * 68 + cs + q * 4]);
                size_t o = (size_t)r * O + colb + q * 4;
                if constexpr (MODE == M_BIAS_ADDX){
                    float4 xa = *reinterpret_cast<const float4*>(&((const float*)add)[o]);
                    vv.x += xa.x; vv.y += xa.y; vv.z += xa.z; vv.w += xa.w;
                }
                *reinterpret_cast<float4*>(&((float*)out0)[o]) = vv;
            }
        } else {
            #pragma unroll
            for (int q = 0; q < 2; q++){
                bf16x8 sv = *reinterpret_cast<const bf16x8*>(&scr[rloc * 68 + cs + q * 8]);
                int cg = colb + q * 8;
                if constexpr (MODE == M_KV){
                    unsigned short* dst = (cg < 256)
                        ? (unsigned short*)out0 + (size_t)r * 256 + cg
                        : (unsigned short*)out1 + (size_t)r * 256 + (cg - 256);
                    *reinterpret_cast<bf16x8*>(dst) = sv;
                } else if constexpr (MODE == M_ATTN){
                    if (cg < 256){
                        size_t o1 = (size_t)r * 256 + cg;
                        bf16x8 xv = *reinterpret_cast<const bf16x8*>((const unsigned short*)add + o1);
                        *reinterpret_cast<bf16x8*>((unsigned short*)out0 + o1) = add_bf8(sv, xv, 1.0f);
                    } else {
                        size_t o2 = (size_t)r * 128 + (cg - 256);
                        bf16x8 cv = *reinterpret_cast<const bf16x8*>((const unsigned short*)bias + o2);
                        *reinterpret_cast<bf16x8*>((unsigned short*)out1 + o2) = add_bf8(sv, cv, -1.0f);
                    }
                } else if constexpr (MODE == M_BIAS_ADD2){
                    size_t o = (size_t)r * O + cg;
                    bf16x8 xv = *reinterpret_cast<const bf16x8*>((const unsigned short*)add + o);
                    *reinterpret_cast<bf16x8*>((unsigned short*)out0 + o) = add_bf8(sv, xv, 2.0f);
                } else {
                    *reinterpret_cast<bf16x8*>((unsigned short*)out0 + (size_t)r * O + cg) = sv;
                }
            }
        }
    }
}

extern "C" void kernel_launch(void* const* d_in, const int* in_sizes, int n_in,
                              void* d_out, int out_size, void* d_ws, size_t ws_size,
                              hipStream_t stream){
    const float* x     = (const float*)d_in[0];
    const float* cor   = (const float*)d_in[1];
    const float* q_w   = (const float*)d_in[2];
    const float* kv_w  = (const float*)d_in[3];
    const float* cor_w = (const float*)d_in[4];
    const float* kln_w = (const float*)d_in[5];
    const float* kln_b = (const float*)d_in[6];
    const float* vln_w = (const float*)d_in[7];
    const float* vln_b = (const float*)d_in[8];
    const float* corln_w = (const float*)d_in[9];
    const float* corln_b = (const float*)d_in[10];
    const float* op1_w = (const float*)d_in[11];
    const float* op1_b = (const float*)d_in[12];
    const float* op2_w = (const float*)d_in[13];
    const float* op2_b = (const float*)d_in[14];
    const float* om1_w = (const float*)d_in[15];
    const float* om1_b = (const float*)d_in[16];
    const float* om2_w = (const float*)d_in[17];
    const float* om2_b = (const float*)d_in[18];
    const float* n1_w  = (const float*)d_in[19];
    const float* n1_b  = (const float*)d_in[20];
    const float* n2_w  = (const float*)d_in[21];
    const float* n2_b  = (const float*)d_in[22];
    const float* fc1_w = (const float*)d_in[23];
    const float* fc1_b = (const float*)d_in[24];
    const float* dw_w  = (const float*)d_in[25];
    const float* dw_b  = (const float*)d_in[26];
    const float* fc2_w = (const float*)d_in[27];
    const float* fc2_b = (const float*)d_in[28];

    // ---- workspace layout (bf16 elements unless noted) ----
    unsigned short* XN  = (unsigned short*)d_ws;           // NTOK*256
    unsigned short* Qb  = XN  + (size_t)NTOK * 256;
    unsigned short* Kb  = Qb  + (size_t)NTOK * 256;
    unsigned short* Vb  = Kb  + (size_t)NTOK * 256;
    unsigned short* CEF = Vb  + (size_t)NTOK * 256;        // NTOK*128
    unsigned short* CE  = CEF + (size_t)NTOK * 128;
    float* KTV = (float*)(CE + (size_t)NTOK * 128);        // 32768 f32
    float* KTC = KTV + 32768;                              // 16384 f32
    unsigned short* WTC = (unsigned short*)(KTC + 16384);  // 4*384*256 bf16
    unsigned short* Wb  = WTC + 4 * 384 * 256;             // 753664 bf16 weights
    unsigned short* H2  = Wb + 753664;                     // NTOK*768
    // overlays (disjoint live ranges):
    unsigned short* T1 = Vb;
    unsigned short* T2 = Kb;
    unsigned short* XB = Qb;
    unsigned short* Y  = Vb;
    unsigned short* TM = CE;
    unsigned short* MH = CEF;
    unsigned short* H1 = XN;      // spans XN+Qb+Kb = NTOK*768
    float* xout = (float*)d_out;
    float* mout = xout + (size_t)NTOK * 256;

    unsigned short* w_kv  = Wb + 65536;
    unsigned short* w_op1 = Wb + 196608;
    unsigned short* w_op2 = Wb + 262144;
    unsigned short* w_om1 = Wb + 327680;
    unsigned short* w_om2 = Wb + 344064;
    unsigned short* w_fc1 = Wb + 360448;
    unsigned short* w_fc2 = Wb + 557056;

    // 0. weights -> bf16
    wconv_kernel<<<736, 256, 0, stream>>>(q_w, kv_w, op1_w, op2_w, om1_w, om2_w, fc1_w, fc2_w, Wb);
    // 1. xn = std_ln(x, norm1)
    stdln_kernel<false><<<2048, 256, 0, stream>>>(x, n1_w, n1_b, XN);
    // 2. kv = xr @ kv_w.T (swapped rows), split K,V — WN=8 full width, A read once
    mgemm<M_KV, true, 256, 512, 8><<<dim3(512, 1), 1024, 0, stream>>>(XN, w_kv, nullptr, nullptr, Kb, Vb);
    // 3. ce_flat
    ce_kernel<<<2048, 256, 0, stream>>>(cor, cor_w, CEF);
    // 4. zero accumulators
    hipMemsetAsync(KTV, 0, (32768 + 16384) * sizeof(float), stream);
    // 5. fused LN + ktv + ktc (register-tiled)
    ktvc_kernel<<<dim3(32, 32), 256, 0, stream>>>(Kb, Vb, CEF, kln_w, kln_b, vln_w, vln_b,
                                                  corln_w, corln_b, KTV, KTC);
    // 6. combined attention weights WTC[b] = q_w^T · blockdiag(ktv|ktc)
    wcomb_kernel<<<dim3(384, 4), 256, 0, stream>>>(q_w, KTV, KTC, WTC);
    // 7. [t | dm] = xn @ WTC[b] (+xn | -ce_flat)
    mgemm<M_ATTN, false, 256, 384, 6><<<dim3(512, 1), 768, 0, stream>>>(XN, WTC, (const float*)CEF, XN, T1, TM);
    // 8. hidden = gelu(t @ op1.T + b)
    mgemm<M_BIAS_GELU, false, 256, 256, 4><<<dim3(512, 1), 512, 0, stream>>>(T1, w_op1, op1_b, nullptr, T2, nullptr);
    // 9. x_back = (hidden @ op2.T + b) + 2*xn
    mgemm<M_BIAS_ADD2, false, 256, 256, 4><<<dim3(512, 1), 512, 0, stream>>>(T2, w_op2, op2_b, XN, XB, nullptr);
    // 10. mh = gelu(dm @ om1.T + b)
    mgemm<M_BIAS_GELU, false, 128, 128, 2><<<dim3(512, 1), 256, 0, stream>>>(TM, w_om1, om1_b, nullptr, MH, nullptr);
    // 11. motion = mh @ om2.T + b -> output 1 (fp32)
    mgemm<M_BIAS, false, 128, 128, 2><<<dim3(512, 1), 256, 0, stream>>>(MH, w_om2, om2_b, nullptr, mout, nullptr);
    // 12. y = std_ln(x_back, norm2)
    stdln_kernel<true><<<2048, 256, 0, stream>>>(XB, n2_w, n2_b, Y);
    // 13. h1 = y @ fc1.T + b (bf16)
    mgemm<M_BIAS_BF16, false, 256, 768, 6><<<dim3(512, 2), 768, 0, stream>>>(Y, w_fc1, fc1_b, nullptr, H1, nullptr);
    // 14. depthwise conv + bias + gelu (y-banded)
    dwconv_kernel<<<512, 192, 0, stream>>>(H1, dw_w, dw_b, H2);
    // 15. x_out = h2 @ fc2.T + b + x -> output 0 (fp32)
    mgemm<M_BIAS_ADDX, false, 768, 256, 4><<<dim3(512, 1), 512, 0, stream>>>(H2, w_fc2, fc2_b, x, xout, nullptr);
}